// Round 1
// baseline (895.726 us; speedup 1.0000x reference)
//
#include <hip/hip_runtime.h>
#include <cstdint>
#include <cstddef>

namespace {
constexpr int B = 256, L = 200, H = 128, V = 50000, TK = 20;
constexpr float NEGV = -1e10f;
}

// ---------------------------------------------------------------- embed + norm
__global__ __launch_bounds__(128) void k_embed(const int* __restrict__ seq,
                                               const float* __restrict__ emb,
                                               float* __restrict__ hidden,
                                               float* __restrict__ nrm) {
  int row = blockIdx.x;            // b*L + l
  int h = threadIdx.x;             // 0..127
  int tok = seq[row];
  float v = emb[(size_t)tok * H + h];
  hidden[(size_t)row * H + h] = v;
  float s = v * v;
  for (int o = 32; o > 0; o >>= 1) s += __shfl_down(s, o, 64);
  __shared__ float red[2];
  if ((h & 63) == 0) red[h >> 6] = s;
  __syncthreads();
  if (h == 0) nrm[row] = sqrtf(red[0] + red[1]);
}

// ------------------------------------------ slen, zero_layer (into ecacc), e_s
__global__ __launch_bounds__(128) void k_init(const int* __restrict__ lengths,
                                              const float* __restrict__ hidden,
                                              float* __restrict__ ecacc,
                                              float* __restrict__ e_s) {
  int b = blockIdx.x, h = threadIdx.x;   // 128 threads
  int cnt = (lengths[b * L + h] > 0) ? 1 : 0;
  if (h + 128 < L && lengths[b * L + h + 128] > 0) cnt++;
  for (int o = 32; o > 0; o >>= 1) cnt += __shfl_down(cnt, o, 64);
  __shared__ int c2[2];
  __shared__ int s_slen;
  if ((h & 63) == 0) c2[h >> 6] = cnt;
  __syncthreads();
  if (h == 0) s_slen = c2[0] + c2[1];
  __syncthreads();
  int slen = s_slen;
  float s = 0.f;
  for (int l = 0; l < L; ++l) s += hidden[(size_t)(b * L + l) * H + h];
  ecacc[b * H + h] = s / (float)slen;
  e_s[b * H + h] = hidden[(size_t)(b * L + slen - 1) * H + h];
}

// -------------------------- S0 = cosine sim (+diag), WS = softplus(hidden·wn)
__global__ __launch_bounds__(256) void k_simws(const float* __restrict__ hidden,
                                               const float* __restrict__ nrm,
                                               const int* __restrict__ rev,
                                               const float* __restrict__ wnoise,
                                               const float* __restrict__ cluster,
                                               float* __restrict__ S0,
                                               float* __restrict__ WS) {
  __shared__ float As[64][65], Bh[64][65], Bw[64][65];
  int b = blockIdx.z;
  int l0 = blockIdx.y * 64, m0 = blockIdx.x * 64;
  int tid = threadIdx.x;
  int tx = tid & 15, ty = tid >> 4;
  int tx4 = tx * 4, ty4 = ty * 4;
  float acc_s[4][4] = {}, acc_w[4][4] = {};
  for (int kc = 0; kc < H; kc += 64) {
#pragma unroll
    for (int it = 0; it < 4; ++it) {
      int r = it * 16 + ty;
      int c4 = tx4;
      int lrow = l0 + r, mrow = m0 + r;
      float4 av = make_float4(0.f, 0.f, 0.f, 0.f);
      float4 bhv = av, bwv = av;
      if (lrow < L) av = *(const float4*)&hidden[(size_t)(b * L + lrow) * H + kc + c4];
      if (mrow < L) {
        bhv = *(const float4*)&hidden[(size_t)(b * L + mrow) * H + kc + c4];
        int rv = rev[b * L + mrow];
        bwv = *(const float4*)&wnoise[(size_t)rv * H + kc + c4];
      }
      As[r][c4 + 0] = av.x; As[r][c4 + 1] = av.y; As[r][c4 + 2] = av.z; As[r][c4 + 3] = av.w;
      Bh[r][c4 + 0] = bhv.x; Bh[r][c4 + 1] = bhv.y; Bh[r][c4 + 2] = bhv.z; Bh[r][c4 + 3] = bhv.w;
      Bw[r][c4 + 0] = bwv.x; Bw[r][c4 + 1] = bwv.y; Bw[r][c4 + 2] = bwv.z; Bw[r][c4 + 3] = bwv.w;
    }
    __syncthreads();
#pragma unroll 8
    for (int kk = 0; kk < 64; ++kk) {
      float a[4], bh[4], bw[4];
#pragma unroll
      for (int i = 0; i < 4; ++i) a[i] = As[ty4 + i][kk];
#pragma unroll
      for (int j = 0; j < 4; ++j) { bh[j] = Bh[tx4 + j][kk]; bw[j] = Bw[tx4 + j][kk]; }
#pragma unroll
      for (int i = 0; i < 4; ++i)
#pragma unroll
        for (int j = 0; j < 4; ++j) {
          acc_s[i][j] = fmaf(a[i], bh[j], acc_s[i][j]);
          acc_w[i][j] = fmaf(a[i], bw[j], acc_w[i][j]);
        }
    }
    __syncthreads();
  }
#pragma unroll
  for (int i = 0; i < 4; ++i) {
    int l = l0 + ty4 + i;
    if (l >= L) continue;
    float nl = nrm[b * L + l];
    float diag = cluster[rev[b * L + l]];
#pragma unroll
    for (int j = 0; j < 4; ++j) {
      int m = m0 + tx4 + j;
      if (m >= L) continue;
      float denom = nl * nrm[b * L + m] + 1e-6f;
      float s0 = acc_s[i][j] / denom;
      if (l == m) s0 += diag;
      size_t o = (size_t)(b * L + l) * L + m;
      S0[o] = s0;
      float x = acc_w[i][j];
      WS[o] = (x > 1.f) ? x : log1pf(expf(fminf(x, 1.f)));
    }
  }
}

// ------- per row: build msim in regs, top-K scatter to ET^T, softmax -> P
__global__ __launch_bounds__(256) void k_rowpass(const float* __restrict__ S0,
                                                 const float* __restrict__ WS,
                                                 const float* __restrict__ coff_i,
                                                 const int* __restrict__ lengths,
                                                 float* __restrict__ P,
                                                 unsigned char* __restrict__ ET) {
  int wid = threadIdx.x >> 6, lane = threadIdx.x & 63;
  int row = blockIdx.x * 4 + wid;          // 0..B*L-1
  int b = row / L, l = row - b * L;
  bool mask_l = lengths[row] > 0;
  size_t base = (size_t)row * L;
  float vals[4];
#pragma unroll
  for (int j = 0; j < 4; ++j) {
    int m = lane + 64 * j;
    float v = -INFINITY;
    if (m < L) {
      bool pair = mask_l && (lengths[b * L + m] > 0);
      v = pair ? (S0[base + m] + coff_i[base + m] * WS[base + m]) : NEGV;
    }
    vals[j] = v;
  }
  // iterative top-K (tie -> lowest index, matching lax.top_k's selected set)
  float tv[4] = {vals[0], vals[1], vals[2], vals[3]};
  float M = NEGV;
  for (int t = 0; t < TK; ++t) {
    float bv = tv[0]; int bi = lane;
#pragma unroll
    for (int j = 1; j < 4; ++j) {
      int m = lane + 64 * j;
      if (tv[j] > bv || (tv[j] == bv && m < bi)) { bv = tv[j]; bi = m; }
    }
    for (int off = 1; off < 64; off <<= 1) {
      float ov = __shfl_xor(bv, off, 64);
      int oi = __shfl_xor(bi, off, 64);
      if (ov > bv || (ov == bv && oi < bi)) { bv = ov; bi = oi; }
    }
    if (t == 0) M = bv;                    // row max (for softmax)
    if (bv <= -5e9f) break;                // only NEG left -> no more edges
    if (lane == 0) ET[(size_t)(b * L + bi) * L + l] = 1;
    if ((bi & 63) == lane) tv[bi >> 6] = -INFINITY;
  }
  // softmax over the row
  float e[4]; float s = 0.f;
#pragma unroll
  for (int j = 0; j < 4; ++j) {
    int m = lane + 64 * j;
    float ev = 0.f;
    if (m < L) ev = expf(vals[j] - M);
    e[j] = ev; s += ev;
  }
  for (int off = 1; off < 64; off <<= 1) s += __shfl_xor(s, off, 64);
  float inv = 1.f / s;
#pragma unroll
  for (int j = 0; j < 4; ++j) {
    int m = lane + 64 * j;
    if (m < L) P[base + m] = e[j] * inv;
  }
}

// ---- ssm row = P * ET, row-sum -> cmask, ordered in-place compaction to lists
__global__ __launch_bounds__(256) void k_compact(float* __restrict__ P,
                                                 unsigned char* __restrict__ ET,
                                                 float* __restrict__ cmask,
                                                 int* __restrict__ cnt) {
  int wid = threadIdx.x >> 6, lane = threadIdx.x & 63;
  int row = blockIdx.x * 4 + wid;
  size_t base = (size_t)row * L;
  float w[4];
  float s = 0.f;
#pragma unroll
  for (int j = 0; j < 4; ++j) {
    int m = lane + 64 * j;
    float ww = 0.f;
    if (m < L) ww = P[base + m] * (float)ET[base + m];
    w[j] = ww; s += ww;
  }
  float ssum = s;
  for (int off = 1; off < 64; off <<= 1) ssum += __shfl_xor(ssum, off, 64);
  if (lane == 0) cmask[row] = ssum;
  int pos_base = 0;
#pragma unroll
  for (int j = 0; j < 4; ++j) {
    bool nz = (w[j] != 0.f);
    unsigned long long mk = __ballot(nz);
    int rank = __popcll(mk & ((1ull << lane) - 1ull));
    if (nz) {
      int pos = pos_base + rank;
      ET[base + pos] = (unsigned char)(lane + 64 * j);
      P[base + pos] = w[j];
    }
    pos_base += (int)__popcll(mk);
  }
  if (lane == 0) cnt[row] = pos_base;
}

// -------------------------------------------- cmask /= max(||cmask||_2, 1e-12)
__global__ __launch_bounds__(64) void k_cnorm(float* __restrict__ cmask) {
  int b = blockIdx.x, lane = threadIdx.x;   // 64 threads
  float v[4]; float s = 0.f;
#pragma unroll
  for (int j = 0; j < 4; ++j) {
    int l = lane + 64 * j;
    float x = (l < L) ? cmask[b * L + l] : 0.f;
    v[j] = x; s += x * x;
  }
  for (int off = 1; off < 64; off <<= 1) s += __shfl_xor(s, off, 64);
  float inv = 1.f / fmaxf(sqrtf(s), 1e-12f);
#pragma unroll
  for (int j = 0; j < 4; ++j) {
    int l = lane + 64 * j;
    if (l < L) cmask[b * L + l] = v[j] * inv;
  }
}

// ------------------------------- update[l,:] = sum over edge list w * hidden[m]
__global__ __launch_bounds__(128) void k_update(const float* __restrict__ P,
                                                const unsigned char* __restrict__ ET,
                                                const int* __restrict__ cnt,
                                                const float* __restrict__ hidden,
                                                float* __restrict__ upd) {
  int row = blockIdx.x; int h = threadIdx.x;
  int b = row / L;
  size_t base = (size_t)row * L;
  int n = cnt[row];
  float acc = 0.f;
  for (int e = 0; e < n; ++e) {
    int m = ET[base + e];
    float w = P[base + e];
    acc += w * hidden[(size_t)(b * L + m) * H + h];
  }
  upd[(size_t)row * H + h] = acc;
}

// ----------- FFN + residual + LN, weighted by cmask, in-place on upd (32 rows)
__global__ __launch_bounds__(256) void k_ffn(float* __restrict__ upd,
                                             const float* __restrict__ W1,
                                             const float* __restrict__ b1,
                                             const float* __restrict__ W2,
                                             const float* __restrict__ b2,
                                             const float* __restrict__ g,
                                             const float* __restrict__ beta,
                                             const float* __restrict__ cmask) {
  __shared__ float xs[32][132];
  __shared__ float ps[32][132];
  __shared__ float mus[32], rsd[32];
  int row0 = blockIdx.x * 32;
  int tid = threadIdx.x;
  int hg = tid & 31, rg = tid >> 5;        // 32 col-groups x 8 row-groups
#pragma unroll
  for (int it = 0; it < 4; ++it) {
    int t = tid + it * 256;
    int r = t >> 5, c4 = t & 31;
    float4 v = *(const float4*)&upd[(size_t)(row0 + r) * H + c4 * 4];
    *(float4*)&xs[r][c4 * 4] = v;
  }
  __syncthreads();
  float acc[4][4];
  {
    float4 bv = *(const float4*)&b1[hg * 4];
#pragma unroll
    for (int i = 0; i < 4; ++i) {
      acc[i][0] = bv.x; acc[i][1] = bv.y; acc[i][2] = bv.z; acc[i][3] = bv.w;
    }
  }
#pragma unroll 4
  for (int k4 = 0; k4 < 32; ++k4) {
    float4 wv[4];
#pragma unroll
    for (int q = 0; q < 4; ++q) wv[q] = *(const float4*)&W1[(size_t)(k4 * 4 + q) * H + hg * 4];
    float4 a4[4];
#pragma unroll
    for (int i = 0; i < 4; ++i) a4[i] = *(const float4*)&xs[rg * 4 + i][k4 * 4];
#pragma unroll
    for (int i = 0; i < 4; ++i) {
      float ax[4] = {a4[i].x, a4[i].y, a4[i].z, a4[i].w};
#pragma unroll
      for (int q = 0; q < 4; ++q) {
        acc[i][0] = fmaf(ax[q], wv[q].x, acc[i][0]);
        acc[i][1] = fmaf(ax[q], wv[q].y, acc[i][1]);
        acc[i][2] = fmaf(ax[q], wv[q].z, acc[i][2]);
        acc[i][3] = fmaf(ax[q], wv[q].w, acc[i][3]);
      }
    }
  }
#pragma unroll
  for (int i = 0; i < 4; ++i) {
    float4 f = make_float4(fmaxf(acc[i][0], 0.f), fmaxf(acc[i][1], 0.f),
                           fmaxf(acc[i][2], 0.f), fmaxf(acc[i][3], 0.f));
    *(float4*)&ps[rg * 4 + i][hg * 4] = f;
  }
  __syncthreads();
  float acc2[4][4];
  {
    float4 bv = *(const float4*)&b2[hg * 4];
#pragma unroll
    for (int i = 0; i < 4; ++i) {
      float4 xv = *(const float4*)&xs[rg * 4 + i][hg * 4];
      acc2[i][0] = bv.x + xv.x; acc2[i][1] = bv.y + xv.y;
      acc2[i][2] = bv.z + xv.z; acc2[i][3] = bv.w + xv.w;
    }
  }
#pragma unroll 4
  for (int k4 = 0; k4 < 32; ++k4) {
    float4 wv[4];
#pragma unroll
    for (int q = 0; q < 4; ++q) wv[q] = *(const float4*)&W2[(size_t)(k4 * 4 + q) * H + hg * 4];
    float4 a4[4];
#pragma unroll
    for (int i = 0; i < 4; ++i) a4[i] = *(const float4*)&ps[rg * 4 + i][k4 * 4];
#pragma unroll
    for (int i = 0; i < 4; ++i) {
      float ax[4] = {a4[i].x, a4[i].y, a4[i].z, a4[i].w};
#pragma unroll
      for (int q = 0; q < 4; ++q) {
        acc2[i][0] = fmaf(ax[q], wv[q].x, acc2[i][0]);
        acc2[i][1] = fmaf(ax[q], wv[q].y, acc2[i][1]);
        acc2[i][2] = fmaf(ax[q], wv[q].z, acc2[i][2]);
        acc2[i][3] = fmaf(ax[q], wv[q].w, acc2[i][3]);
      }
    }
  }
  __syncthreads();                          // all reads of f1 done
#pragma unroll
  for (int i = 0; i < 4; ++i) {
    float4 f = make_float4(acc2[i][0], acc2[i][1], acc2[i][2], acc2[i][3]);
    *(float4*)&ps[rg * 4 + i][hg * 4] = f;  // pre
  }
  __syncthreads();
  {
    int r = tid >> 3, sub = tid & 7;
    float s = 0.f, sq = 0.f;
#pragma unroll
    for (int t2 = 0; t2 < 16; ++t2) {
      float x = ps[r][sub * 16 + t2];
      s += x; sq += x * x;
    }
    for (int off = 1; off < 8; off <<= 1) {
      s += __shfl_down(s, off, 8);
      sq += __shfl_down(sq, off, 8);
    }
    if (sub == 0) {
      float mu = s * (1.f / 128.f);
      float var = sq * (1.f / 128.f) - mu * mu;
      mus[r] = mu;
      rsd[r] = rsqrtf(var + 1e-5f);
    }
  }
  __syncthreads();
  {
    float4 g4 = *(const float4*)&g[hg * 4];
    float4 be4 = *(const float4*)&beta[hg * 4];
#pragma unroll
    for (int i = 0; i < 4; ++i) {
      int r = rg * 4 + i;
      float cm = cmask[row0 + r];
      float mu = mus[r], rs = rsd[r];
      float4 o;
      o.x = ((acc2[i][0] - mu) * rs * g4.x + be4.x) * cm;
      o.y = ((acc2[i][1] - mu) * rs * g4.y + be4.y) * cm;
      o.z = ((acc2[i][2] - mu) * rs * g4.z + be4.z) * cm;
      o.w = ((acc2[i][3] - mu) * rs * g4.w + be4.w) * cm;
      *(float4*)&upd[(size_t)(row0 + r) * H + hg * 4] = o;
    }
  }
}

// ---------------------------------------------- ecacc += sum_l (weighted feed2)
__global__ __launch_bounds__(128) void k_ecadd(const float* __restrict__ wf,
                                               float* __restrict__ ecacc) {
  int b = blockIdx.x, h = threadIdx.x;
  float s = 0.f;
  for (int l = 0; l < L; ++l) s += wf[(size_t)(b * L + l) * H + h];
  ecacc[b * H + h] += s;
}

// -------------------------------------------------------- gate -> sess, extras
__global__ __launch_bounds__(128) void k_gate(const float* __restrict__ ecacc,
                                              const float* __restrict__ e_s,
                                              const float* __restrict__ gw,
                                              float* __restrict__ sess,
                                              float* __restrict__ out) {
  __shared__ float cat[256];
  int b = blockIdx.x, h = threadIdx.x;
  float ec = ecacc[b * H + h] * (1.f / 3.f);
  float es = e_s[b * H + h];
  cat[h] = ec; cat[128 + h] = es;
  __syncthreads();
  float a = 0.f;
  for (int j = 0; j < 256; ++j) a = fmaf(cat[j], gw[(size_t)j * H + h], a);
  a = 1.f / (1.f + expf(-a));
  sess[b * H + h] = a * ec + (1.f - a) * es;
  if (b == 0 && h == 0) out[(size_t)B * V] = 0.f;   // con_loss
}

// ------------------------------------------------- scores = sess @ emb^T (NT)
__global__ __launch_bounds__(256) void k_scores(const float* __restrict__ sess,
                                                const float* __restrict__ emb,
                                                float* __restrict__ out) {
  __shared__ float As[64][65], Bs[64][65];
  int n0 = blockIdx.x * 64, m0 = blockIdx.y * 64;
  int tid = threadIdx.x, tx = tid & 15, ty = tid >> 4;
  int tx4 = tx * 4, ty4 = ty * 4;
  float acc[4][4] = {};
  for (int kc = 0; kc < H; kc += 64) {
#pragma unroll
    for (int it = 0; it < 4; ++it) {
      int r = it * 16 + ty, c4 = tx4;
      float4 av = *(const float4*)&sess[(size_t)(m0 + r) * H + kc + c4];
      As[r][c4 + 0] = av.x; As[r][c4 + 1] = av.y; As[r][c4 + 2] = av.z; As[r][c4 + 3] = av.w;
      float4 bv = make_float4(0.f, 0.f, 0.f, 0.f);
      if (n0 + r < V) bv = *(const float4*)&emb[(size_t)(n0 + r) * H + kc + c4];
      Bs[r][c4 + 0] = bv.x; Bs[r][c4 + 1] = bv.y; Bs[r][c4 + 2] = bv.z; Bs[r][c4 + 3] = bv.w;
    }
    __syncthreads();
#pragma unroll 8
    for (int kk = 0; kk < 64; ++kk) {
      float a[4], bb[4];
#pragma unroll
      for (int i = 0; i < 4; ++i) a[i] = As[ty4 + i][kk];
#pragma unroll
      for (int j = 0; j < 4; ++j) bb[j] = Bs[tx4 + j][kk];
#pragma unroll
      for (int i = 0; i < 4; ++i)
#pragma unroll
        for (int j = 0; j < 4; ++j) acc[i][j] = fmaf(a[i], bb[j], acc[i][j]);
    }
    __syncthreads();
  }
#pragma unroll
  for (int i = 0; i < 4; ++i) {
    int m = m0 + ty4 + i;
#pragma unroll
    for (int j = 0; j < 4; ++j) {
      int n = n0 + tx4 + j;
      if (n < V) out[(size_t)m * V + n] = acc[i][j];
    }
  }
}

extern "C" void kernel_launch(void* const* d_in, const int* in_sizes, int n_in,
                              void* d_out, int out_size, void* d_ws, size_t ws_size,
                              hipStream_t stream) {
  const int*   seq  = (const int*)d_in[0];
  const int*   lens = (const int*)d_in[1];
  const int*   rev  = (const int*)d_in[2];
  const float* emb  = (const float*)d_in[3];
  const float* wnz  = (const float*)d_in[4];
  const float* clw  = (const float*)d_in[5];
  const float* w1   = (const float*)d_in[6];
  const float* fb1  = (const float*)d_in[7];
  const float* w2   = (const float*)d_in[8];
  const float* fb2  = (const float*)d_in[9];
  const float* lng  = (const float*)d_in[10];
  const float* lnb  = (const float*)d_in[11];
  const float* gw   = (const float*)d_in[12];
  const float* coff = (const float*)d_in[13];
  float* out = (float*)d_out;

  char* ws = (char*)d_ws;
  size_t off = 0;
  auto alloc = [&](size_t bytes) {
    void* p = ws + off;
    off += (bytes + 255) & ~(size_t)255;
    return p;
  };
  float* hidden = (float*)alloc((size_t)B * L * H * 4);
  float* nrm    = (float*)alloc((size_t)B * L * 4);
  float* S0     = (float*)alloc((size_t)B * L * L * 4);
  float* WS     = (float*)alloc((size_t)B * L * L * 4);
  float* P      = (float*)alloc((size_t)B * L * L * 4);
  float* upd    = (float*)alloc((size_t)B * L * H * 4);
  float* cmask  = (float*)alloc((size_t)B * L * 4);
  int*   cnt    = (int*)alloc((size_t)B * L * 4);
  float* e_s    = (float*)alloc((size_t)B * H * 4);
  float* ecacc  = (float*)alloc((size_t)B * H * 4);
  float* sess   = (float*)alloc((size_t)B * H * 4);
  unsigned char* ET = (unsigned char*)alloc((size_t)B * L * L);

  k_embed<<<B * L, 128, 0, stream>>>(seq, emb, hidden, nrm);
  k_init<<<B, 128, 0, stream>>>(lens, hidden, ecacc, e_s);
  k_simws<<<dim3(4, 4, B), 256, 0, stream>>>(hidden, nrm, rev, wnz, clw, S0, WS);

  for (int i = 0; i < 2; ++i) {
    hipMemsetAsync(ET, 0, (size_t)B * L * L, stream);
    k_rowpass<<<B * L / 4, 256, 0, stream>>>(S0, WS, coff + (size_t)i * B * L * L,
                                             lens, P, ET);
    k_compact<<<B * L / 4, 256, 0, stream>>>(P, ET, cmask, cnt);
    k_cnorm<<<B, 64, 0, stream>>>(cmask);
    k_update<<<B * L, 128, 0, stream>>>(P, ET, cnt, hidden, upd);
    k_ffn<<<B * L / 32, 256, 0, stream>>>(upd, w1, fb1, w2, fb2, lng, lnb, cmask);
    k_ecadd<<<B, 128, 0, stream>>>(upd, ecacc);
  }

  k_gate<<<B, 128, 0, stream>>>(ecacc, e_s, gw, sess, out);
  k_scores<<<dim3((V + 63) / 64, 4), 256, 0, stream>>>(sess, emb, out);
}

// Round 2
// 790.269 us; speedup vs baseline: 1.1334x; 1.1334x over previous
//
#include <hip/hip_runtime.h>
#include <cstdint>
#include <cstddef>

namespace {
constexpr int B = 256, L = 200, H = 128, V = 50000, TK = 20;
constexpr int LP = 224;                    // L padded to 7 tiles of 32
constexpr float NEGV = -1e10f;
}

using bf16x8 = __attribute__((ext_vector_type(8))) short;
using f32x16 = __attribute__((ext_vector_type(16))) float;

__device__ inline unsigned short f2bf(float f) {
  unsigned int u = __float_as_uint(f);
  unsigned int r = (u + 0x7fffu + ((u >> 16) & 1u)) >> 16;   // RNE
  return (unsigned short)r;
}

// -------------------- embed + norm + bf16 staging (hidden, wnoise[rev]) -------
__global__ __launch_bounds__(128) void k_embed(const int* __restrict__ seq,
                                               const int* __restrict__ rev,
                                               const float* __restrict__ emb,
                                               const float* __restrict__ wnoise,
                                               float* __restrict__ hidden,
                                               float* __restrict__ nrm,
                                               unsigned short* __restrict__ hb,
                                               unsigned short* __restrict__ wnb) {
  int b = blockIdx.x / LP, l = blockIdx.x % LP;
  int h = threadIdx.x;
  size_t pb = ((size_t)b * LP + l) * H + h;
  if (l >= L) { hb[pb] = 0; wnb[pb] = 0; return; }
  int row = b * L + l;
  int tok = seq[row];
  float v = emb[(size_t)tok * H + h];
  hidden[(size_t)row * H + h] = v;
  hb[pb] = f2bf(v);
  wnb[pb] = f2bf(wnoise[(size_t)rev[row] * H + h]);
  float s = v * v;
  for (int o = 32; o > 0; o >>= 1) s += __shfl_down(s, o, 64);
  __shared__ float red[2];
  if ((h & 63) == 0) red[h >> 6] = s;
  __syncthreads();
  if (h == 0) nrm[row] = sqrtf(red[0] + red[1]);
}

// ------------------------------------------ slen, zero_layer (into ecacc), e_s
__global__ __launch_bounds__(128) void k_init(const int* __restrict__ lengths,
                                              const float* __restrict__ hidden,
                                              float* __restrict__ ecacc,
                                              float* __restrict__ e_s) {
  int b = blockIdx.x, h = threadIdx.x;   // 128 threads
  int cnt = (lengths[b * L + h] > 0) ? 1 : 0;
  if (h + 128 < L && lengths[b * L + h + 128] > 0) cnt++;
  for (int o = 32; o > 0; o >>= 1) cnt += __shfl_down(cnt, o, 64);
  __shared__ int c2[2];
  __shared__ int s_slen;
  if ((h & 63) == 0) c2[h >> 6] = cnt;
  __syncthreads();
  if (h == 0) s_slen = c2[0] + c2[1];
  __syncthreads();
  int slen = s_slen;
  float s = 0.f;
  for (int l = 0; l < L; ++l) s += hidden[(size_t)(b * L + l) * H + h];
  ecacc[b * H + h] = s / (float)slen;
  e_s[b * H + h] = hidden[(size_t)(b * L + slen - 1) * H + h];
}

// ---------- S0 = cosine sim (+diag), WS = softplus(hidden·wn) via bf16 MFMA ---
// wave layout (32x32x16): A row = lane&31 (l), B col = lane&31 (m),
// k = ks*16 + (lane>>5)*8 + i;  C/D: col=lane&31, row=(r&3)+8*(r>>2)+4*(lane>>5)
__global__ __launch_bounds__(256) void k_simws(const unsigned short* __restrict__ hb,
                                               const unsigned short* __restrict__ wnb,
                                               const float* __restrict__ nrm,
                                               const int* __restrict__ rev,
                                               const float* __restrict__ cluster,
                                               float* __restrict__ S0,
                                               float* __restrict__ WS) {
  int b = blockIdx.y;
  int lt = blockIdx.x;                       // 0..6
  int wid = threadIdx.x >> 6, lane = threadIdx.x & 63;
  int lr = lane & 31, kh = lane >> 5;
  const unsigned short* hbB = hb + (size_t)b * LP * H;
  const unsigned short* wnB = wnb + (size_t)b * LP * H;
  int arow = lt * 32 + lr;
  bf16x8 a[8];
#pragma unroll
  for (int ks = 0; ks < 8; ++ks)
    a[ks] = *(const bf16x8*)&hbB[(size_t)arow * H + ks * 16 + kh * 8];
  for (int mt = wid; mt < 7; mt += 4) {
    int mrow = mt * 32 + lr;
    f32x16 accs = {}, accw = {};
#pragma unroll
    for (int ks = 0; ks < 8; ++ks) {
      bf16x8 bh = *(const bf16x8*)&hbB[(size_t)mrow * H + ks * 16 + kh * 8];
      bf16x8 bw = *(const bf16x8*)&wnB[(size_t)mrow * H + ks * 16 + kh * 8];
      accs = __builtin_amdgcn_mfma_f32_32x32x16_bf16(a[ks], bh, accs, 0, 0, 0);
      accw = __builtin_amdgcn_mfma_f32_32x32x16_bf16(a[ks], bw, accw, 0, 0, 0);
    }
    int m = mt * 32 + lr;
    if (m < L) {
      float nm = nrm[b * L + m];
#pragma unroll
      for (int r = 0; r < 16; ++r) {
        int row = lt * 32 + (r & 3) + 8 * (r >> 2) + 4 * kh;
        if (row < L) {
          float nl = nrm[b * L + row];
          float s0 = accs[r] / (nl * nm + 1e-6f);
          if (row == m) s0 += cluster[rev[b * L + row]];
          size_t o = (size_t)(b * L + row) * L + m;
          S0[o] = s0;
          float x = accw[r];
          WS[o] = (x > 1.f) ? x : log1pf(expf(fminf(x, 1.f)));
        }
      }
    }
  }
}

// ------- per row: build msim in regs, top-K scatter to ET^T, softmax -> P
__global__ __launch_bounds__(256) void k_rowpass(const float* __restrict__ S0,
                                                 const float* __restrict__ WS,
                                                 const float* __restrict__ coff_i,
                                                 const int* __restrict__ lengths,
                                                 float* __restrict__ P,
                                                 unsigned char* __restrict__ ET) {
  int wid = threadIdx.x >> 6, lane = threadIdx.x & 63;
  int row = blockIdx.x * 4 + wid;          // 0..B*L-1
  int b = row / L, l = row - b * L;
  bool mask_l = lengths[row] > 0;
  size_t base = (size_t)row * L;
  float vals[4];
#pragma unroll
  for (int j = 0; j < 4; ++j) {
    int m = lane + 64 * j;
    float v = -INFINITY;
    if (m < L) {
      bool pair = mask_l && (lengths[b * L + m] > 0);
      v = pair ? (S0[base + m] + coff_i[base + m] * WS[base + m]) : NEGV;
    }
    vals[j] = v;
  }
  // iterative top-K (tie -> lowest index, matching lax.top_k's selected set)
  float tv[4] = {vals[0], vals[1], vals[2], vals[3]};
  float M = NEGV;
  for (int t = 0; t < TK; ++t) {
    float bv = tv[0]; int bi = lane;
#pragma unroll
    for (int j = 1; j < 4; ++j) {
      int m = lane + 64 * j;
      if (tv[j] > bv || (tv[j] == bv && m < bi)) { bv = tv[j]; bi = m; }
    }
    for (int off = 1; off < 64; off <<= 1) {
      float ov = __shfl_xor(bv, off, 64);
      int oi = __shfl_xor(bi, off, 64);
      if (ov > bv || (ov == bv && oi < bi)) { bv = ov; bi = oi; }
    }
    if (t == 0) M = bv;                    // row max (for softmax)
    if (bv <= -5e9f) break;                // only NEG left -> no more edges
    if (lane == 0) ET[(size_t)(b * L + bi) * L + l] = 1;
    if ((bi & 63) == lane) tv[bi >> 6] = -INFINITY;
  }
  // softmax over the row
  float e[4]; float s = 0.f;
#pragma unroll
  for (int j = 0; j < 4; ++j) {
    int m = lane + 64 * j;
    float ev = 0.f;
    if (m < L) ev = expf(vals[j] - M);
    e[j] = ev; s += ev;
  }
  for (int off = 1; off < 64; off <<= 1) s += __shfl_xor(s, off, 64);
  float inv = 1.f / s;
#pragma unroll
  for (int j = 0; j < 4; ++j) {
    int m = lane + 64 * j;
    if (m < L) P[base + m] = e[j] * inv;
  }
}

// ---- ssm row = P * ET, row-sum -> cmask, ordered in-place compaction to lists
__global__ __launch_bounds__(256) void k_compact(float* __restrict__ P,
                                                 unsigned char* __restrict__ ET,
                                                 float* __restrict__ cmask,
                                                 int* __restrict__ cnt) {
  int wid = threadIdx.x >> 6, lane = threadIdx.x & 63;
  int row = blockIdx.x * 4 + wid;
  size_t base = (size_t)row * L;
  float w[4];
  float s = 0.f;
#pragma unroll
  for (int j = 0; j < 4; ++j) {
    int m = lane + 64 * j;
    float ww = 0.f;
    if (m < L) ww = P[base + m] * (float)ET[base + m];
    w[j] = ww; s += ww;
  }
  float ssum = s;
  for (int off = 1; off < 64; off <<= 1) ssum += __shfl_xor(ssum, off, 64);
  if (lane == 0) cmask[row] = ssum;
  int pos_base = 0;
#pragma unroll
  for (int j = 0; j < 4; ++j) {
    bool nz = (w[j] != 0.f);
    unsigned long long mk = __ballot(nz);
    int rank = __popcll(mk & ((1ull << lane) - 1ull));
    if (nz) {
      int pos = pos_base + rank;
      ET[base + pos] = (unsigned char)(lane + 64 * j);
      P[base + pos] = w[j];
    }
    pos_base += (int)__popcll(mk);
  }
  if (lane == 0) cnt[row] = pos_base;
}

// -------------------------------------------- cmask /= max(||cmask||_2, 1e-12)
__global__ __launch_bounds__(64) void k_cnorm(float* __restrict__ cmask) {
  int b = blockIdx.x, lane = threadIdx.x;   // 64 threads
  float v[4]; float s = 0.f;
#pragma unroll
  for (int j = 0; j < 4; ++j) {
    int l = lane + 64 * j;
    float x = (l < L) ? cmask[b * L + l] : 0.f;
    v[j] = x; s += x * x;
  }
  for (int off = 1; off < 64; off <<= 1) s += __shfl_xor(s, off, 64);
  float inv = 1.f / fmaxf(sqrtf(s), 1e-12f);
#pragma unroll
  for (int j = 0; j < 4; ++j) {
    int l = lane + 64 * j;
    if (l < L) cmask[b * L + l] = v[j] * inv;
  }
}

// ------------------------------- update[l,:] = sum over edge list w * hidden[m]
__global__ __launch_bounds__(128) void k_update(const float* __restrict__ P,
                                                const unsigned char* __restrict__ ET,
                                                const int* __restrict__ cnt,
                                                const float* __restrict__ hidden,
                                                float* __restrict__ upd) {
  int row = blockIdx.x; int h = threadIdx.x;
  int b = row / L;
  size_t base = (size_t)row * L;
  int n = cnt[row];
  float acc = 0.f;
  for (int e = 0; e < n; ++e) {
    int m = ET[base + e];
    float w = P[base + e];
    acc += w * hidden[(size_t)(b * L + m) * H + h];
  }
  upd[(size_t)row * H + h] = acc;
}

// ----------- FFN + residual + LN, weighted by cmask, in-place on upd (32 rows)
__global__ __launch_bounds__(256) void k_ffn(float* __restrict__ upd,
                                             const float* __restrict__ W1,
                                             const float* __restrict__ b1,
                                             const float* __restrict__ W2,
                                             const float* __restrict__ b2,
                                             const float* __restrict__ g,
                                             const float* __restrict__ beta,
                                             const float* __restrict__ cmask) {
  __shared__ float xs[32][132];
  __shared__ float ps[32][132];
  __shared__ float mus[32], rsd[32];
  int row0 = blockIdx.x * 32;
  int tid = threadIdx.x;
  int hg = tid & 31, rg = tid >> 5;        // 32 col-groups x 8 row-groups
#pragma unroll
  for (int it = 0; it < 4; ++it) {
    int t = tid + it * 256;
    int r = t >> 5, c4 = t & 31;
    float4 v = *(const float4*)&upd[(size_t)(row0 + r) * H + c4 * 4];
    *(float4*)&xs[r][c4 * 4] = v;
  }
  __syncthreads();
  float acc[4][4];
  {
    float4 bv = *(const float4*)&b1[hg * 4];
#pragma unroll
    for (int i = 0; i < 4; ++i) {
      acc[i][0] = bv.x; acc[i][1] = bv.y; acc[i][2] = bv.z; acc[i][3] = bv.w;
    }
  }
#pragma unroll 4
  for (int k4 = 0; k4 < 32; ++k4) {
    float4 wv[4];
#pragma unroll
    for (int q = 0; q < 4; ++q) wv[q] = *(const float4*)&W1[(size_t)(k4 * 4 + q) * H + hg * 4];
    float4 a4[4];
#pragma unroll
    for (int i = 0; i < 4; ++i) a4[i] = *(const float4*)&xs[rg * 4 + i][k4 * 4];
#pragma unroll
    for (int i = 0; i < 4; ++i) {
      float ax[4] = {a4[i].x, a4[i].y, a4[i].z, a4[i].w};
#pragma unroll
      for (int q = 0; q < 4; ++q) {
        acc[i][0] = fmaf(ax[q], wv[q].x, acc[i][0]);
        acc[i][1] = fmaf(ax[q], wv[q].y, acc[i][1]);
        acc[i][2] = fmaf(ax[q], wv[q].z, acc[i][2]);
        acc[i][3] = fmaf(ax[q], wv[q].w, acc[i][3]);
      }
    }
  }
#pragma unroll
  for (int i = 0; i < 4; ++i) {
    float4 f = make_float4(fmaxf(acc[i][0], 0.f), fmaxf(acc[i][1], 0.f),
                           fmaxf(acc[i][2], 0.f), fmaxf(acc[i][3], 0.f));
    *(float4*)&ps[rg * 4 + i][hg * 4] = f;
  }
  __syncthreads();
  float acc2[4][4];
  {
    float4 bv = *(const float4*)&b2[hg * 4];
#pragma unroll
    for (int i = 0; i < 4; ++i) {
      float4 xv = *(const float4*)&xs[rg * 4 + i][hg * 4];
      acc2[i][0] = bv.x + xv.x; acc2[i][1] = bv.y + xv.y;
      acc2[i][2] = bv.z + xv.z; acc2[i][3] = bv.w + xv.w;
    }
  }
#pragma unroll 4
  for (int k4 = 0; k4 < 32; ++k4) {
    float4 wv[4];
#pragma unroll
    for (int q = 0; q < 4; ++q) wv[q] = *(const float4*)&W2[(size_t)(k4 * 4 + q) * H + hg * 4];
    float4 a4[4];
#pragma unroll
    for (int i = 0; i < 4; ++i) a4[i] = *(const float4*)&ps[rg * 4 + i][k4 * 4];
#pragma unroll
    for (int i = 0; i < 4; ++i) {
      float ax[4] = {a4[i].x, a4[i].y, a4[i].z, a4[i].w};
#pragma unroll
      for (int q = 0; q < 4; ++q) {
        acc2[i][0] = fmaf(ax[q], wv[q].x, acc2[i][0]);
        acc2[i][1] = fmaf(ax[q], wv[q].y, acc2[i][1]);
        acc2[i][2] = fmaf(ax[q], wv[q].z, acc2[i][2]);
        acc2[i][3] = fmaf(ax[q], wv[q].w, acc2[i][3]);
      }
    }
  }
  __syncthreads();                          // all reads of f1 done
#pragma unroll
  for (int i = 0; i < 4; ++i) {
    float4 f = make_float4(acc2[i][0], acc2[i][1], acc2[i][2], acc2[i][3]);
    *(float4*)&ps[rg * 4 + i][hg * 4] = f;  // pre
  }
  __syncthreads();
  {
    int r = tid >> 3, sub = tid & 7;
    float s = 0.f, sq = 0.f;
#pragma unroll
    for (int t2 = 0; t2 < 16; ++t2) {
      float x = ps[r][sub * 16 + t2];
      s += x; sq += x * x;
    }
    for (int off = 1; off < 8; off <<= 1) {
      s += __shfl_down(s, off, 8);
      sq += __shfl_down(sq, off, 8);
    }
    if (sub == 0) {
      float mu = s * (1.f / 128.f);
      float var = sq * (1.f / 128.f) - mu * mu;
      mus[r] = mu;
      rsd[r] = rsqrtf(var + 1e-5f);
    }
  }
  __syncthreads();
  {
    float4 g4 = *(const float4*)&g[hg * 4];
    float4 be4 = *(const float4*)&beta[hg * 4];
#pragma unroll
    for (int i = 0; i < 4; ++i) {
      int r = rg * 4 + i;
      float cm = cmask[row0 + r];
      float mu = mus[r], rs = rsd[r];
      float4 o;
      o.x = ((acc2[i][0] - mu) * rs * g4.x + be4.x) * cm;
      o.y = ((acc2[i][1] - mu) * rs * g4.y + be4.y) * cm;
      o.z = ((acc2[i][2] - mu) * rs * g4.z + be4.z) * cm;
      o.w = ((acc2[i][3] - mu) * rs * g4.w + be4.w) * cm;
      *(float4*)&upd[(size_t)(row0 + r) * H + hg * 4] = o;
    }
  }
}

// ---------------------------------------------- ecacc += sum_l (weighted feed2)
__global__ __launch_bounds__(128) void k_ecadd(const float* __restrict__ wf,
                                               float* __restrict__ ecacc) {
  int b = blockIdx.x, h = threadIdx.x;
  float s = 0.f;
  for (int l = 0; l < L; ++l) s += wf[(size_t)(b * L + l) * H + h];
  ecacc[b * H + h] += s;
}

// -------------------------------------------------------- gate -> sess, extras
__global__ __launch_bounds__(128) void k_gate(const float* __restrict__ ecacc,
                                              const float* __restrict__ e_s,
                                              const float* __restrict__ gw,
                                              float* __restrict__ sess,
                                              float* __restrict__ out) {
  __shared__ float cat[256];
  int b = blockIdx.x, h = threadIdx.x;
  float ec = ecacc[b * H + h] * (1.f / 3.f);
  float es = e_s[b * H + h];
  cat[h] = ec; cat[128 + h] = es;
  __syncthreads();
  float a = 0.f;
  for (int j = 0; j < 256; ++j) a = fmaf(cat[j], gw[(size_t)j * H + h], a);
  a = 1.f / (1.f + expf(-a));
  sess[b * H + h] = a * ec + (1.f - a) * es;
  if (b == 0 && h == 0) out[(size_t)B * V] = 0.f;   // con_loss
}

// ------------------------------------------------- scores = sess @ emb^T (NT)
__global__ __launch_bounds__(256) void k_scores(const float* __restrict__ sess,
                                                const float* __restrict__ emb,
                                                float* __restrict__ out) {
  __shared__ float As[64][65], Bs[64][65];
  int n0 = blockIdx.x * 64, m0 = blockIdx.y * 64;
  int tid = threadIdx.x, tx = tid & 15, ty = tid >> 4;
  int tx4 = tx * 4, ty4 = ty * 4;
  float acc[4][4] = {};
  for (int kc = 0; kc < H; kc += 64) {
#pragma unroll
    for (int it = 0; it < 4; ++it) {
      int r = it * 16 + ty, c4 = tx4;
      float4 av = *(const float4*)&sess[(size_t)(m0 + r) * H + kc + c4];
      As[r][c4 + 0] = av.x; As[r][c4 + 1] = av.y; As[r][c4 + 2] = av.z; As[r][c4 + 3] = av.w;
      float4 bv = make_float4(0.f, 0.f, 0.f, 0.f);
      if (n0 + r < V) bv = *(const float4*)&emb[(size_t)(n0 + r) * H + kc + c4];
      Bs[r][c4 + 0] = bv.x; Bs[r][c4 + 1] = bv.y; Bs[r][c4 + 2] = bv.z; Bs[r][c4 + 3] = bv.w;
    }
    __syncthreads();
#pragma unroll 8
    for (int kk = 0; kk < 64; ++kk) {
      float a[4], bb[4];
#pragma unroll
      for (int i = 0; i < 4; ++i) a[i] = As[ty4 + i][kk];
#pragma unroll
      for (int j = 0; j < 4; ++j) bb[j] = Bs[tx4 + j][kk];
#pragma unroll
      for (int i = 0; i < 4; ++i)
#pragma unroll
        for (int j = 0; j < 4; ++j) acc[i][j] = fmaf(a[i], bb[j], acc[i][j]);
    }
    __syncthreads();
  }
#pragma unroll
  for (int i = 0; i < 4; ++i) {
    int m = m0 + ty4 + i;
#pragma unroll
    for (int j = 0; j < 4; ++j) {
      int n = n0 + tx4 + j;
      if (n < V) out[(size_t)m * V + n] = acc[i][j];
    }
  }
}

extern "C" void kernel_launch(void* const* d_in, const int* in_sizes, int n_in,
                              void* d_out, int out_size, void* d_ws, size_t ws_size,
                              hipStream_t stream) {
  const int*   seq  = (const int*)d_in[0];
  const int*   lens = (const int*)d_in[1];
  const int*   rev  = (const int*)d_in[2];
  const float* emb  = (const float*)d_in[3];
  const float* wnz  = (const float*)d_in[4];
  const float* clw  = (const float*)d_in[5];
  const float* w1   = (const float*)d_in[6];
  const float* fb1  = (const float*)d_in[7];
  const float* w2   = (const float*)d_in[8];
  const float* fb2  = (const float*)d_in[9];
  const float* lng  = (const float*)d_in[10];
  const float* lnb  = (const float*)d_in[11];
  const float* gw   = (const float*)d_in[12];
  const float* coff = (const float*)d_in[13];
  float* out = (float*)d_out;

  char* ws = (char*)d_ws;
  size_t off = 0;
  auto alloc = [&](size_t bytes) {
    void* p = ws + off;
    off += (bytes + 255) & ~(size_t)255;
    return p;
  };
  float* hidden = (float*)alloc((size_t)B * L * H * 4);
  float* nrm    = (float*)alloc((size_t)B * L * 4);
  float* S0     = (float*)alloc((size_t)B * L * L * 4);
  float* WS     = (float*)alloc((size_t)B * L * L * 4);
  float* P      = (float*)alloc((size_t)B * L * L * 4);
  float* upd    = (float*)alloc((size_t)B * L * H * 4);
  float* cmask  = (float*)alloc((size_t)B * L * 4);
  int*   cnt    = (int*)alloc((size_t)B * L * 4);
  float* e_s    = (float*)alloc((size_t)B * H * 4);
  float* ecacc  = (float*)alloc((size_t)B * H * 4);
  float* sess   = (float*)alloc((size_t)B * H * 4);
  unsigned char* ET = (unsigned char*)alloc((size_t)B * L * L);
  unsigned short* hb  = (unsigned short*)alloc((size_t)B * LP * H * 2);
  unsigned short* wnb = (unsigned short*)alloc((size_t)B * LP * H * 2);

  k_embed<<<B * LP, 128, 0, stream>>>(seq, rev, emb, wnz, hidden, nrm, hb, wnb);
  k_init<<<B, 128, 0, stream>>>(lens, hidden, ecacc, e_s);
  k_simws<<<dim3(7, B), 256, 0, stream>>>(hb, wnb, nrm, rev, clw, S0, WS);

  for (int i = 0; i < 2; ++i) {
    hipMemsetAsync(ET, 0, (size_t)B * L * L, stream);
    k_rowpass<<<B * L / 4, 256, 0, stream>>>(S0, WS, coff + (size_t)i * B * L * L,
                                             lens, P, ET);
    k_compact<<<B * L / 4, 256, 0, stream>>>(P, ET, cmask, cnt);
    k_cnorm<<<B, 64, 0, stream>>>(cmask);
    k_update<<<B * L, 128, 0, stream>>>(P, ET, cnt, hidden, upd);
    k_ffn<<<B * L / 32, 256, 0, stream>>>(upd, w1, fb1, w2, fb2, lng, lnb, cmask);
    k_ecadd<<<B, 128, 0, stream>>>(upd, ecacc);
  }

  k_gate<<<B, 128, 0, stream>>>(ecacc, e_s, gw, sess, out);
  k_scores<<<dim3((V + 63) / 64, 4), 256, 0, stream>>>(sess, emb, out);
}

// Round 3
// 755.342 us; speedup vs baseline: 1.1859x; 1.0462x over previous
//
#include <hip/hip_runtime.h>
#include <cstdint>
#include <cstddef>

namespace {
constexpr int B = 256, L = 200, H = 128, V = 50000, TK = 20;
constexpr int LP = 224;                    // L padded to 7 tiles of 32
constexpr float NEGV = -1e10f;
}

using bf16x8 = __attribute__((ext_vector_type(8))) short;
using f32x16 = __attribute__((ext_vector_type(16))) float;

__device__ inline unsigned short f2bf(float f) {
  unsigned int u = __float_as_uint(f);
  unsigned int r = (u + 0x7fffu + ((u >> 16) & 1u)) >> 16;   // RNE
  return (unsigned short)r;
}

// ---- DPP wave64 reductions (gfx9 idiom: xor1,xor2,half_mirror,mirror,
//      bcast15->rows1,3, bcast31->rows2,3; result in lane 63) ----------------
#define DPP_QUAD_XOR1 0xB1
#define DPP_QUAD_XOR2 0x4E
#define DPP_ROW_HMIRR 0x141
#define DPP_ROW_MIRR  0x140
#define DPP_BCAST15   0x142
#define DPP_BCAST31   0x143

template <int CTRL, int RM>
__device__ inline unsigned dpp_max_step(unsigned v) {
  unsigned t = (unsigned)__builtin_amdgcn_update_dpp(0, (int)v, CTRL, RM, 0xF, true);
  return v > t ? v : t;
}
__device__ inline unsigned wave_max_u32(unsigned v) {
  v = dpp_max_step<DPP_QUAD_XOR1, 0xF>(v);
  v = dpp_max_step<DPP_QUAD_XOR2, 0xF>(v);
  v = dpp_max_step<DPP_ROW_HMIRR, 0xF>(v);
  v = dpp_max_step<DPP_ROW_MIRR, 0xF>(v);
  v = dpp_max_step<DPP_BCAST15, 0xA>(v);
  v = dpp_max_step<DPP_BCAST31, 0xC>(v);
  return (unsigned)__builtin_amdgcn_readlane((int)v, 63);   // uniform
}
template <int CTRL, int RM>
__device__ inline float dpp_add_step(float v) {
  int t = __builtin_amdgcn_update_dpp(0, __float_as_int(v), CTRL, RM, 0xF, true);
  return v + __int_as_float(t);
}
__device__ inline float wave_sum_f32(float v) {
  v = dpp_add_step<DPP_QUAD_XOR1, 0xF>(v);
  v = dpp_add_step<DPP_QUAD_XOR2, 0xF>(v);
  v = dpp_add_step<DPP_ROW_HMIRR, 0xF>(v);
  v = dpp_add_step<DPP_ROW_MIRR, 0xF>(v);
  v = dpp_add_step<DPP_BCAST15, 0xA>(v);
  v = dpp_add_step<DPP_BCAST31, 0xC>(v);
  return __int_as_float(__builtin_amdgcn_readlane(__float_as_int(v), 63));
}

__device__ inline unsigned f2key(float f) {        // order-preserving, bijective
  unsigned b = __float_as_uint(f);
  unsigned m = (unsigned)((int)b >> 31);
  return b ^ (m | 0x80000000u);
}
__device__ inline float key2f(unsigned u) {
  unsigned b = (u & 0x80000000u) ? (u & 0x7fffffffu) : ~u;
  return __uint_as_float(b);
}

// ---- embed + norm + bf16 hi/lo staging (hidden, wnoise[rev]) ----------------
__global__ __launch_bounds__(128) void k_embed(const int* __restrict__ seq,
                                               const int* __restrict__ rev,
                                               const float* __restrict__ emb,
                                               const float* __restrict__ wnoise,
                                               float* __restrict__ hidden,
                                               float* __restrict__ nrm,
                                               unsigned short* __restrict__ hbh,
                                               unsigned short* __restrict__ hbl,
                                               unsigned short* __restrict__ wnh,
                                               unsigned short* __restrict__ wnl) {
  int b = blockIdx.x / LP, l = blockIdx.x % LP;
  int h = threadIdx.x;
  size_t pb = ((size_t)b * LP + l) * H + h;
  if (l >= L) { hbh[pb] = 0; hbl[pb] = 0; wnh[pb] = 0; wnl[pb] = 0; return; }
  int row = b * L + l;
  int tok = seq[row];
  float v = emb[(size_t)tok * H + h];
  hidden[(size_t)row * H + h] = v;
  unsigned short hi = f2bf(v);
  hbh[pb] = hi;
  hbl[pb] = f2bf(v - __uint_as_float((unsigned)hi << 16));
  float w = wnoise[(size_t)rev[row] * H + h];
  unsigned short wh = f2bf(w);
  wnh[pb] = wh;
  wnl[pb] = f2bf(w - __uint_as_float((unsigned)wh << 16));
  float s = v * v;
  for (int o = 32; o > 0; o >>= 1) s += __shfl_down(s, o, 64);
  __shared__ float red[2];
  if ((h & 63) == 0) red[h >> 6] = s;
  __syncthreads();
  if (h == 0) nrm[row] = sqrtf(red[0] + red[1]);
}

// ------------------------------------------ slen, zero_layer (into ecacc), e_s
__global__ __launch_bounds__(128) void k_init(const int* __restrict__ lengths,
                                              const float* __restrict__ hidden,
                                              float* __restrict__ ecacc,
                                              float* __restrict__ e_s) {
  int b = blockIdx.x, h = threadIdx.x;   // 128 threads
  int cnt = (lengths[b * L + h] > 0) ? 1 : 0;
  if (h + 128 < L && lengths[b * L + h + 128] > 0) cnt++;
  for (int o = 32; o > 0; o >>= 1) cnt += __shfl_down(cnt, o, 64);
  __shared__ int c2[2];
  __shared__ int s_slen;
  if ((h & 63) == 0) c2[h >> 6] = cnt;
  __syncthreads();
  if (h == 0) s_slen = c2[0] + c2[1];
  __syncthreads();
  int slen = s_slen;
  float s = 0.f;
  for (int l = 0; l < L; ++l) s += hidden[(size_t)(b * L + l) * H + h];
  ecacc[b * H + h] = s / (float)slen;
  e_s[b * H + h] = hidden[(size_t)(b * L + slen - 1) * H + h];
}

// ---- S0 = cosine sim (+diag), WS = softplus(hidden·wn), bf16x3 split MFMA ---
// 32x32x16: C/D: col=lane&31, row=(r&3)+8*(r>>2)+4*(lane>>5)
__global__ __launch_bounds__(256) void k_simws(const unsigned short* __restrict__ hbh,
                                               const unsigned short* __restrict__ hbl,
                                               const unsigned short* __restrict__ wnh,
                                               const unsigned short* __restrict__ wnl,
                                               const float* __restrict__ nrm,
                                               const int* __restrict__ rev,
                                               const float* __restrict__ cluster,
                                               float* __restrict__ S0,
                                               float* __restrict__ WS) {
  int b = blockIdx.y;
  int lt = blockIdx.x;                       // 0..6
  int wid = threadIdx.x >> 6, lane = threadIdx.x & 63;
  int lr = lane & 31, kh = lane >> 5;
  size_t bb = (size_t)b * LP * H;
  int arow = lt * 32 + lr;
  bf16x8 ah[8], al[8];
#pragma unroll
  for (int ks = 0; ks < 8; ++ks) {
    ah[ks] = *(const bf16x8*)&hbh[bb + (size_t)arow * H + ks * 16 + kh * 8];
    al[ks] = *(const bf16x8*)&hbl[bb + (size_t)arow * H + ks * 16 + kh * 8];
  }
  for (int mt = wid; mt < 7; mt += 4) {
    int mrow = mt * 32 + lr;
    f32x16 accs = {}, accw = {};
#pragma unroll
    for (int ks = 0; ks < 8; ++ks) {
      size_t o = bb + (size_t)mrow * H + ks * 16 + kh * 8;
      bf16x8 bhh = *(const bf16x8*)&hbh[o];
      bf16x8 bhl = *(const bf16x8*)&hbl[o];
      bf16x8 bwh = *(const bf16x8*)&wnh[o];
      bf16x8 bwl = *(const bf16x8*)&wnl[o];
      accs = __builtin_amdgcn_mfma_f32_32x32x16_bf16(ah[ks], bhh, accs, 0, 0, 0);
      accs = __builtin_amdgcn_mfma_f32_32x32x16_bf16(ah[ks], bhl, accs, 0, 0, 0);
      accs = __builtin_amdgcn_mfma_f32_32x32x16_bf16(al[ks], bhh, accs, 0, 0, 0);
      accw = __builtin_amdgcn_mfma_f32_32x32x16_bf16(ah[ks], bwh, accw, 0, 0, 0);
      accw = __builtin_amdgcn_mfma_f32_32x32x16_bf16(ah[ks], bwl, accw, 0, 0, 0);
      accw = __builtin_amdgcn_mfma_f32_32x32x16_bf16(al[ks], bwh, accw, 0, 0, 0);
    }
    int m = mt * 32 + lr;
    if (m < L) {
      float nm = nrm[b * L + m];
#pragma unroll
      for (int r = 0; r < 16; ++r) {
        int row = lt * 32 + (r & 3) + 8 * (r >> 2) + 4 * kh;
        if (row < L) {
          float nl = nrm[b * L + row];
          float s0 = accs[r] / (nl * nm + 1e-6f);
          if (row == m) s0 += cluster[rev[b * L + row]];
          size_t o = (size_t)(b * L + row) * L + m;
          S0[o] = s0;
          float x = accw[r];
          WS[o] = (x > 1.f) ? x : log1pf(expf(fminf(x, 1.f)));
        }
      }
    }
  }
}

// ------- per row: msim in regs, DPP-argmax top-K scatter to ET^T, softmax -> P
__global__ __launch_bounds__(256) void k_rowpass(const float* __restrict__ S0,
                                                 const float* __restrict__ WS,
                                                 const float* __restrict__ coff_i,
                                                 const int* __restrict__ lengths,
                                                 float* __restrict__ P,
                                                 unsigned char* __restrict__ ET) {
  int wid = threadIdx.x >> 6, lane = threadIdx.x & 63;
  int row = blockIdx.x * 4 + wid;          // 0..B*L-1
  int b = row / L, l = row - b * L;
  bool mask_l = lengths[row] > 0;
  size_t base = (size_t)row * L;
  float v0 = 0.f, v1 = 0.f, v2 = 0.f, v3 = 0.f;
  bool a0 = false, a1 = false, a2 = false, a3 = false;
  if (lane < 50) {
    float4 s4 = *(const float4*)&S0[base + lane * 4];
    float4 w4 = *(const float4*)&WS[base + lane * 4];
    float4 c4 = *(const float4*)&coff_i[base + lane * 4];
    int4 ln4 = *(const int4*)&lengths[b * L + lane * 4];
    a0 = mask_l && ln4.x > 0; a1 = mask_l && ln4.y > 0;
    a2 = mask_l && ln4.z > 0; a3 = mask_l && ln4.w > 0;
    v0 = s4.x + c4.x * w4.x; v1 = s4.y + c4.y * w4.y;
    v2 = s4.z + c4.z * w4.z; v3 = s4.w + c4.w * w4.w;
  }
  unsigned k0 = a0 ? f2key(v0) : 0u, k1 = a1 ? f2key(v1) : 0u;
  unsigned k2 = a2 ? f2key(v2) : 0u, k3 = a3 ? f2key(v3) : 0u;
  unsigned Mu = 0u;
  for (int t = 0; t < TK; ++t) {
    unsigned lm = k0 > k1 ? k0 : k1;
    unsigned lm2 = k2 > k3 ? k2 : k3;
    lm = lm > lm2 ? lm : lm2;
    unsigned wm = wave_max_u32(lm);
    if (t == 0) Mu = wm;
    if (wm == 0u) break;                   // only NEG/pad left (or empty row)
    bool e0 = (k0 == wm), e1 = (k1 == wm), e2 = (k2 == wm), e3 = (k3 == wm);
    unsigned long long mk = __ballot(e0 || e1 || e2 || e3);
    int owner = (int)__builtin_ctzll(mk);  // lowest lane (tie -> lowest index)
    if (lane == owner) {
      int js = e0 ? 0 : (e1 ? 1 : (e2 ? 2 : 3));
      int bi = lane * 4 + js;
      ET[((size_t)b * L + bi) * L + l] = 1;
      if (js == 0) k0 = 0u; else if (js == 1) k1 = 0u;
      else if (js == 2) k2 = 0u; else k3 = 0u;
    }
  }
  // softmax over the row (invalid entries contribute exactly 0, as exp(NEG-M))
  float M = key2f(Mu);
  float e0f = a0 ? expf(v0 - M) : 0.f;
  float e1f = a1 ? expf(v1 - M) : 0.f;
  float e2f = a2 ? expf(v2 - M) : 0.f;
  float e3f = a3 ? expf(v3 - M) : 0.f;
  float s = wave_sum_f32(e0f + e1f + e2f + e3f);
  float inv = (s > 0.f) ? 1.f / s : 0.f;
  if (lane < 50) {
    float4 p4 = make_float4(e0f * inv, e1f * inv, e2f * inv, e3f * inv);
    *(float4*)&P[base + lane * 4] = p4;
  }
}

// ---- ssm row = P * ET, row-sum -> cmask, ordered in-place compaction to lists
__global__ __launch_bounds__(256) void k_compact(float* __restrict__ P,
                                                 unsigned char* __restrict__ ET,
                                                 float* __restrict__ cmask,
                                                 int* __restrict__ cnt) {
  int wid = threadIdx.x >> 6, lane = threadIdx.x & 63;
  int row = blockIdx.x * 4 + wid;
  size_t base = (size_t)row * L;
  float w[4];
  float s = 0.f;
#pragma unroll
  for (int j = 0; j < 4; ++j) {
    int m = lane + 64 * j;
    float ww = 0.f;
    if (m < L) ww = P[base + m] * (float)ET[base + m];
    w[j] = ww; s += ww;
  }
  float ssum = s;
  for (int off = 1; off < 64; off <<= 1) ssum += __shfl_xor(ssum, off, 64);
  if (lane == 0) cmask[row] = ssum;
  int pos_base = 0;
#pragma unroll
  for (int j = 0; j < 4; ++j) {
    bool nz = (w[j] != 0.f);
    unsigned long long mk = __ballot(nz);
    int rank = __popcll(mk & ((1ull << lane) - 1ull));
    if (nz) {
      int pos = pos_base + rank;
      ET[base + pos] = (unsigned char)(lane + 64 * j);
      P[base + pos] = w[j];
    }
    pos_base += (int)__popcll(mk);
  }
  if (lane == 0) cnt[row] = pos_base;
}

// -------------------------------------------- cmask /= max(||cmask||_2, 1e-12)
__global__ __launch_bounds__(64) void k_cnorm(float* __restrict__ cmask) {
  int b = blockIdx.x, lane = threadIdx.x;   // 64 threads
  float v[4]; float s = 0.f;
#pragma unroll
  for (int j = 0; j < 4; ++j) {
    int l = lane + 64 * j;
    float x = (l < L) ? cmask[b * L + l] : 0.f;
    v[j] = x; s += x * x;
  }
  for (int off = 1; off < 64; off <<= 1) s += __shfl_xor(s, off, 64);
  float inv = 1.f / fmaxf(sqrtf(s), 1e-12f);
#pragma unroll
  for (int j = 0; j < 4; ++j) {
    int l = lane + 64 * j;
    if (l < L) cmask[b * L + l] = v[j] * inv;
  }
}

// ------------------------------- update[l,:] = sum over edge list w * hidden[m]
__global__ __launch_bounds__(128) void k_update(const float* __restrict__ P,
                                                const unsigned char* __restrict__ ET,
                                                const int* __restrict__ cnt,
                                                const float* __restrict__ hidden,
                                                float* __restrict__ upd) {
  int row = blockIdx.x; int h = threadIdx.x;
  int b = row / L;
  size_t base = (size_t)row * L;
  int n = cnt[row];
  float acc = 0.f;
  for (int e = 0; e < n; ++e) {
    int m = ET[base + e];
    float w = P[base + e];
    acc += w * hidden[(size_t)(b * L + m) * H + h];
  }
  upd[(size_t)row * H + h] = acc;
}

// ----------- FFN + residual + LN, weighted by cmask, in-place on upd (32 rows)
__global__ __launch_bounds__(256) void k_ffn(float* __restrict__ upd,
                                             const float* __restrict__ W1,
                                             const float* __restrict__ b1,
                                             const float* __restrict__ W2,
                                             const float* __restrict__ b2,
                                             const float* __restrict__ g,
                                             const float* __restrict__ beta,
                                             const float* __restrict__ cmask) {
  __shared__ float xs[32][132];
  __shared__ float ps[32][132];
  __shared__ float mus[32], rsd[32];
  int row0 = blockIdx.x * 32;
  int tid = threadIdx.x;
  int hg = tid & 31, rg = tid >> 5;        // 32 col-groups x 8 row-groups
#pragma unroll
  for (int it = 0; it < 4; ++it) {
    int t = tid + it * 256;
    int r = t >> 5, c4 = t & 31;
    float4 v = *(const float4*)&upd[(size_t)(row0 + r) * H + c4 * 4];
    *(float4*)&xs[r][c4 * 4] = v;
  }
  __syncthreads();
  float acc[4][4];
  {
    float4 bv = *(const float4*)&b1[hg * 4];
#pragma unroll
    for (int i = 0; i < 4; ++i) {
      acc[i][0] = bv.x; acc[i][1] = bv.y; acc[i][2] = bv.z; acc[i][3] = bv.w;
    }
  }
#pragma unroll 4
  for (int k4 = 0; k4 < 32; ++k4) {
    float4 wv[4];
#pragma unroll
    for (int q = 0; q < 4; ++q) wv[q] = *(const float4*)&W1[(size_t)(k4 * 4 + q) * H + hg * 4];
    float4 a4[4];
#pragma unroll
    for (int i = 0; i < 4; ++i) a4[i] = *(const float4*)&xs[rg * 4 + i][k4 * 4];
#pragma unroll
    for (int i = 0; i < 4; ++i) {
      float ax[4] = {a4[i].x, a4[i].y, a4[i].z, a4[i].w};
#pragma unroll
      for (int q = 0; q < 4; ++q) {
        acc[i][0] = fmaf(ax[q], wv[q].x, acc[i][0]);
        acc[i][1] = fmaf(ax[q], wv[q].y, acc[i][1]);
        acc[i][2] = fmaf(ax[q], wv[q].z, acc[i][2]);
        acc[i][3] = fmaf(ax[q], wv[q].w, acc[i][3]);
      }
    }
  }
#pragma unroll
  for (int i = 0; i < 4; ++i) {
    float4 f = make_float4(fmaxf(acc[i][0], 0.f), fmaxf(acc[i][1], 0.f),
                           fmaxf(acc[i][2], 0.f), fmaxf(acc[i][3], 0.f));
    *(float4*)&ps[rg * 4 + i][hg * 4] = f;
  }
  __syncthreads();
  float acc2[4][4];
  {
    float4 bv = *(const float4*)&b2[hg * 4];
#pragma unroll
    for (int i = 0; i < 4; ++i) {
      float4 xv = *(const float4*)&xs[rg * 4 + i][hg * 4];
      acc2[i][0] = bv.x + xv.x; acc2[i][1] = bv.y + xv.y;
      acc2[i][2] = bv.z + xv.z; acc2[i][3] = bv.w + xv.w;
    }
  }
#pragma unroll 4
  for (int k4 = 0; k4 < 32; ++k4) {
    float4 wv[4];
#pragma unroll
    for (int q = 0; q < 4; ++q) wv[q] = *(const float4*)&W2[(size_t)(k4 * 4 + q) * H + hg * 4];
    float4 a4[4];
#pragma unroll
    for (int i = 0; i < 4; ++i) a4[i] = *(const float4*)&ps[rg * 4 + i][k4 * 4];
#pragma unroll
    for (int i = 0; i < 4; ++i) {
      float ax[4] = {a4[i].x, a4[i].y, a4[i].z, a4[i].w};
#pragma unroll
      for (int q = 0; q < 4; ++q) {
        acc2[i][0] = fmaf(ax[q], wv[q].x, acc2[i][0]);
        acc2[i][1] = fmaf(ax[q], wv[q].y, acc2[i][1]);
        acc2[i][2] = fmaf(ax[q], wv[q].z, acc2[i][2]);
        acc2[i][3] = fmaf(ax[q], wv[q].w, acc2[i][3]);
      }
    }
  }
  __syncthreads();                          // all reads of f1 done
#pragma unroll
  for (int i = 0; i < 4; ++i) {
    float4 f = make_float4(acc2[i][0], acc2[i][1], acc2[i][2], acc2[i][3]);
    *(float4*)&ps[rg * 4 + i][hg * 4] = f;  // pre
  }
  __syncthreads();
  {
    int r = tid >> 3, sub = tid & 7;
    float s = 0.f, sq = 0.f;
#pragma unroll
    for (int t2 = 0; t2 < 16; ++t2) {
      float x = ps[r][sub * 16 + t2];
      s += x; sq += x * x;
    }
    for (int off = 1; off < 8; off <<= 1) {
      s += __shfl_down(s, off, 8);
      sq += __shfl_down(sq, off, 8);
    }
    if (sub == 0) {
      float mu = s * (1.f / 128.f);
      float var = sq * (1.f / 128.f) - mu * mu;
      mus[r] = mu;
      rsd[r] = rsqrtf(var + 1e-5f);
    }
  }
  __syncthreads();
  {
    float4 g4 = *(const float4*)&g[hg * 4];
    float4 be4 = *(const float4*)&beta[hg * 4];
#pragma unroll
    for (int i = 0; i < 4; ++i) {
      int r = rg * 4 + i;
      float cm = cmask[row0 + r];
      float mu = mus[r], rs = rsd[r];
      float4 o;
      o.x = ((acc2[i][0] - mu) * rs * g4.x + be4.x) * cm;
      o.y = ((acc2[i][1] - mu) * rs * g4.y + be4.y) * cm;
      o.z = ((acc2[i][2] - mu) * rs * g4.z + be4.z) * cm;
      o.w = ((acc2[i][3] - mu) * rs * g4.w + be4.w) * cm;
      *(float4*)&upd[(size_t)(row0 + r) * H + hg * 4] = o;
    }
  }
}

// ---------------------------------------------- ecacc += sum_l (weighted feed2)
__global__ __launch_bounds__(128) void k_ecadd(const float* __restrict__ wf,
                                               float* __restrict__ ecacc) {
  int b = blockIdx.x, h = threadIdx.x;
  float s = 0.f;
  for (int l = 0; l < L; ++l) s += wf[(size_t)(b * L + l) * H + h];
  ecacc[b * H + h] += s;
}

// -------------------------------------------------------- gate -> sess, extras
__global__ __launch_bounds__(128) void k_gate(const float* __restrict__ ecacc,
                                              const float* __restrict__ e_s,
                                              const float* __restrict__ gw,
                                              float* __restrict__ sess,
                                              float* __restrict__ out) {
  __shared__ float cat[256];
  int b = blockIdx.x, h = threadIdx.x;
  float ec = ecacc[b * H + h] * (1.f / 3.f);
  float es = e_s[b * H + h];
  cat[h] = ec; cat[128 + h] = es;
  __syncthreads();
  float a = 0.f;
  for (int j = 0; j < 256; ++j) a = fmaf(cat[j], gw[(size_t)j * H + h], a);
  a = 1.f / (1.f + expf(-a));
  sess[b * H + h] = a * ec + (1.f - a) * es;
  if (b == 0 && h == 0) out[(size_t)B * V] = 0.f;   // con_loss
}

// ------------------------------------------------- scores = sess @ emb^T (NT)
__global__ __launch_bounds__(256) void k_scores(const float* __restrict__ sess,
                                                const float* __restrict__ emb,
                                                float* __restrict__ out) {
  __shared__ float As[64][65], Bs[64][65];
  int n0 = blockIdx.x * 64, m0 = blockIdx.y * 64;
  int tid = threadIdx.x, tx = tid & 15, ty = tid >> 4;
  int tx4 = tx * 4, ty4 = ty * 4;
  float acc[4][4] = {};
  for (int kc = 0; kc < H; kc += 64) {
#pragma unroll
    for (int it = 0; it < 4; ++it) {
      int r = it * 16 + ty, c4 = tx4;
      float4 av = *(const float4*)&sess[(size_t)(m0 + r) * H + kc + c4];
      As[r][c4 + 0] = av.x; As[r][c4 + 1] = av.y; As[r][c4 + 2] = av.z; As[r][c4 + 3] = av.w;
      float4 bv = make_float4(0.f, 0.f, 0.f, 0.f);
      if (n0 + r < V) bv = *(const float4*)&emb[(size_t)(n0 + r) * H + kc + c4];
      Bs[r][c4 + 0] = bv.x; Bs[r][c4 + 1] = bv.y; Bs[r][c4 + 2] = bv.z; Bs[r][c4 + 3] = bv.w;
    }
    __syncthreads();
#pragma unroll 8
    for (int kk = 0; kk < 64; ++kk) {
      float a[4], bb[4];
#pragma unroll
      for (int i = 0; i < 4; ++i) a[i] = As[ty4 + i][kk];
#pragma unroll
      for (int j = 0; j < 4; ++j) bb[j] = Bs[tx4 + j][kk];
#pragma unroll
      for (int i = 0; i < 4; ++i)
#pragma unroll
        for (int j = 0; j < 4; ++j) acc[i][j] = fmaf(a[i], bb[j], acc[i][j]);
    }
    __syncthreads();
  }
#pragma unroll
  for (int i = 0; i < 4; ++i) {
    int m = m0 + ty4 + i;
#pragma unroll
    for (int j = 0; j < 4; ++j) {
      int n = n0 + tx4 + j;
      if (n < V) out[(size_t)m * V + n] = acc[i][j];
    }
  }
}

extern "C" void kernel_launch(void* const* d_in, const int* in_sizes, int n_in,
                              void* d_out, int out_size, void* d_ws, size_t ws_size,
                              hipStream_t stream) {
  const int*   seq  = (const int*)d_in[0];
  const int*   lens = (const int*)d_in[1];
  const int*   rev  = (const int*)d_in[2];
  const float* emb  = (const float*)d_in[3];
  const float* wnz  = (const float*)d_in[4];
  const float* clw  = (const float*)d_in[5];
  const float* w1   = (const float*)d_in[6];
  const float* fb1  = (const float*)d_in[7];
  const float* w2   = (const float*)d_in[8];
  const float* fb2  = (const float*)d_in[9];
  const float* lng  = (const float*)d_in[10];
  const float* lnb  = (const float*)d_in[11];
  const float* gw   = (const float*)d_in[12];
  const float* coff = (const float*)d_in[13];
  float* out = (float*)d_out;

  char* ws = (char*)d_ws;
  size_t off = 0;
  auto alloc = [&](size_t bytes) {
    void* p = ws + off;
    off += (bytes + 255) & ~(size_t)255;
    return p;
  };
  float* hidden = (float*)alloc((size_t)B * L * H * 4);
  float* nrm    = (float*)alloc((size_t)B * L * 4);
  float* S0     = (float*)alloc((size_t)B * L * L * 4);
  float* WS     = (float*)alloc((size_t)B * L * L * 4);
  float* P      = (float*)alloc((size_t)B * L * L * 4);
  float* upd    = (float*)alloc((size_t)B * L * H * 4);
  float* cmask  = (float*)alloc((size_t)B * L * 4);
  int*   cnt    = (int*)alloc((size_t)B * L * 4);
  float* e_s    = (float*)alloc((size_t)B * H * 4);
  float* ecacc  = (float*)alloc((size_t)B * H * 4);
  float* sess   = (float*)alloc((size_t)B * H * 4);
  unsigned char* ET = (unsigned char*)alloc((size_t)B * L * L);
  unsigned short* hbh = (unsigned short*)alloc((size_t)B * LP * H * 2);
  unsigned short* wnh = (unsigned short*)alloc((size_t)B * LP * H * 2);
  // lo-residual staging aliases P/upd (first written only inside the layer loop,
  // strictly after k_simws has consumed the staging buffers)
  unsigned short* hbl = (unsigned short*)P;
  unsigned short* wnl = (unsigned short*)upd;

  k_embed<<<B * LP, 128, 0, stream>>>(seq, rev, emb, wnz, hidden, nrm,
                                      hbh, hbl, wnh, wnl);
  k_init<<<B, 128, 0, stream>>>(lens, hidden, ecacc, e_s);
  k_simws<<<dim3(7, B), 256, 0, stream>>>(hbh, hbl, wnh, wnl, nrm, rev, clw, S0, WS);

  for (int i = 0; i < 2; ++i) {
    hipMemsetAsync(ET, 0, (size_t)B * L * L, stream);
    k_rowpass<<<B * L / 4, 256, 0, stream>>>(S0, WS, coff + (size_t)i * B * L * L,
                                             lens, P, ET);
    k_compact<<<B * L / 4, 256, 0, stream>>>(P, ET, cmask, cnt);
    k_cnorm<<<B, 64, 0, stream>>>(cmask);
    k_update<<<B * L, 128, 0, stream>>>(P, ET, cnt, hidden, upd);
    k_ffn<<<B * L / 32, 256, 0, stream>>>(upd, w1, fb1, w2, fb2, lng, lnb, cmask);
    k_ecadd<<<B, 128, 0, stream>>>(upd, ecacc);
  }

  k_gate<<<B, 128, 0, stream>>>(ecacc, e_s, gw, sess, out);
  k_scores<<<dim3((V + 63) / 64, 4), 256, 0, stream>>>(sess, emb, out);
}

// Round 4
// 688.532 us; speedup vs baseline: 1.3009x; 1.0970x over previous
//
#include <hip/hip_runtime.h>
#include <cstdint>
#include <cstddef>

namespace {
constexpr int B = 256, L = 200, H = 128, V = 50000, TK = 20;
constexpr float NEGV = -1e10f;
}

using bf16x8 = __attribute__((ext_vector_type(8))) short;
using s16x8  = __attribute__((ext_vector_type(8))) short;
using f32x16 = __attribute__((ext_vector_type(16))) float;

__device__ inline unsigned short f2bf(float f) {
  unsigned int u = __float_as_uint(f);
  unsigned int r = (u + 0x7fffu + ((u >> 16) & 1u)) >> 16;   // RNE
  return (unsigned short)r;
}

// ---- 16-lane-group DPP reductions (quad xor1, xor2, half-mirror, mirror ->
//      full 16-lane result broadcast to all 16 lanes; rows independent) ------
#define DPP_QUAD_XOR1 0xB1
#define DPP_QUAD_XOR2 0x4E
#define DPP_ROW_HMIRR 0x141
#define DPP_ROW_MIRR  0x140

template <int CTRL>
__device__ inline unsigned dpp16_max_step(unsigned v) {
  unsigned t = (unsigned)__builtin_amdgcn_update_dpp(0, (int)v, CTRL, 0xF, 0xF, true);
  return v > t ? v : t;
}
__device__ inline unsigned grp16_max(unsigned v) {
  v = dpp16_max_step<DPP_QUAD_XOR1>(v);
  v = dpp16_max_step<DPP_QUAD_XOR2>(v);
  v = dpp16_max_step<DPP_ROW_HMIRR>(v);
  v = dpp16_max_step<DPP_ROW_MIRR>(v);
  return v;                                   // uniform within each 16-group
}
template <int CTRL>
__device__ inline float dpp16_add_step(float v) {
  int t = __builtin_amdgcn_update_dpp(0, __float_as_int(v), CTRL, 0xF, 0xF, true);
  return v + __int_as_float(t);
}
__device__ inline float grp16_sum(float v) {
  v = dpp16_add_step<DPP_QUAD_XOR1>(v);
  v = dpp16_add_step<DPP_QUAD_XOR2>(v);
  v = dpp16_add_step<DPP_ROW_HMIRR>(v);
  v = dpp16_add_step<DPP_ROW_MIRR>(v);
  return v;
}

__device__ inline unsigned f2key(float f) {        // order-preserving, bijective
  unsigned b = __float_as_uint(f);
  unsigned m = (unsigned)((int)b >> 31);
  return b ^ (m | 0x80000000u);
}
__device__ inline float key2f(unsigned u) {
  unsigned b = (u & 0x80000000u) ? (u & 0x7fffffffu) : ~u;
  return __uint_as_float(b);
}

// ---- embed + norm + frag-linear bf16 hi/lo staging --------------------------
// staging layout (16B units): fi(b,lt,ks,lane) = ((b*7+lt)*8+ks)*64 + lane,
// lane = kh*32 + row32; chunk holds k = ks*16 + kh*8 .. +8 of row lt*32+row32.
__global__ __launch_bounds__(256) void k_embed(const int* __restrict__ seq,
                                               const int* __restrict__ rev,
                                               const float* __restrict__ emb,
                                               const float* __restrict__ wnoise,
                                               float* __restrict__ hidden,
                                               float* __restrict__ nrm,
                                               s16x8* __restrict__ hbh,
                                               s16x8* __restrict__ hbl,
                                               s16x8* __restrict__ wnh,
                                               s16x8* __restrict__ wnl) {
  int b = blockIdx.x / 7, lt = blockIdx.x % 7;
  int t = threadIdx.x;
  int r = t >> 3, c2 = t & 7;                 // row-in-tile, 16-elem h-chunk
  int l = lt * 32 + r;
  bool valid = l < L;
  float vv[16], wv[16];
  if (valid) {
    int row = b * L + l;
    int tok = seq[row];
    const float4* ep = (const float4*)&emb[(size_t)tok * H + c2 * 16];
    const float4* wp = (const float4*)&wnoise[(size_t)rev[row] * H + c2 * 16];
#pragma unroll
    for (int i = 0; i < 4; ++i) {
      float4 x = ep[i];
      vv[i * 4 + 0] = x.x; vv[i * 4 + 1] = x.y; vv[i * 4 + 2] = x.z; vv[i * 4 + 3] = x.w;
      float4 y = wp[i];
      wv[i * 4 + 0] = y.x; wv[i * 4 + 1] = y.y; wv[i * 4 + 2] = y.z; wv[i * 4 + 3] = y.w;
    }
  } else {
#pragma unroll
    for (int i = 0; i < 16; ++i) { vv[i] = 0.f; wv[i] = 0.f; }
  }
  // hidden + nrm (8 threads per row)
  if (valid) {
    int row = b * L + l;
#pragma unroll
    for (int i = 0; i < 4; ++i)
      *(float4*)&hidden[(size_t)row * H + c2 * 16 + i * 4] =
          make_float4(vv[i * 4], vv[i * 4 + 1], vv[i * 4 + 2], vv[i * 4 + 3]);
    float s = 0.f;
#pragma unroll
    for (int i = 0; i < 16; ++i) s += vv[i] * vv[i];
    s += __shfl_down(s, 4, 8);
    s += __shfl_down(s, 2, 8);
    s += __shfl_down(s, 1, 8);
    if (c2 == 0) nrm[row] = sqrtf(s);
  }
  // bf16 hi/lo split -> two 16B chunks per buffer (kh=0: i 0..7, kh=1: i 8..15)
  s16x8 h0, h1, l0, l1, w0, w1, x0, x1;
#pragma unroll
  for (int i = 0; i < 8; ++i) {
    unsigned short hi = f2bf(vv[i]);
    h0[i] = (short)hi;
    l0[i] = (short)f2bf(vv[i] - __uint_as_float((unsigned)hi << 16));
    unsigned short wh = f2bf(wv[i]);
    w0[i] = (short)wh;
    x0[i] = (short)f2bf(wv[i] - __uint_as_float((unsigned)wh << 16));
  }
#pragma unroll
  for (int i = 0; i < 8; ++i) {
    unsigned short hi = f2bf(vv[8 + i]);
    h1[i] = (short)hi;
    l1[i] = (short)f2bf(vv[8 + i] - __uint_as_float((unsigned)hi << 16));
    unsigned short wh = f2bf(wv[8 + i]);
    w1[i] = (short)wh;
    x1[i] = (short)f2bf(wv[8 + i] - __uint_as_float((unsigned)wh << 16));
  }
  size_t fi0 = ((size_t)(b * 7 + lt) * 8 + c2) * 64 + r;   // kh=0
  size_t fi1 = fi0 + 32;                                   // kh=1
  hbh[fi0] = h0; hbh[fi1] = h1;
  hbl[fi0] = l0; hbl[fi1] = l1;
  wnh[fi0] = w0; wnh[fi1] = w1;
  wnl[fi0] = x0; wnl[fi1] = x1;
}

// ------------------------------------------ slen, zero_layer (into ecacc), e_s
__global__ __launch_bounds__(128) void k_init(const int* __restrict__ lengths,
                                              const float* __restrict__ hidden,
                                              float* __restrict__ ecacc,
                                              float* __restrict__ e_s) {
  int b = blockIdx.x, h = threadIdx.x;   // 128 threads
  int cnt = (lengths[b * L + h] > 0) ? 1 : 0;
  if (h + 128 < L && lengths[b * L + h + 128] > 0) cnt++;
  for (int o = 32; o > 0; o >>= 1) cnt += __shfl_down(cnt, o, 64);
  __shared__ int c2[2];
  __shared__ int s_slen;
  if ((h & 63) == 0) c2[h >> 6] = cnt;
  __syncthreads();
  if (h == 0) s_slen = c2[0] + c2[1];
  __syncthreads();
  int slen = s_slen;
  float s = 0.f;
  for (int l = 0; l < L; ++l) s += hidden[(size_t)(b * L + l) * H + h];
  ecacc[b * H + h] = s / (float)slen;
  e_s[b * H + h] = hidden[(size_t)(b * L + slen - 1) * H + h];
}

// ---- S0 = cosine sim (+diag), WS = softplus(hidden·wn), bf16x3 split MFMA ---
// frag-linear loads (1KB coalesced) + XCD-chunked block swizzle.
// 32x32x16 C/D: col=lane&31, row=(r&3)+8*(r>>2)+4*(lane>>5)
__global__ __launch_bounds__(256) void k_simws(const s16x8* __restrict__ hbh,
                                               const s16x8* __restrict__ hbl,
                                               const s16x8* __restrict__ wnh,
                                               const s16x8* __restrict__ wnl,
                                               const float* __restrict__ nrm,
                                               const int* __restrict__ rev,
                                               const float* __restrict__ cluster,
                                               float* __restrict__ S0,
                                               float* __restrict__ WS) {
  int orig = blockIdx.x;                     // 0..1791 (= 8 XCD * 32 b * 7 lt)
  int xcd = orig & 7, slot = orig >> 3;
  int b = xcd * 32 + slot / 7, lt = slot % 7;
  int wid = threadIdx.x >> 6, lane = threadIdx.x & 63;
  int lr = lane & 31, kh = lane >> 5;
  size_t abase = ((size_t)(b * 7 + lt) * 8) * 64 + lane;
  bf16x8 ah[8], al[8];
#pragma unroll
  for (int ks = 0; ks < 8; ++ks) {
    ah[ks] = (bf16x8)hbh[abase + ks * 64];
    al[ks] = (bf16x8)hbl[abase + ks * 64];
  }
  for (int mt = wid; mt < 7; mt += 4) {
    size_t bbase = ((size_t)(b * 7 + mt) * 8) * 64 + lane;
    f32x16 accs = {}, accw = {};
#pragma unroll
    for (int ks = 0; ks < 8; ++ks) {
      bf16x8 bhh = (bf16x8)hbh[bbase + ks * 64];
      bf16x8 bhl = (bf16x8)hbl[bbase + ks * 64];
      bf16x8 bwh = (bf16x8)wnh[bbase + ks * 64];
      bf16x8 bwl = (bf16x8)wnl[bbase + ks * 64];
      accs = __builtin_amdgcn_mfma_f32_32x32x16_bf16(ah[ks], bhh, accs, 0, 0, 0);
      accs = __builtin_amdgcn_mfma_f32_32x32x16_bf16(ah[ks], bhl, accs, 0, 0, 0);
      accs = __builtin_amdgcn_mfma_f32_32x32x16_bf16(al[ks], bhh, accs, 0, 0, 0);
      accw = __builtin_amdgcn_mfma_f32_32x32x16_bf16(ah[ks], bwh, accw, 0, 0, 0);
      accw = __builtin_amdgcn_mfma_f32_32x32x16_bf16(ah[ks], bwl, accw, 0, 0, 0);
      accw = __builtin_amdgcn_mfma_f32_32x32x16_bf16(al[ks], bwh, accw, 0, 0, 0);
    }
    int m = mt * 32 + lr;
    if (m < L) {
      float nm = nrm[b * L + m];
#pragma unroll
      for (int r = 0; r < 16; ++r) {
        int row = lt * 32 + (r & 3) + 8 * (r >> 2) + 4 * kh;
        if (row < L) {
          float nl = nrm[b * L + row];
          float s0 = accs[r] / (nl * nm + 1e-6f);
          if (row == m) s0 += cluster[rev[b * L + row]];
          size_t o = (size_t)(b * L + row) * L + m;
          S0[o] = s0;
          float x = accw[r];
          WS[o] = (x > 1.f) ? x : log1pf(expf(fminf(x, 1.f)));
        }
      }
    }
  }
}

// ------- per row: msim in regs (13/lane over 16 lanes), DPP16 top-K, softmax
// 4 waves/block, 4 rows/wave (one per 16-lane group) -> 16 rows/block
__global__ __launch_bounds__(256) void k_rowpass(const float* __restrict__ S0,
                                                 const float* __restrict__ WS,
                                                 const float* __restrict__ coff_i,
                                                 const int* __restrict__ lengths,
                                                 float* __restrict__ P,
                                                 unsigned char* __restrict__ ET) {
  int wid = threadIdx.x >> 6, lane = threadIdx.x & 63;
  int g = lane >> 4, q = lane & 15;
  int bb = blockIdx.x / 13, blk = blockIdx.x % 13;
  int l = blk * 16 + wid * 4 + g;
  bool lvalid = l < L;
  int lrow = bb * L + (lvalid ? l : 0);
  bool mask_l = lvalid && (lengths[lrow] > 0);
  size_t base = (size_t)lrow * L;
  float val[13]; unsigned key[13]; unsigned vmask = 0;
#pragma unroll
  for (int j = 0; j < 13; ++j) {
    int m = q + 16 * j;
    float v = 0.f; bool ok = false;
    if (mask_l && m < L) {
      ok = lengths[bb * L + m] > 0;
      if (ok) v = S0[base + m] + coff_i[base + m] * WS[base + m];
    }
    val[j] = v;
    key[j] = ok ? f2key(v) : 0u;
    vmask |= ok ? (1u << j) : 0u;
  }
  unsigned Mu = 0u;
  for (int t = 0; t < TK; ++t) {
    unsigned lv = key[0]; int lj = 0;
#pragma unroll
    for (int j = 1; j < 13; ++j) {
      bool gt = key[j] > lv;
      lv = gt ? key[j] : lv;
      lj = gt ? j : lj;
    }
    unsigned gm = grp16_max(lv);
    if (t == 0) Mu = gm;
    if (__all(gm == 0u)) break;              // all 4 groups exhausted
    unsigned long long bal = __ballot(lv == gm && gm != 0u);
    unsigned long long mine = bal & (0xFFFFull << (g * 16));
    int owner = mine ? (int)__builtin_ctzll(mine) : -1;
    bool is_owner = (lane == owner);         // lowest lane of group (tie ok)
    if (is_owner) {
      int m = q + 16 * lj;
      ET[((size_t)bb * L + m) * L + l] = 1;
    }
#pragma unroll
    for (int j = 0; j < 13; ++j) key[j] = (is_owner && lj == j) ? 0u : key[j];
  }
  // softmax over the row (invalid entries contribute exactly 0)
  float M = key2f(Mu);
  float e[13]; float s = 0.f;
#pragma unroll
  for (int j = 0; j < 13; ++j) {
    float ev = ((vmask >> j) & 1u) ? expf(val[j] - M) : 0.f;
    e[j] = ev; s += ev;
  }
  s = grp16_sum(s);
  float inv = (s > 0.f) ? 1.f / s : 0.f;
  if (lvalid) {
#pragma unroll
    for (int j = 0; j < 13; ++j) {
      int m = q + 16 * j;
      if (m < L) P[base + m] = e[j] * inv;
    }
  }
}

// ---- ssm row = P * ET, row-sum -> cmask, ordered in-place compaction to lists
__global__ __launch_bounds__(256) void k_compact(float* __restrict__ P,
                                                 unsigned char* __restrict__ ET,
                                                 float* __restrict__ cmask,
                                                 int* __restrict__ cnt) {
  int wid = threadIdx.x >> 6, lane = threadIdx.x & 63;
  int row = blockIdx.x * 4 + wid;
  size_t base = (size_t)row * L;
  float w[4];
  float s = 0.f;
#pragma unroll
  for (int j = 0; j < 4; ++j) {
    int m = lane + 64 * j;
    float ww = 0.f;
    if (m < L) ww = P[base + m] * (float)ET[base + m];
    w[j] = ww; s += ww;
  }
  float ssum = s;
  for (int off = 1; off < 64; off <<= 1) ssum += __shfl_xor(ssum, off, 64);
  if (lane == 0) cmask[row] = ssum;
  int pos_base = 0;
#pragma unroll
  for (int j = 0; j < 4; ++j) {
    bool nz = (w[j] != 0.f);
    unsigned long long mk = __ballot(nz);
    int rank = __popcll(mk & ((1ull << lane) - 1ull));
    if (nz) {
      int pos = pos_base + rank;
      ET[base + pos] = (unsigned char)(lane + 64 * j);
      P[base + pos] = w[j];
    }
    pos_base += (int)__popcll(mk);
  }
  if (lane == 0) cnt[row] = pos_base;
}

// -------------------------------------------- cmask /= max(||cmask||_2, 1e-12)
__global__ __launch_bounds__(64) void k_cnorm(float* __restrict__ cmask) {
  int b = blockIdx.x, lane = threadIdx.x;   // 64 threads
  float v[4]; float s = 0.f;
#pragma unroll
  for (int j = 0; j < 4; ++j) {
    int l = lane + 64 * j;
    float x = (l < L) ? cmask[b * L + l] : 0.f;
    v[j] = x; s += x * x;
  }
  for (int off = 1; off < 64; off <<= 1) s += __shfl_xor(s, off, 64);
  float inv = 1.f / fmaxf(sqrtf(s), 1e-12f);
#pragma unroll
  for (int j = 0; j < 4; ++j) {
    int l = lane + 64 * j;
    if (l < L) cmask[b * L + l] = v[j] * inv;
  }
}

// ------------------------------- update[l,:] = sum over edge list w * hidden[m]
__global__ __launch_bounds__(128) void k_update(const float* __restrict__ P,
                                                const unsigned char* __restrict__ ET,
                                                const int* __restrict__ cnt,
                                                const float* __restrict__ hidden,
                                                float* __restrict__ upd) {
  int row = blockIdx.x; int h = threadIdx.x;
  int b = row / L;
  size_t base = (size_t)row * L;
  int n = cnt[row];
  float acc = 0.f;
  for (int e = 0; e < n; ++e) {
    int m = ET[base + e];
    float w = P[base + e];
    acc += w * hidden[(size_t)(b * L + m) * H + h];
  }
  upd[(size_t)row * H + h] = acc;
}

// ----------- FFN + residual + LN, weighted by cmask, in-place on upd (32 rows)
__global__ __launch_bounds__(256) void k_ffn(float* __restrict__ upd,
                                             const float* __restrict__ W1,
                                             const float* __restrict__ b1,
                                             const float* __restrict__ W2,
                                             const float* __restrict__ b2,
                                             const float* __restrict__ g,
                                             const float* __restrict__ beta,
                                             const float* __restrict__ cmask) {
  __shared__ float xs[32][132];
  __shared__ float ps[32][132];
  __shared__ float mus[32], rsd[32];
  int row0 = blockIdx.x * 32;
  int tid = threadIdx.x;
  int hg = tid & 31, rg = tid >> 5;        // 32 col-groups x 8 row-groups
#pragma unroll
  for (int it = 0; it < 4; ++it) {
    int t = tid + it * 256;
    int r = t >> 5, c4 = t & 31;
    float4 v = *(const float4*)&upd[(size_t)(row0 + r) * H + c4 * 4];
    *(float4*)&xs[r][c4 * 4] = v;
  }
  __syncthreads();
  float acc[4][4];
  {
    float4 bv = *(const float4*)&b1[hg * 4];
#pragma unroll
    for (int i = 0; i < 4; ++i) {
      acc[i][0] = bv.x; acc[i][1] = bv.y; acc[i][2] = bv.z; acc[i][3] = bv.w;
    }
  }
#pragma unroll 4
  for (int k4 = 0; k4 < 32; ++k4) {
    float4 wv[4];
#pragma unroll
    for (int q = 0; q < 4; ++q) wv[q] = *(const float4*)&W1[(size_t)(k4 * 4 + q) * H + hg * 4];
    float4 a4[4];
#pragma unroll
    for (int i = 0; i < 4; ++i) a4[i] = *(const float4*)&xs[rg * 4 + i][k4 * 4];
#pragma unroll
    for (int i = 0; i < 4; ++i) {
      float ax[4] = {a4[i].x, a4[i].y, a4[i].z, a4[i].w};
#pragma unroll
      for (int q = 0; q < 4; ++q) {
        acc[i][0] = fmaf(ax[q], wv[q].x, acc[i][0]);
        acc[i][1] = fmaf(ax[q], wv[q].y, acc[i][1]);
        acc[i][2] = fmaf(ax[q], wv[q].z, acc[i][2]);
        acc[i][3] = fmaf(ax[q], wv[q].w, acc[i][3]);
      }
    }
  }
#pragma unroll
  for (int i = 0; i < 4; ++i) {
    float4 f = make_float4(fmaxf(acc[i][0], 0.f), fmaxf(acc[i][1], 0.f),
                           fmaxf(acc[i][2], 0.f), fmaxf(acc[i][3], 0.f));
    *(float4*)&ps[rg * 4 + i][hg * 4] = f;
  }
  __syncthreads();
  float acc2[4][4];
  {
    float4 bv = *(const float4*)&b2[hg * 4];
#pragma unroll
    for (int i = 0; i < 4; ++i) {
      float4 xv = *(const float4*)&xs[rg * 4 + i][hg * 4];
      acc2[i][0] = bv.x + xv.x; acc2[i][1] = bv.y + xv.y;
      acc2[i][2] = bv.z + xv.z; acc2[i][3] = bv.w + xv.w;
    }
  }
#pragma unroll 4
  for (int k4 = 0; k4 < 32; ++k4) {
    float4 wv[4];
#pragma unroll
    for (int q = 0; q < 4; ++q) wv[q] = *(const float4*)&W2[(size_t)(k4 * 4 + q) * H + hg * 4];
    float4 a4[4];
#pragma unroll
    for (int i = 0; i < 4; ++i) a4[i] = *(const float4*)&ps[rg * 4 + i][k4 * 4];
#pragma unroll
    for (int i = 0; i < 4; ++i) {
      float ax[4] = {a4[i].x, a4[i].y, a4[i].z, a4[i].w};
#pragma unroll
      for (int q = 0; q < 4; ++q) {
        acc2[i][0] = fmaf(ax[q], wv[q].x, acc2[i][0]);
        acc2[i][1] = fmaf(ax[q], wv[q].y, acc2[i][1]);
        acc2[i][2] = fmaf(ax[q], wv[q].z, acc2[i][2]);
        acc2[i][3] = fmaf(ax[q], wv[q].w, acc2[i][3]);
      }
    }
  }
  __syncthreads();                          // all reads of f1 done
#pragma unroll
  for (int i = 0; i < 4; ++i) {
    float4 f = make_float4(acc2[i][0], acc2[i][1], acc2[i][2], acc2[i][3]);
    *(float4*)&ps[rg * 4 + i][hg * 4] = f;  // pre
  }
  __syncthreads();
  {
    int r = tid >> 3, sub = tid & 7;
    float s = 0.f, sq = 0.f;
#pragma unroll
    for (int t2 = 0; t2 < 16; ++t2) {
      float x = ps[r][sub * 16 + t2];
      s += x; sq += x * x;
    }
    for (int off = 1; off < 8; off <<= 1) {
      s += __shfl_down(s, off, 8);
      sq += __shfl_down(sq, off, 8);
    }
    if (sub == 0) {
      float mu = s * (1.f / 128.f);
      float var = sq * (1.f / 128.f) - mu * mu;
      mus[r] = mu;
      rsd[r] = rsqrtf(var + 1e-5f);
    }
  }
  __syncthreads();
  {
    float4 g4 = *(const float4*)&g[hg * 4];
    float4 be4 = *(const float4*)&beta[hg * 4];
#pragma unroll
    for (int i = 0; i < 4; ++i) {
      int r = rg * 4 + i;
      float cm = cmask[row0 + r];
      float mu = mus[r], rs = rsd[r];
      float4 o;
      o.x = ((acc2[i][0] - mu) * rs * g4.x + be4.x) * cm;
      o.y = ((acc2[i][1] - mu) * rs * g4.y + be4.y) * cm;
      o.z = ((acc2[i][2] - mu) * rs * g4.z + be4.z) * cm;
      o.w = ((acc2[i][3] - mu) * rs * g4.w + be4.w) * cm;
      *(float4*)&upd[(size_t)(row0 + r) * H + hg * 4] = o;
    }
  }
}

// ---------------------------------------------- ecacc += sum_l (weighted feed2)
__global__ __launch_bounds__(128) void k_ecadd(const float* __restrict__ wf,
                                               float* __restrict__ ecacc) {
  int b = blockIdx.x, h = threadIdx.x;
  float s = 0.f;
  for (int l = 0; l < L; ++l) s += wf[(size_t)(b * L + l) * H + h];
  ecacc[b * H + h] += s;
}

// -------------------------------------------------------- gate -> sess, extras
__global__ __launch_bounds__(128) void k_gate(const float* __restrict__ ecacc,
                                              const float* __restrict__ e_s,
                                              const float* __restrict__ gw,
                                              float* __restrict__ sess,
                                              float* __restrict__ out) {
  __shared__ float cat[256];
  int b = blockIdx.x, h = threadIdx.x;
  float ec = ecacc[b * H + h] * (1.f / 3.f);
  float es = e_s[b * H + h];
  cat[h] = ec; cat[128 + h] = es;
  __syncthreads();
  float a = 0.f;
  for (int j = 0; j < 256; ++j) a = fmaf(cat[j], gw[(size_t)j * H + h], a);
  a = 1.f / (1.f + expf(-a));
  sess[b * H + h] = a * ec + (1.f - a) * es;
  if (b == 0 && h == 0) out[(size_t)B * V] = 0.f;   // con_loss
}

// ------------------------------------------------- scores = sess @ emb^T (NT)
__global__ __launch_bounds__(256) void k_scores(const float* __restrict__ sess,
                                                const float* __restrict__ emb,
                                                float* __restrict__ out) {
  __shared__ float As[64][65], Bs[64][65];
  int n0 = blockIdx.x * 64, m0 = blockIdx.y * 64;
  int tid = threadIdx.x, tx = tid & 15, ty = tid >> 4;
  int tx4 = tx * 4, ty4 = ty * 4;
  float acc[4][4] = {};
  for (int kc = 0; kc < H; kc += 64) {
#pragma unroll
    for (int it = 0; it < 4; ++it) {
      int r = it * 16 + ty, c4 = tx4;
      float4 av = *(const float4*)&sess[(size_t)(m0 + r) * H + kc + c4];
      As[r][c4 + 0] = av.x; As[r][c4 + 1] = av.y; As[r][c4 + 2] = av.z; As[r][c4 + 3] = av.w;
      float4 bv = make_float4(0.f, 0.f, 0.f, 0.f);
      if (n0 + r < V) bv = *(const float4*)&emb[(size_t)(n0 + r) * H + kc + c4];
      Bs[r][c4 + 0] = bv.x; Bs[r][c4 + 1] = bv.y; Bs[r][c4 + 2] = bv.z; Bs[r][c4 + 3] = bv.w;
    }
    __syncthreads();
#pragma unroll 8
    for (int kk = 0; kk < 64; ++kk) {
      float a[4], bb[4];
#pragma unroll
      for (int i = 0; i < 4; ++i) a[i] = As[ty4 + i][kk];
#pragma unroll
      for (int j = 0; j < 4; ++j) bb[j] = Bs[tx4 + j][kk];
#pragma unroll
      for (int i = 0; i < 4; ++i)
#pragma unroll
        for (int j = 0; j < 4; ++j) acc[i][j] = fmaf(a[i], bb[j], acc[i][j]);
    }
    __syncthreads();
  }
#pragma unroll
  for (int i = 0; i < 4; ++i) {
    int m = m0 + ty4 + i;
#pragma unroll
    for (int j = 0; j < 4; ++j) {
      int n = n0 + tx4 + j;
      if (n < V) out[(size_t)m * V + n] = acc[i][j];
    }
  }
}

extern "C" void kernel_launch(void* const* d_in, const int* in_sizes, int n_in,
                              void* d_out, int out_size, void* d_ws, size_t ws_size,
                              hipStream_t stream) {
  const int*   seq  = (const int*)d_in[0];
  const int*   lens = (const int*)d_in[1];
  const int*   rev  = (const int*)d_in[2];
  const float* emb  = (const float*)d_in[3];
  const float* wnz  = (const float*)d_in[4];
  const float* clw  = (const float*)d_in[5];
  const float* w1   = (const float*)d_in[6];
  const float* fb1  = (const float*)d_in[7];
  const float* w2   = (const float*)d_in[8];
  const float* fb2  = (const float*)d_in[9];
  const float* lng  = (const float*)d_in[10];
  const float* lnb  = (const float*)d_in[11];
  const float* gw   = (const float*)d_in[12];
  const float* coff = (const float*)d_in[13];
  float* out = (float*)d_out;

  char* ws = (char*)d_ws;
  size_t off = 0;
  auto alloc = [&](size_t bytes) {
    void* p = ws + off;
    off += (bytes + 255) & ~(size_t)255;
    return p;
  };
  float* hidden = (float*)alloc((size_t)B * L * H * 4);
  float* nrm    = (float*)alloc((size_t)B * L * 4);
  float* S0     = (float*)alloc((size_t)B * L * L * 4);
  float* WS     = (float*)alloc((size_t)B * L * L * 4);
  float* P      = (float*)alloc((size_t)B * L * L * 4);
  float* upd    = (float*)alloc((size_t)B * L * H * 4);
  float* cmask  = (float*)alloc((size_t)B * L * 4);
  int*   cnt    = (int*)alloc((size_t)B * L * 4);
  float* e_s    = (float*)alloc((size_t)B * H * 4);
  float* ecacc  = (float*)alloc((size_t)B * H * 4);
  float* sess   = (float*)alloc((size_t)B * H * 4);
  unsigned char* ET = (unsigned char*)alloc((size_t)B * L * L);
  s16x8* hbh = (s16x8*)alloc((size_t)B * 7 * 8 * 64 * 16);   // frag-linear
  s16x8* wnh = (s16x8*)alloc((size_t)B * 7 * 8 * 64 * 16);
  // lo-residual staging aliases P/upd (first written only inside the layer loop,
  // strictly after k_simws has consumed the staging buffers)
  s16x8* hbl = (s16x8*)P;
  s16x8* wnl = (s16x8*)upd;

  k_embed<<<B * 7, 256, 0, stream>>>(seq, rev, emb, wnz, hidden, nrm,
                                     hbh, hbl, wnh, wnl);
  k_init<<<B, 128, 0, stream>>>(lens, hidden, ecacc, e_s);
  k_simws<<<B * 7, 256, 0, stream>>>(hbh, hbl, wnh, wnl, nrm, rev, clw, S0, WS);

  for (int i = 0; i < 2; ++i) {
    hipMemsetAsync(ET, 0, (size_t)B * L * L, stream);
    k_rowpass<<<B * 13, 256, 0, stream>>>(S0, WS, coff + (size_t)i * B * L * L,
                                          lens, P, ET);
    k_compact<<<B * L / 4, 256, 0, stream>>>(P, ET, cmask, cnt);
    k_cnorm<<<B, 64, 0, stream>>>(cmask);
    k_update<<<B * L, 128, 0, stream>>>(P, ET, cnt, hidden, upd);
    k_ffn<<<B * L / 32, 256, 0, stream>>>(upd, w1, fb1, w2, fb2, lng, lnb, cmask);
    k_ecadd<<<B, 128, 0, stream>>>(upd, ecacc);
  }

  k_gate<<<B, 128, 0, stream>>>(ecacc, e_s, gw, sess, out);
  k_scores<<<dim3((V + 63) / 64, 4), 256, 0, stream>>>(sess, emb, out);
}

// Round 5
// 591.569 us; speedup vs baseline: 1.5142x; 1.1639x over previous
//
#include <hip/hip_runtime.h>
#include <cstdint>
#include <cstddef>

namespace {
constexpr int B = 256, L = 200, H = 128, V = 50000, TK = 20;
constexpr float NEGV = -1e10f;
}

using bf16x8 = __attribute__((ext_vector_type(8))) short;
using s16x8  = __attribute__((ext_vector_type(8))) short;
using f32x16 = __attribute__((ext_vector_type(16))) float;

__device__ inline unsigned short f2bf(float f) {
  unsigned int u = __float_as_uint(f);
  unsigned int r = (u + 0x7fffu + ((u >> 16) & 1u)) >> 16;   // RNE
  return (unsigned short)r;
}

// ---- 16-lane-group DPP reductions ------------------------------------------
#define DPP_QUAD_XOR1 0xB1
#define DPP_QUAD_XOR2 0x4E
#define DPP_ROW_HMIRR 0x141
#define DPP_ROW_MIRR  0x140

template <int CTRL>
__device__ inline unsigned dpp16_max_step(unsigned v) {
  unsigned t = (unsigned)__builtin_amdgcn_update_dpp(0, (int)v, CTRL, 0xF, 0xF, true);
  return v > t ? v : t;
}
__device__ inline unsigned grp16_max(unsigned v) {
  v = dpp16_max_step<DPP_QUAD_XOR1>(v);
  v = dpp16_max_step<DPP_QUAD_XOR2>(v);
  v = dpp16_max_step<DPP_ROW_HMIRR>(v);
  v = dpp16_max_step<DPP_ROW_MIRR>(v);
  return v;                                   // uniform within each 16-group
}
template <int CTRL>
__device__ inline float dpp16_add_step(float v) {
  int t = __builtin_amdgcn_update_dpp(0, __float_as_int(v), CTRL, 0xF, 0xF, true);
  return v + __int_as_float(t);
}
__device__ inline float grp16_sum(float v) {
  v = dpp16_add_step<DPP_QUAD_XOR1>(v);
  v = dpp16_add_step<DPP_QUAD_XOR2>(v);
  v = dpp16_add_step<DPP_ROW_HMIRR>(v);
  v = dpp16_add_step<DPP_ROW_MIRR>(v);
  return v;
}

__device__ inline unsigned f2key(float f) {        // order-preserving, bijective
  unsigned b = __float_as_uint(f);
  unsigned m = (unsigned)((int)b >> 31);
  return b ^ (m | 0x80000000u);
}
__device__ inline float key2f(unsigned u) {
  unsigned b = (u & 0x80000000u) ? (u & 0x7fffffffu) : ~u;
  return __uint_as_float(b);
}

// ---- embed + norm + frag-linear bf16 hi/lo staging --------------------------
__global__ __launch_bounds__(256) void k_embed(const int* __restrict__ seq,
                                               const int* __restrict__ rev,
                                               const float* __restrict__ emb,
                                               const float* __restrict__ wnoise,
                                               float* __restrict__ hidden,
                                               float* __restrict__ nrm,
                                               s16x8* __restrict__ hbh,
                                               s16x8* __restrict__ hbl,
                                               s16x8* __restrict__ wnh,
                                               s16x8* __restrict__ wnl) {
  int b = blockIdx.x / 7, lt = blockIdx.x % 7;
  int t = threadIdx.x;
  int r = t >> 3, c2 = t & 7;                 // row-in-tile, 16-elem h-chunk
  int l = lt * 32 + r;
  bool valid = l < L;
  float vv[16], wv[16];
  if (valid) {
    int row = b * L + l;
    int tok = seq[row];
    const float4* ep = (const float4*)&emb[(size_t)tok * H + c2 * 16];
    const float4* wp = (const float4*)&wnoise[(size_t)rev[row] * H + c2 * 16];
#pragma unroll
    for (int i = 0; i < 4; ++i) {
      float4 x = ep[i];
      vv[i * 4 + 0] = x.x; vv[i * 4 + 1] = x.y; vv[i * 4 + 2] = x.z; vv[i * 4 + 3] = x.w;
      float4 y = wp[i];
      wv[i * 4 + 0] = y.x; wv[i * 4 + 1] = y.y; wv[i * 4 + 2] = y.z; wv[i * 4 + 3] = y.w;
    }
  } else {
#pragma unroll
    for (int i = 0; i < 16; ++i) { vv[i] = 0.f; wv[i] = 0.f; }
  }
  if (valid) {
    int row = b * L + l;
#pragma unroll
    for (int i = 0; i < 4; ++i)
      *(float4*)&hidden[(size_t)row * H + c2 * 16 + i * 4] =
          make_float4(vv[i * 4], vv[i * 4 + 1], vv[i * 4 + 2], vv[i * 4 + 3]);
    float s = 0.f;
#pragma unroll
    for (int i = 0; i < 16; ++i) s += vv[i] * vv[i];
    s += __shfl_down(s, 4, 8);
    s += __shfl_down(s, 2, 8);
    s += __shfl_down(s, 1, 8);
    if (c2 == 0) nrm[row] = sqrtf(s);
  }
  s16x8 h0, h1, l0, l1, w0, w1, x0, x1;
#pragma unroll
  for (int i = 0; i < 8; ++i) {
    unsigned short hi = f2bf(vv[i]);
    h0[i] = (short)hi;
    l0[i] = (short)f2bf(vv[i] - __uint_as_float((unsigned)hi << 16));
    unsigned short wh = f2bf(wv[i]);
    w0[i] = (short)wh;
    x0[i] = (short)f2bf(wv[i] - __uint_as_float((unsigned)wh << 16));
  }
#pragma unroll
  for (int i = 0; i < 8; ++i) {
    unsigned short hi = f2bf(vv[8 + i]);
    h1[i] = (short)hi;
    l1[i] = (short)f2bf(vv[8 + i] - __uint_as_float((unsigned)hi << 16));
    unsigned short wh = f2bf(wv[8 + i]);
    w1[i] = (short)wh;
    x1[i] = (short)f2bf(wv[8 + i] - __uint_as_float((unsigned)wh << 16));
  }
  size_t fi0 = ((size_t)(b * 7 + lt) * 8 + c2) * 64 + r;   // kh=0
  size_t fi1 = fi0 + 32;                                   // kh=1
  hbh[fi0] = h0; hbh[fi1] = h1;
  hbl[fi0] = l0; hbl[fi1] = l1;
  wnh[fi0] = w0; wnh[fi1] = w1;
  wnl[fi0] = x0; wnl[fi1] = x1;
}

// ------------------------------------------ slen, zero_layer (into ecacc), e_s
__global__ __launch_bounds__(512) void k_init(const int* __restrict__ lengths,
                                              const float* __restrict__ hidden,
                                              float* __restrict__ ecacc,
                                              float* __restrict__ e_s) {
  int b = blockIdx.x, tid = threadIdx.x;
  __shared__ float part[4][128];
  __shared__ int wcnt[8];
  __shared__ int s_slen;
  int c = (tid < L && lengths[b * L + tid] > 0) ? 1 : 0;
  for (int o = 32; o > 0; o >>= 1) c += __shfl_down(c, o, 64);
  if ((tid & 63) == 0) wcnt[tid >> 6] = c;
  __syncthreads();
  if (tid == 0) {
    int s = 0;
#pragma unroll
    for (int i = 0; i < 8; ++i) s += wcnt[i];
    s_slen = s;
  }
  int h = tid & 127, seg = tid >> 7;
  float s = 0.f;
  for (int l = seg; l < L; l += 4) s += hidden[(size_t)(b * L + l) * H + h];
  part[seg][h] = s;
  __syncthreads();
  if (tid < 128) {
    float tot = part[0][h] + part[1][h] + part[2][h] + part[3][h];
    int slen = s_slen;
    ecacc[b * H + h] = tot / (float)slen;
    e_s[b * H + h] = hidden[(size_t)(b * L + slen - 1) * H + h];
  }
}

// ---- S0 = cosine sim (+diag), WS = softplus(hidden·wn), bf16x3 split MFMA ---
__global__ __launch_bounds__(256) void k_simws(const s16x8* __restrict__ hbh,
                                               const s16x8* __restrict__ hbl,
                                               const s16x8* __restrict__ wnh,
                                               const s16x8* __restrict__ wnl,
                                               const float* __restrict__ nrm,
                                               const int* __restrict__ rev,
                                               const float* __restrict__ cluster,
                                               float* __restrict__ S0,
                                               float* __restrict__ WS) {
  int orig = blockIdx.x;                     // 0..1791 (= 8 XCD * 32 b * 7 lt)
  int xcd = orig & 7, slot = orig >> 3;
  int b = xcd * 32 + slot / 7, lt = slot % 7;
  int wid = threadIdx.x >> 6, lane = threadIdx.x & 63;
  int lr = lane & 31, kh = lane >> 5;
  size_t abase = ((size_t)(b * 7 + lt) * 8) * 64 + lane;
  bf16x8 ah[8], al[8];
#pragma unroll
  for (int ks = 0; ks < 8; ++ks) {
    ah[ks] = (bf16x8)hbh[abase + ks * 64];
    al[ks] = (bf16x8)hbl[abase + ks * 64];
  }
  for (int mt = wid; mt < 7; mt += 4) {
    size_t bbase = ((size_t)(b * 7 + mt) * 8) * 64 + lane;
    f32x16 accs = {}, accw = {};
#pragma unroll
    for (int ks = 0; ks < 8; ++ks) {
      bf16x8 bhh = (bf16x8)hbh[bbase + ks * 64];
      bf16x8 bhl = (bf16x8)hbl[bbase + ks * 64];
      bf16x8 bwh = (bf16x8)wnh[bbase + ks * 64];
      bf16x8 bwl = (bf16x8)wnl[bbase + ks * 64];
      accs = __builtin_amdgcn_mfma_f32_32x32x16_bf16(ah[ks], bhh, accs, 0, 0, 0);
      accs = __builtin_amdgcn_mfma_f32_32x32x16_bf16(ah[ks], bhl, accs, 0, 0, 0);
      accs = __builtin_amdgcn_mfma_f32_32x32x16_bf16(al[ks], bhh, accs, 0, 0, 0);
      accw = __builtin_amdgcn_mfma_f32_32x32x16_bf16(ah[ks], bwh, accw, 0, 0, 0);
      accw = __builtin_amdgcn_mfma_f32_32x32x16_bf16(ah[ks], bwl, accw, 0, 0, 0);
      accw = __builtin_amdgcn_mfma_f32_32x32x16_bf16(al[ks], bwh, accw, 0, 0, 0);
    }
    int m = mt * 32 + lr;
    if (m < L) {
      float nm = nrm[b * L + m];
#pragma unroll
      for (int r = 0; r < 16; ++r) {
        int row = lt * 32 + (r & 3) + 8 * (r >> 2) + 4 * kh;
        if (row < L) {
          float nl = nrm[b * L + row];
          float s0 = accs[r] * __builtin_amdgcn_rcpf(nl * nm + 1e-6f);
          if (row == m) s0 += cluster[rev[b * L + row]];
          size_t o = (size_t)(b * L + row) * L + m;
          S0[o] = s0;
          float x = accw[r];
          WS[o] = (x > 1.f) ? x : __logf(1.f + __expf(x));
        }
      }
    }
  }
}

// ------- per row: msim in regs (13/lane over 16 lanes), DPP16 top-K, softmax
__global__ __launch_bounds__(256) void k_rowpass(const float* __restrict__ S0,
                                                 const float* __restrict__ WS,
                                                 const float* __restrict__ coff_i,
                                                 const int* __restrict__ lengths,
                                                 float* __restrict__ P,
                                                 unsigned char* __restrict__ ET) {
  int wid = threadIdx.x >> 6, lane = threadIdx.x & 63;
  int g = lane >> 4, q = lane & 15;
  int bb = blockIdx.x / 13, blk = blockIdx.x % 13;
  int l = blk * 16 + wid * 4 + g;
  bool lvalid = l < L;
  int lrow = bb * L + (lvalid ? l : 0);
  bool mask_l = lvalid && (lengths[lrow] > 0);
  size_t base = (size_t)lrow * L;
  float val[13]; unsigned key[13]; unsigned vmask = 0;
#pragma unroll
  for (int j = 0; j < 13; ++j) {
    int m = q + 16 * j;
    float v = 0.f; bool ok = false;
    if (mask_l && m < L) {
      ok = lengths[bb * L + m] > 0;
      if (ok) v = S0[base + m] + coff_i[base + m] * WS[base + m];
    }
    val[j] = v;
    key[j] = ok ? f2key(v) : 0u;
    vmask |= ok ? (1u << j) : 0u;
  }
  unsigned Mu = 0u;
  for (int t = 0; t < TK; ++t) {
    unsigned lv = key[0]; int lj = 0;
#pragma unroll
    for (int j = 1; j < 13; ++j) {
      bool gt = key[j] > lv;
      lv = gt ? key[j] : lv;
      lj = gt ? j : lj;
    }
    unsigned gm = grp16_max(lv);
    if (t == 0) Mu = gm;
    if (__all(gm == 0u)) break;              // all 4 groups exhausted
    unsigned long long bal = __ballot(lv == gm && gm != 0u);
    unsigned long long mine = bal & (0xFFFFull << (g * 16));
    int owner = mine ? (int)__builtin_ctzll(mine) : -1;
    bool is_owner = (lane == owner);         // lowest lane of group (tie ok)
    if (is_owner) {
      int m = q + 16 * lj;
      ET[((size_t)bb * L + m) * L + l] = 1;
    }
#pragma unroll
    for (int j = 0; j < 13; ++j) key[j] = (is_owner && lj == j) ? 0u : key[j];
  }
  // softmax over the row (invalid entries contribute exactly 0)
  float M = key2f(Mu);
  float e[13]; float s = 0.f;
#pragma unroll
  for (int j = 0; j < 13; ++j) {
    float ev = ((vmask >> j) & 1u) ? __expf(val[j] - M) : 0.f;
    e[j] = ev; s += ev;
  }
  s = grp16_sum(s);
  float inv = (s > 0.f) ? __builtin_amdgcn_rcpf(s) : 0.f;
  if (lvalid) {
#pragma unroll
    for (int j = 0; j < 13; ++j) {
      int m = q + 16 * j;
      if (m < L) P[base + m] = e[j] * inv;
    }
  }
}

// ---- ssm row = P * ET, row-sum -> cmask, ordered in-place compaction to lists
__global__ __launch_bounds__(256) void k_compact(float* __restrict__ P,
                                                 unsigned char* __restrict__ ET,
                                                 float* __restrict__ cmask,
                                                 int* __restrict__ cnt) {
  int wid = threadIdx.x >> 6, lane = threadIdx.x & 63;
  int row = blockIdx.x * 4 + wid;
  size_t base = (size_t)row * L;
  float w[4];
  float s = 0.f;
#pragma unroll
  for (int j = 0; j < 4; ++j) {
    int m = lane + 64 * j;
    float ww = 0.f;
    if (m < L) ww = P[base + m] * (float)ET[base + m];
    w[j] = ww; s += ww;
  }
  float ssum = s;
  for (int off = 1; off < 64; off <<= 1) ssum += __shfl_xor(ssum, off, 64);
  if (lane == 0) cmask[row] = ssum;
  int pos_base = 0;
#pragma unroll
  for (int j = 0; j < 4; ++j) {
    bool nz = (w[j] != 0.f);
    unsigned long long mk = __ballot(nz);
    int rank = __popcll(mk & ((1ull << lane) - 1ull));
    if (nz) {
      int pos = pos_base + rank;
      ET[base + pos] = (unsigned char)(lane + 64 * j);
      P[base + pos] = w[j];
    }
    pos_base += (int)__popcll(mk);
  }
  if (lane == 0) cnt[row] = pos_base;
}

// -------------------------------------------- cmask /= max(||cmask||_2, 1e-12)
__global__ __launch_bounds__(64) void k_cnorm(float* __restrict__ cmask) {
  int b = blockIdx.x, lane = threadIdx.x;   // 64 threads
  float v[4]; float s = 0.f;
#pragma unroll
  for (int j = 0; j < 4; ++j) {
    int l = lane + 64 * j;
    float x = (l < L) ? cmask[b * L + l] : 0.f;
    v[j] = x; s += x * x;
  }
  for (int off = 1; off < 64; off <<= 1) s += __shfl_xor(s, off, 64);
  float inv = 1.f / fmaxf(sqrtf(s), 1e-12f);
#pragma unroll
  for (int j = 0; j < 4; ++j) {
    int l = lane + 64 * j;
    if (l < L) cmask[b * L + l] = v[j] * inv;
  }
}

// ------------------------------- update[l,:] = sum over edge list w * hidden[m]
__global__ __launch_bounds__(128) void k_update(const float* __restrict__ P,
                                                const unsigned char* __restrict__ ET,
                                                const int* __restrict__ cnt,
                                                const float* __restrict__ hidden,
                                                float* __restrict__ upd) {
  int row = blockIdx.x; int h = threadIdx.x;
  int b = row / L;
  size_t base = (size_t)row * L;
  int n = cnt[row];
  float acc = 0.f;
  for (int e = 0; e < n; ++e) {
    int m = ET[base + e];
    float w = P[base + e];
    acc += w * hidden[(size_t)(b * L + m) * H + h];
  }
  upd[(size_t)row * H + h] = acc;
}

// ----- FFN + residual + LN via bf16x3 MFMA, weighted by cmask, in-place ------
// 64 rows/block, 4 waves, wave w owns cols n0=w*32. 32x32x16 MFMA.
__global__ __launch_bounds__(256) void k_ffn(float* __restrict__ upd,
                                             const float* __restrict__ W1,
                                             const float* __restrict__ b1,
                                             const float* __restrict__ W2,
                                             const float* __restrict__ b2,
                                             const float* __restrict__ g,
                                             const float* __restrict__ beta,
                                             const float* __restrict__ cmask) {
  constexpr int AS = 136;                            // short stride (16B-aligned rows)
  __shared__ __align__(16) char smem[4 * 64 * AS * 2];  // 69632 B
  short* ahs = (short*)smem;                         // A hi  [64][AS]
  short* als = ahs + 64 * AS;                        // A lo
  short* f1h = (short*)(smem + 2 * 64 * AS * 2);     // feed1 hi
  short* f1l = f1h + 64 * AS;
  float (*ps)[132] = (float (*)[132])smem;           // aliases A (dead after GEMM1)
  __shared__ float mus[64], rsd[64];
  int row0 = blockIdx.x * 64;
  int tid = threadIdx.x;
  int wid = tid >> 6, lane = tid & 63;
  int lr = lane & 31, kh = lane >> 5;
  int n0 = wid * 32;
  int n = n0 + lr;
  // ---- stage upd -> bf16 hi/lo LDS ----
#pragma unroll
  for (int it = 0; it < 8; ++it) {
    int f = it * 256 + tid;
    int r = f >> 5, c4 = (f & 31) * 4;
    float4 v = *(const float4*)&upd[(size_t)(row0 + r) * H + c4];
    float vv[4] = {v.x, v.y, v.z, v.w};
    unsigned short hh[4]; short ll[4];
#pragma unroll
    for (int q2 = 0; q2 < 4; ++q2) {
      hh[q2] = f2bf(vv[q2]);
      ll[q2] = (short)f2bf(vv[q2] - __uint_as_float((unsigned)hh[q2] << 16));
    }
    uint2 ph = make_uint2((unsigned)hh[0] | ((unsigned)hh[1] << 16),
                          (unsigned)hh[2] | ((unsigned)hh[3] << 16));
    uint2 pl = make_uint2((unsigned short)ll[0] | ((unsigned)(unsigned short)ll[1] << 16),
                          (unsigned short)ll[2] | ((unsigned)(unsigned short)ll[3] << 16));
    *(uint2*)&ahs[r * AS + c4] = ph;
    *(uint2*)&als[r * AS + c4] = pl;
  }
  __syncthreads();
  // ---- W1 fragments ----
  bf16x8 wfh[8], wfl[8];
#pragma unroll
  for (int ks = 0; ks < 8; ++ks) {
#pragma unroll
    for (int i = 0; i < 8; ++i) {
      float w = W1[(size_t)(ks * 16 + kh * 8 + i) * H + n];
      unsigned short hi = f2bf(w);
      wfh[ks][i] = (short)hi;
      wfl[ks][i] = (short)f2bf(w - __uint_as_float((unsigned)hi << 16));
    }
  }
  // ---- GEMM1: feed1 = relu(upd @ W1 + b1) ----
  f32x16 acc0, acc1;
  {
    float bv = b1[n];
#pragma unroll
    for (int r = 0; r < 16; ++r) { acc0[r] = bv; acc1[r] = bv; }
  }
#pragma unroll
  for (int ks = 0; ks < 8; ++ks) {
    bf16x8 xh0 = *(const bf16x8*)&ahs[(0 * 32 + lr) * AS + ks * 16 + kh * 8];
    bf16x8 xl0 = *(const bf16x8*)&als[(0 * 32 + lr) * AS + ks * 16 + kh * 8];
    bf16x8 xh1 = *(const bf16x8*)&ahs[(1 * 32 + lr) * AS + ks * 16 + kh * 8];
    bf16x8 xl1 = *(const bf16x8*)&als[(1 * 32 + lr) * AS + ks * 16 + kh * 8];
    acc0 = __builtin_amdgcn_mfma_f32_32x32x16_bf16(xh0, wfh[ks], acc0, 0, 0, 0);
    acc0 = __builtin_amdgcn_mfma_f32_32x32x16_bf16(xl0, wfh[ks], acc0, 0, 0, 0);
    acc0 = __builtin_amdgcn_mfma_f32_32x32x16_bf16(xh0, wfl[ks], acc0, 0, 0, 0);
    acc1 = __builtin_amdgcn_mfma_f32_32x32x16_bf16(xh1, wfh[ks], acc1, 0, 0, 0);
    acc1 = __builtin_amdgcn_mfma_f32_32x32x16_bf16(xl1, wfh[ks], acc1, 0, 0, 0);
    acc1 = __builtin_amdgcn_mfma_f32_32x32x16_bf16(xh1, wfl[ks], acc1, 0, 0, 0);
  }
  // relu -> f1 hi/lo LDS (C layout: row=(r&3)+8*(r>>2)+4*kh, col=n)
#pragma unroll
  for (int r = 0; r < 16; ++r) {
    int crow = (r & 3) + 8 * (r >> 2) + 4 * kh;
    float f0 = fmaxf(acc0[r], 0.f);
    unsigned short h0 = f2bf(f0);
    f1h[crow * AS + n] = (short)h0;
    f1l[crow * AS + n] = (short)f2bf(f0 - __uint_as_float((unsigned)h0 << 16));
    float f1v = fmaxf(acc1[r], 0.f);
    unsigned short h1 = f2bf(f1v);
    f1h[(32 + crow) * AS + n] = (short)h1;
    f1l[(32 + crow) * AS + n] = (short)f2bf(f1v - __uint_as_float((unsigned)h1 << 16));
  }
  __syncthreads();                                    // f1 complete; A region dead
  // ---- W2 fragments ----
#pragma unroll
  for (int ks = 0; ks < 8; ++ks) {
#pragma unroll
    for (int i = 0; i < 8; ++i) {
      float w = W2[(size_t)(ks * 16 + kh * 8 + i) * H + n];
      unsigned short hi = f2bf(w);
      wfh[ks][i] = (short)hi;
      wfl[ks][i] = (short)f2bf(w - __uint_as_float((unsigned)hi << 16));
    }
  }
  // ---- GEMM2: pre = feed1 @ W2 + b2 + upd ----
  {
    float bv = b2[n];
#pragma unroll
    for (int r = 0; r < 16; ++r) { acc0[r] = bv; acc1[r] = bv; }
  }
#pragma unroll
  for (int ks = 0; ks < 8; ++ks) {
    bf16x8 xh0 = *(const bf16x8*)&f1h[(0 * 32 + lr) * AS + ks * 16 + kh * 8];
    bf16x8 xl0 = *(const bf16x8*)&f1l[(0 * 32 + lr) * AS + ks * 16 + kh * 8];
    bf16x8 xh1 = *(const bf16x8*)&f1h[(1 * 32 + lr) * AS + ks * 16 + kh * 8];
    bf16x8 xl1 = *(const bf16x8*)&f1l[(1 * 32 + lr) * AS + ks * 16 + kh * 8];
    acc0 = __builtin_amdgcn_mfma_f32_32x32x16_bf16(xh0, wfh[ks], acc0, 0, 0, 0);
    acc0 = __builtin_amdgcn_mfma_f32_32x32x16_bf16(xl0, wfh[ks], acc0, 0, 0, 0);
    acc0 = __builtin_amdgcn_mfma_f32_32x32x16_bf16(xh0, wfl[ks], acc0, 0, 0, 0);
    acc1 = __builtin_amdgcn_mfma_f32_32x32x16_bf16(xh1, wfh[ks], acc1, 0, 0, 0);
    acc1 = __builtin_amdgcn_mfma_f32_32x32x16_bf16(xl1, wfh[ks], acc1, 0, 0, 0);
    acc1 = __builtin_amdgcn_mfma_f32_32x32x16_bf16(xh1, wfl[ks], acc1, 0, 0, 0);
  }
  // residual + write ps (pre) — ps aliases A region (dead since barrier)
#pragma unroll
  for (int r = 0; r < 16; ++r) {
    int crow = (r & 3) + 8 * (r >> 2) + 4 * kh;
    float p0 = acc0[r] + upd[(size_t)(row0 + crow) * H + n];
    float p1 = acc1[r] + upd[(size_t)(row0 + 32 + crow) * H + n];
    acc0[r] = p0; acc1[r] = p1;
    ps[crow][n] = p0;
    ps[32 + crow][n] = p1;
  }
  __syncthreads();
  // ---- LN stats: 4 threads per row ----
  {
    int r = tid >> 2, sub = tid & 3;
    float s = 0.f, sq = 0.f;
#pragma unroll
    for (int j = 0; j < 8; ++j) {
      float4 x = *(const float4*)&ps[r][sub * 32 + j * 4];
      s += x.x + x.y + x.z + x.w;
      sq += x.x * x.x + x.y * x.y + x.z * x.z + x.w * x.w;
    }
    s += __shfl_down(s, 2, 4);  s += __shfl_down(s, 1, 4);
    sq += __shfl_down(sq, 2, 4); sq += __shfl_down(sq, 1, 4);
    if (sub == 0) {
      float mu = s * (1.f / 128.f);
      float var = sq * (1.f / 128.f) - mu * mu;
      mus[r] = mu;
      rsd[r] = rsqrtf(var + 1e-5f);
    }
  }
  __syncthreads();
  // ---- normalize, scale by cmask, write ----
  {
    float gn = g[n], bn = beta[n];
#pragma unroll
    for (int r = 0; r < 16; ++r) {
      int crow = (r & 3) + 8 * (r >> 2) + 4 * kh;
      float o0 = ((acc0[r] - mus[crow]) * rsd[crow] * gn + bn) * cmask[row0 + crow];
      float o1 = ((acc1[r] - mus[32 + crow]) * rsd[32 + crow] * gn + bn) * cmask[row0 + 32 + crow];
      upd[(size_t)(row0 + crow) * H + n] = o0;
      upd[(size_t)(row0 + 32 + crow) * H + n] = o1;
    }
  }
}

// ---------------------------------------------- ecacc += sum_l (weighted feed2)
__global__ __launch_bounds__(128) void k_ecadd(const float* __restrict__ wf,
                                               float* __restrict__ ecacc) {
  int b = blockIdx.x, h = threadIdx.x;
  float s = 0.f;
  for (int l = 0; l < L; ++l) s += wf[(size_t)(b * L + l) * H + h];
  ecacc[b * H + h] += s;
}

// -------------------------------------------------------- gate -> sess, extras
__global__ __launch_bounds__(128) void k_gate(const float* __restrict__ ecacc,
                                              const float* __restrict__ e_s,
                                              const float* __restrict__ gw,
                                              float* __restrict__ sess,
                                              float* __restrict__ out) {
  __shared__ float cat[256];
  int b = blockIdx.x, h = threadIdx.x;
  float ec = ecacc[b * H + h] * (1.f / 3.f);
  float es = e_s[b * H + h];
  cat[h] = ec; cat[128 + h] = es;
  __syncthreads();
  float a = 0.f;
  for (int j = 0; j < 256; ++j) a = fmaf(cat[j], gw[(size_t)j * H + h], a);
  a = 1.f / (1.f + __expf(-a));
  sess[b * H + h] = a * ec + (1.f - a) * es;
  if (b == 0 && h == 0) out[(size_t)B * V] = 0.f;   // con_loss
}

// ------------------------------------------------- scores = sess @ emb^T (NT)
__global__ __launch_bounds__(256) void k_scores(const float* __restrict__ sess,
                                                const float* __restrict__ emb,
                                                float* __restrict__ out) {
  __shared__ float As[64][65], Bs[64][65];
  int n0 = blockIdx.x * 64, m0 = blockIdx.y * 64;
  int tid = threadIdx.x, tx = tid & 15, ty = tid >> 4;
  int tx4 = tx * 4, ty4 = ty * 4;
  float acc[4][4] = {};
  for (int kc = 0; kc < H; kc += 64) {
#pragma unroll
    for (int it = 0; it < 4; ++it) {
      int r = it * 16 + ty, c4 = tx4;
      float4 av = *(const float4*)&sess[(size_t)(m0 + r) * H + kc + c4];
      As[r][c4 + 0] = av.x; As[r][c4 + 1] = av.y; As[r][c4 + 2] = av.z; As[r][c4 + 3] = av.w;
      float4 bv = make_float4(0.f, 0.f, 0.f, 0.f);
      if (n0 + r < V) bv = *(const float4*)&emb[(size_t)(n0 + r) * H + kc + c4];
      Bs[r][c4 + 0] = bv.x; Bs[r][c4 + 1] = bv.y; Bs[r][c4 + 2] = bv.z; Bs[r][c4 + 3] = bv.w;
    }
    __syncthreads();
#pragma unroll 8
    for (int kk = 0; kk < 64; ++kk) {
      float a[4], bb[4];
#pragma unroll
      for (int i = 0; i < 4; ++i) a[i] = As[ty4 + i][kk];
#pragma unroll
      for (int j = 0; j < 4; ++j) bb[j] = Bs[tx4 + j][kk];
#pragma unroll
      for (int i = 0; i < 4; ++i)
#pragma unroll
        for (int j = 0; j < 4; ++j) acc[i][j] = fmaf(a[i], bb[j], acc[i][j]);
    }
    __syncthreads();
  }
#pragma unroll
  for (int i = 0; i < 4; ++i) {
    int m = m0 + ty4 + i;
#pragma unroll
    for (int j = 0; j < 4; ++j) {
      int n = n0 + tx4 + j;
      if (n < V) out[(size_t)m * V + n] = acc[i][j];
    }
  }
}

extern "C" void kernel_launch(void* const* d_in, const int* in_sizes, int n_in,
                              void* d_out, int out_size, void* d_ws, size_t ws_size,
                              hipStream_t stream) {
  const int*   seq  = (const int*)d_in[0];
  const int*   lens = (const int*)d_in[1];
  const int*   rev  = (const int*)d_in[2];
  const float* emb  = (const float*)d_in[3];
  const float* wnz  = (const float*)d_in[4];
  const float* clw  = (const float*)d_in[5];
  const float* w1   = (const float*)d_in[6];
  const float* fb1  = (const float*)d_in[7];
  const float* w2   = (const float*)d_in[8];
  const float* fb2  = (const float*)d_in[9];
  const float* lng  = (const float*)d_in[10];
  const float* lnb  = (const float*)d_in[11];
  const float* gw   = (const float*)d_in[12];
  const float* coff = (const float*)d_in[13];
  float* out = (float*)d_out;

  char* ws = (char*)d_ws;
  size_t off = 0;
  auto alloc = [&](size_t bytes) {
    void* p = ws + off;
    off += (bytes + 255) & ~(size_t)255;
    return p;
  };
  float* hidden = (float*)alloc((size_t)B * L * H * 4);
  float* nrm    = (float*)alloc((size_t)B * L * 4);
  float* S0     = (float*)alloc((size_t)B * L * L * 4);
  float* WS     = (float*)alloc((size_t)B * L * L * 4);
  float* P      = (float*)alloc((size_t)B * L * L * 4);
  float* upd    = (float*)alloc((size_t)B * L * H * 4);
  float* cmask  = (float*)alloc((size_t)B * L * 4);
  int*   cnt    = (int*)alloc((size_t)B * L * 4);
  float* e_s    = (float*)alloc((size_t)B * H * 4);
  float* ecacc  = (float*)alloc((size_t)B * H * 4);
  float* sess   = (float*)alloc((size_t)B * H * 4);
  unsigned char* ET = (unsigned char*)alloc((size_t)B * L * L);
  s16x8* hbh = (s16x8*)alloc((size_t)B * 7 * 8 * 64 * 16);   // frag-linear
  s16x8* wnh = (s16x8*)alloc((size_t)B * 7 * 8 * 64 * 16);
  // lo-residual staging aliases P/upd (first written only inside the layer loop,
  // strictly after k_simws has consumed the staging buffers)
  s16x8* hbl = (s16x8*)P;
  s16x8* wnl = (s16x8*)upd;

  k_embed<<<B * 7, 256, 0, stream>>>(seq, rev, emb, wnz, hidden, nrm,
                                     hbh, hbl, wnh, wnl);
  k_init<<<B, 512, 0, stream>>>(lens, hidden, ecacc, e_s);
  k_simws<<<B * 7, 256, 0, stream>>>(hbh, hbl, wnh, wnl, nrm, rev, clw, S0, WS);

  for (int i = 0; i < 2; ++i) {
    hipMemsetAsync(ET, 0, (size_t)B * L * L, stream);
    k_rowpass<<<B * 13, 256, 0, stream>>>(S0, WS, coff + (size_t)i * B * L * L,
                                          lens, P, ET);
    k_compact<<<B * L / 4, 256, 0, stream>>>(P, ET, cmask, cnt);
    k_cnorm<<<B, 64, 0, stream>>>(cmask);
    k_update<<<B * L, 128, 0, stream>>>(P, ET, cnt, hidden, upd);
    k_ffn<<<B * L / 64, 256, 0, stream>>>(upd, w1, fb1, w2, fb2, lng, lnb, cmask);
    k_ecadd<<<B, 128, 0, stream>>>(upd, ecacc);
  }

  k_gate<<<B, 128, 0, stream>>>(ecacc, e_s, gw, sess, out);
  k_scores<<<dim3((V + 63) / 64, 4), 256, 0, stream>>>(sess, emb, out);
}

// Round 7
// 494.332 us; speedup vs baseline: 1.8120x; 1.1967x over previous
//
#include <hip/hip_runtime.h>
#include <cstdint>
#include <cstddef>

namespace {
constexpr int B = 256, L = 200, H = 128, V = 50000, TK = 20;
constexpr float NEGV = -1e10f;
}

using bf16x8 = __attribute__((ext_vector_type(8))) short;
using s16x8  = __attribute__((ext_vector_type(8))) short;
using f32x16 = __attribute__((ext_vector_type(16))) float;

__device__ inline unsigned short f2bf(float f) {
  unsigned int u = __float_as_uint(f);
  unsigned int r = (u + 0x7fffu + ((u >> 16) & 1u)) >> 16;   // RNE
  return (unsigned short)r;
}

// ---- 16-lane-group DPP reductions ------------------------------------------
#define DPP_QUAD_XOR1 0xB1
#define DPP_QUAD_XOR2 0x4E
#define DPP_ROW_HMIRR 0x141
#define DPP_ROW_MIRR  0x140

template <int CTRL>
__device__ inline unsigned dpp16_max_step(unsigned v) {
  unsigned t = (unsigned)__builtin_amdgcn_update_dpp(0, (int)v, CTRL, 0xF, 0xF, true);
  return v > t ? v : t;
}
__device__ inline unsigned grp16_max(unsigned v) {
  v = dpp16_max_step<DPP_QUAD_XOR1>(v);
  v = dpp16_max_step<DPP_QUAD_XOR2>(v);
  v = dpp16_max_step<DPP_ROW_HMIRR>(v);
  v = dpp16_max_step<DPP_ROW_MIRR>(v);
  return v;                                   // uniform within each 16-group
}
template <int CTRL>
__device__ inline float dpp16_add_step(float v) {
  int t = __builtin_amdgcn_update_dpp(0, __float_as_int(v), CTRL, 0xF, 0xF, true);
  return v + __int_as_float(t);
}
__device__ inline float grp16_sum(float v) {
  v = dpp16_add_step<DPP_QUAD_XOR1>(v);
  v = dpp16_add_step<DPP_QUAD_XOR2>(v);
  v = dpp16_add_step<DPP_ROW_HMIRR>(v);
  v = dpp16_add_step<DPP_ROW_MIRR>(v);
  return v;
}

__device__ inline unsigned f2key(float f) {        // order-preserving, bijective
  unsigned b = __float_as_uint(f);
  unsigned m = (unsigned)((int)b >> 31);
  return b ^ (m | 0x80000000u);
}
__device__ inline float key2f(unsigned u) {
  unsigned b = (u & 0x80000000u) ? (u & 0x7fffffffu) : ~u;
  return __uint_as_float(b);
}

// ---- embed + norm + frag-linear bf16 hi/lo staging --------------------------
__global__ __launch_bounds__(256) void k_embed(const int* __restrict__ seq,
                                               const int* __restrict__ rev,
                                               const float* __restrict__ emb,
                                               const float* __restrict__ wnoise,
                                               float* __restrict__ hidden,
                                               float* __restrict__ nrm,
                                               s16x8* __restrict__ hbh,
                                               s16x8* __restrict__ hbl,
                                               s16x8* __restrict__ wnh,
                                               s16x8* __restrict__ wnl) {
  int b = blockIdx.x / 7, lt = blockIdx.x % 7;
  int t = threadIdx.x;
  int r = t >> 3, c2 = t & 7;                 // row-in-tile, 16-elem h-chunk
  int l = lt * 32 + r;
  bool valid = l < L;
  float vv[16], wv[16];
  if (valid) {
    int row = b * L + l;
    int tok = seq[row];
    const float4* ep = (const float4*)&emb[(size_t)tok * H + c2 * 16];
    const float4* wp = (const float4*)&wnoise[(size_t)rev[row] * H + c2 * 16];
#pragma unroll
    for (int i = 0; i < 4; ++i) {
      float4 x = ep[i];
      vv[i * 4 + 0] = x.x; vv[i * 4 + 1] = x.y; vv[i * 4 + 2] = x.z; vv[i * 4 + 3] = x.w;
      float4 y = wp[i];
      wv[i * 4 + 0] = y.x; wv[i * 4 + 1] = y.y; wv[i * 4 + 2] = y.z; wv[i * 4 + 3] = y.w;
    }
  } else {
#pragma unroll
    for (int i = 0; i < 16; ++i) { vv[i] = 0.f; wv[i] = 0.f; }
  }
  if (valid) {
    int row = b * L + l;
#pragma unroll
    for (int i = 0; i < 4; ++i)
      *(float4*)&hidden[(size_t)row * H + c2 * 16 + i * 4] =
          make_float4(vv[i * 4], vv[i * 4 + 1], vv[i * 4 + 2], vv[i * 4 + 3]);
    float s = 0.f;
#pragma unroll
    for (int i = 0; i < 16; ++i) s += vv[i] * vv[i];
    s += __shfl_down(s, 4, 8);
    s += __shfl_down(s, 2, 8);
    s += __shfl_down(s, 1, 8);
    if (c2 == 0) nrm[row] = sqrtf(s);
  }
  s16x8 h0, h1, l0, l1, w0, w1, x0, x1;
#pragma unroll
  for (int i = 0; i < 8; ++i) {
    unsigned short hi = f2bf(vv[i]);
    h0[i] = (short)hi;
    l0[i] = (short)f2bf(vv[i] - __uint_as_float((unsigned)hi << 16));
    unsigned short wh = f2bf(wv[i]);
    w0[i] = (short)wh;
    x0[i] = (short)f2bf(wv[i] - __uint_as_float((unsigned)wh << 16));
  }
#pragma unroll
  for (int i = 0; i < 8; ++i) {
    unsigned short hi = f2bf(vv[8 + i]);
    h1[i] = (short)hi;
    l1[i] = (short)f2bf(vv[8 + i] - __uint_as_float((unsigned)hi << 16));
    unsigned short wh = f2bf(wv[8 + i]);
    w1[i] = (short)wh;
    x1[i] = (short)f2bf(wv[8 + i] - __uint_as_float((unsigned)wh << 16));
  }
  size_t fi0 = ((size_t)(b * 7 + lt) * 8 + c2) * 64 + r;   // kh=0
  size_t fi1 = fi0 + 32;                                   // kh=1
  hbh[fi0] = h0; hbh[fi1] = h1;
  hbl[fi0] = l0; hbl[fi1] = l1;
  wnh[fi0] = w0; wnh[fi1] = w1;
  wnl[fi0] = x0; wnl[fi1] = x1;
}

// ------------------------------------------ slen, zero_layer (into ecacc), e_s
__global__ __launch_bounds__(512) void k_init(const int* __restrict__ lengths,
                                              const float* __restrict__ hidden,
                                              float* __restrict__ ecacc,
                                              float* __restrict__ e_s) {
  int b = blockIdx.x, tid = threadIdx.x;
  __shared__ float part[4][128];
  __shared__ int wcnt[8];
  __shared__ int s_slen;
  int c = (tid < L && lengths[b * L + tid] > 0) ? 1 : 0;
  for (int o = 32; o > 0; o >>= 1) c += __shfl_down(c, o, 64);
  if ((tid & 63) == 0) wcnt[tid >> 6] = c;
  __syncthreads();
  if (tid == 0) {
    int s = 0;
#pragma unroll
    for (int i = 0; i < 8; ++i) s += wcnt[i];
    s_slen = s;
  }
  int h = tid & 127, seg = tid >> 7;
  float s = 0.f;
  for (int l = seg; l < L; l += 4) s += hidden[(size_t)(b * L + l) * H + h];
  part[seg][h] = s;
  __syncthreads();
  if (tid < 128) {
    float tot = part[0][h] + part[1][h] + part[2][h] + part[3][h];
    int slen = s_slen;
    ecacc[b * H + h] = tot / (float)slen;
    e_s[b * H + h] = hidden[(size_t)(b * L + slen - 1) * H + h];
  }
}

// ---- S0 = cosine sim (+diag), WS = softplus(hidden·wn), bf16x3 split MFMA ---
__global__ __launch_bounds__(256) void k_simws(const s16x8* __restrict__ hbh,
                                               const s16x8* __restrict__ hbl,
                                               const s16x8* __restrict__ wnh,
                                               const s16x8* __restrict__ wnl,
                                               const float* __restrict__ nrm,
                                               const int* __restrict__ rev,
                                               const float* __restrict__ cluster,
                                               float* __restrict__ S0,
                                               float* __restrict__ WS) {
  int orig = blockIdx.x;                     // 0..1791 (= 8 XCD * 32 b * 7 lt)
  int xcd = orig & 7, slot = orig >> 3;
  int b = xcd * 32 + slot / 7, lt = slot % 7;
  int wid = threadIdx.x >> 6, lane = threadIdx.x & 63;
  int lr = lane & 31, kh = lane >> 5;
  size_t abase = ((size_t)(b * 7 + lt) * 8) * 64 + lane;
  bf16x8 ah[8], al[8];
#pragma unroll
  for (int ks = 0; ks < 8; ++ks) {
    ah[ks] = (bf16x8)hbh[abase + ks * 64];
    al[ks] = (bf16x8)hbl[abase + ks * 64];
  }
  for (int mt = wid; mt < 7; mt += 4) {
    size_t bbase = ((size_t)(b * 7 + mt) * 8) * 64 + lane;
    f32x16 accs = {}, accw = {};
#pragma unroll
    for (int ks = 0; ks < 8; ++ks) {
      bf16x8 bhh = (bf16x8)hbh[bbase + ks * 64];
      bf16x8 bhl = (bf16x8)hbl[bbase + ks * 64];
      bf16x8 bwh = (bf16x8)wnh[bbase + ks * 64];
      bf16x8 bwl = (bf16x8)wnl[bbase + ks * 64];
      accs = __builtin_amdgcn_mfma_f32_32x32x16_bf16(ah[ks], bhh, accs, 0, 0, 0);
      accs = __builtin_amdgcn_mfma_f32_32x32x16_bf16(ah[ks], bhl, accs, 0, 0, 0);
      accs = __builtin_amdgcn_mfma_f32_32x32x16_bf16(al[ks], bhh, accs, 0, 0, 0);
      accw = __builtin_amdgcn_mfma_f32_32x32x16_bf16(ah[ks], bwh, accw, 0, 0, 0);
      accw = __builtin_amdgcn_mfma_f32_32x32x16_bf16(ah[ks], bwl, accw, 0, 0, 0);
      accw = __builtin_amdgcn_mfma_f32_32x32x16_bf16(al[ks], bwh, accw, 0, 0, 0);
    }
    int m = mt * 32 + lr;
    if (m < L) {
      float nm = nrm[b * L + m];
#pragma unroll
      for (int r = 0; r < 16; ++r) {
        int row = lt * 32 + (r & 3) + 8 * (r >> 2) + 4 * kh;
        if (row < L) {
          float nl = nrm[b * L + row];
          float s0 = accs[r] * __builtin_amdgcn_rcpf(nl * nm + 1e-6f);
          if (row == m) s0 += cluster[rev[b * L + row]];
          size_t o = (size_t)(b * L + row) * L + m;
          S0[o] = s0;
          float x = accw[r];
          WS[o] = (x > 1.f) ? x : __logf(1.f + __expf(x));
        }
      }
    }
  }
}

// ------- per row: msim in regs (13/lane over 16 lanes), DPP16 top-K, softmax
__global__ __launch_bounds__(256) void k_rowpass(const float* __restrict__ S0,
                                                 const float* __restrict__ WS,
                                                 const float* __restrict__ coff_i,
                                                 const int* __restrict__ lengths,
                                                 float* __restrict__ P,
                                                 unsigned char* __restrict__ ET) {
  int wid = threadIdx.x >> 6, lane = threadIdx.x & 63;
  int g = lane >> 4, q = lane & 15;
  int bb = blockIdx.x / 13, blk = blockIdx.x % 13;
  int l = blk * 16 + wid * 4 + g;
  bool lvalid = l < L;
  int lrow = bb * L + (lvalid ? l : 0);
  bool mask_l = lvalid && (lengths[lrow] > 0);
  size_t base = (size_t)lrow * L;
  float val[13]; unsigned key[13]; unsigned vmask = 0;
#pragma unroll
  for (int j = 0; j < 13; ++j) {
    int m = q + 16 * j;
    float v = 0.f; bool ok = false;
    if (mask_l && m < L) {
      ok = lengths[bb * L + m] > 0;
      if (ok) v = S0[base + m] + coff_i[base + m] * WS[base + m];
    }
    val[j] = v;
    key[j] = ok ? f2key(v) : 0u;
    vmask |= ok ? (1u << j) : 0u;
  }
  unsigned Mu = 0u;
  for (int t = 0; t < TK; ++t) {
    unsigned lv = key[0]; int lj = 0;
#pragma unroll
    for (int j = 1; j < 13; ++j) {
      bool gt = key[j] > lv;
      lv = gt ? key[j] : lv;
      lj = gt ? j : lj;
    }
    unsigned gm = grp16_max(lv);
    if (t == 0) Mu = gm;
    if (__all(gm == 0u)) break;              // all 4 groups exhausted
    unsigned long long bal = __ballot(lv == gm && gm != 0u);
    unsigned long long mine = bal & (0xFFFFull << (g * 16));
    int owner = mine ? (int)__builtin_ctzll(mine) : -1;
    bool is_owner = (lane == owner);         // lowest lane of group (tie ok)
    if (is_owner) {
      int m = q + 16 * lj;
      ET[((size_t)bb * L + m) * L + l] = 1;
    }
#pragma unroll
    for (int j = 0; j < 13; ++j) key[j] = (is_owner && lj == j) ? 0u : key[j];
  }
  // softmax over the row (invalid entries contribute exactly 0)
  float M = key2f(Mu);
  float e[13]; float s = 0.f;
#pragma unroll
  for (int j = 0; j < 13; ++j) {
    float ev = ((vmask >> j) & 1u) ? __expf(val[j] - M) : 0.f;
    e[j] = ev; s += ev;
  }
  s = grp16_sum(s);
  float inv = (s > 0.f) ? __builtin_amdgcn_rcpf(s) : 0.f;
  if (lvalid) {
#pragma unroll
    for (int j = 0; j < 13; ++j) {
      int m = q + 16 * j;
      if (m < L) P[base + m] = e[j] * inv;
    }
  }
}

// ---- ssm row = P * ET, row-sum -> cmask, ordered in-place compaction to lists
__global__ __launch_bounds__(256) void k_compact(float* __restrict__ P,
                                                 unsigned char* __restrict__ ET,
                                                 float* __restrict__ cmask,
                                                 int* __restrict__ cnt) {
  int wid = threadIdx.x >> 6, lane = threadIdx.x & 63;
  int row = blockIdx.x * 4 + wid;
  size_t base = (size_t)row * L;
  float w[4];
  float s = 0.f;
#pragma unroll
  for (int j = 0; j < 4; ++j) {
    int m = lane + 64 * j;
    float ww = 0.f;
    if (m < L) ww = P[base + m] * (float)ET[base + m];
    w[j] = ww; s += ww;
  }
  float ssum = s;
  for (int off = 1; off < 64; off <<= 1) ssum += __shfl_xor(ssum, off, 64);
  if (lane == 0) cmask[row] = ssum;
  int pos_base = 0;
#pragma unroll
  for (int j = 0; j < 4; ++j) {
    bool nz = (w[j] != 0.f);
    unsigned long long mk = __ballot(nz);
    int rank = __popcll(mk & ((1ull << lane) - 1ull));
    if (nz) {
      int pos = pos_base + rank;
      ET[base + pos] = (unsigned char)(lane + 64 * j);
      P[base + pos] = w[j];
    }
    pos_base += (int)__popcll(mk);
  }
  if (lane == 0) cnt[row] = pos_base;
}

// -------------------------------------------- cmask /= max(||cmask||_2, 1e-12)
__global__ __launch_bounds__(64) void k_cnorm(float* __restrict__ cmask) {
  int b = blockIdx.x, lane = threadIdx.x;   // 64 threads
  float v[4]; float s = 0.f;
#pragma unroll
  for (int j = 0; j < 4; ++j) {
    int l = lane + 64 * j;
    float x = (l < L) ? cmask[b * L + l] : 0.f;
    v[j] = x; s += x * x;
  }
  for (int off = 1; off < 64; off <<= 1) s += __shfl_xor(s, off, 64);
  float inv = 1.f / fmaxf(sqrtf(s), 1e-12f);
#pragma unroll
  for (int j = 0; j < 4; ++j) {
    int l = lane + 64 * j;
    if (l < L) cmask[b * L + l] = v[j] * inv;
  }
}

// --- update[l,:] = sum over edge list; chunked batched gather (n can be >TK!)
// n = in-degree of row, up to L. Chunks of 20: load 20 (w,m) pairs, issue 20
// independent gathers, predicated FMA. avg n ~= 20 -> ~1.3 chunks.
__global__ __launch_bounds__(256) void k_update(const float* __restrict__ P,
                                                const unsigned char* __restrict__ ET,
                                                const int* __restrict__ cnt,
                                                const float* __restrict__ hidden,
                                                float* __restrict__ upd) {
  int row = blockIdx.x * 2 + (threadIdx.x >> 7);
  int h = threadIdx.x & 127;
  int b = row / L;
  size_t base = (size_t)row * L;
  int n = cnt[row];
  float acc = 0.f;
  for (int e0 = 0; e0 < n; e0 += TK) {       // e0 multiple of 20, e0+20 <= 200
    float w[TK]; int m[TK];
    float4 p4[5];
#pragma unroll
    for (int i = 0; i < 5; ++i) p4[i] = *(const float4*)&P[base + e0 + i * 4];
#pragma unroll
    for (int i = 0; i < 5; ++i) {
      w[i * 4 + 0] = p4[i].x; w[i * 4 + 1] = p4[i].y;
      w[i * 4 + 2] = p4[i].z; w[i * 4 + 3] = p4[i].w;
    }
#pragma unroll
    for (int e = 0; e < TK; ++e) m[e] = ET[base + e0 + e];
    float hv[TK];
#pragma unroll
    for (int e = 0; e < TK; ++e)
      hv[e] = hidden[(size_t)(b * L + m[e]) * H + h];
#pragma unroll
    for (int e = 0; e < TK; ++e)
      acc += ((e0 + e) < n ? w[e] : 0.f) * hv[e];
  }
  upd[(size_t)row * H + h] = acc;
}

// ----- FFN + residual + LN via bf16x3 MFMA, weighted by cmask, in-place ------
// 64 rows/block, 4 waves, wave w owns cols n0=w*32. 32x32x16 MFMA.
__global__ __launch_bounds__(256) void k_ffn(float* __restrict__ upd,
                                             const float* __restrict__ W1,
                                             const float* __restrict__ b1,
                                             const float* __restrict__ W2,
                                             const float* __restrict__ b2,
                                             const float* __restrict__ g,
                                             const float* __restrict__ beta,
                                             const float* __restrict__ cmask) {
  constexpr int AS = 136;                            // short stride (16B-aligned rows)
  __shared__ __align__(16) char smem[4 * 64 * AS * 2];  // 69632 B
  short* ahs = (short*)smem;                         // A hi  [64][AS]
  short* als = ahs + 64 * AS;                        // A lo
  short* f1h = (short*)(smem + 2 * 64 * AS * 2);     // feed1 hi
  short* f1l = f1h + 64 * AS;
  float (*ps)[132] = (float (*)[132])smem;           // aliases A (dead after GEMM1)
  __shared__ float mus[64], rsd[64];
  int row0 = blockIdx.x * 64;
  int tid = threadIdx.x;
  int wid = tid >> 6, lane = tid & 63;
  int lr = lane & 31, kh = lane >> 5;
  int n0 = wid * 32;
  int n = n0 + lr;
  // ---- stage upd -> bf16 hi/lo LDS ----
#pragma unroll
  for (int it = 0; it < 8; ++it) {
    int f = it * 256 + tid;
    int r = f >> 5, c4 = (f & 31) * 4;
    float4 v = *(const float4*)&upd[(size_t)(row0 + r) * H + c4];
    float vv[4] = {v.x, v.y, v.z, v.w};
    unsigned short hh[4]; short ll[4];
#pragma unroll
    for (int q2 = 0; q2 < 4; ++q2) {
      hh[q2] = f2bf(vv[q2]);
      ll[q2] = (short)f2bf(vv[q2] - __uint_as_float((unsigned)hh[q2] << 16));
    }
    uint2 ph = make_uint2((unsigned)hh[0] | ((unsigned)hh[1] << 16),
                          (unsigned)hh[2] | ((unsigned)hh[3] << 16));
    uint2 pl = make_uint2((unsigned short)ll[0] | ((unsigned)(unsigned short)ll[1] << 16),
                          (unsigned short)ll[2] | ((unsigned)(unsigned short)ll[3] << 16));
    *(uint2*)&ahs[r * AS + c4] = ph;
    *(uint2*)&als[r * AS + c4] = pl;
  }
  __syncthreads();
  // ---- W1 fragments ----
  bf16x8 wfh[8], wfl[8];
#pragma unroll
  for (int ks = 0; ks < 8; ++ks) {
#pragma unroll
    for (int i = 0; i < 8; ++i) {
      float w = W1[(size_t)(ks * 16 + kh * 8 + i) * H + n];
      unsigned short hi = f2bf(w);
      wfh[ks][i] = (short)hi;
      wfl[ks][i] = (short)f2bf(w - __uint_as_float((unsigned)hi << 16));
    }
  }
  // ---- GEMM1: feed1 = relu(upd @ W1 + b1) ----
  f32x16 acc0, acc1;
  {
    float bv = b1[n];
#pragma unroll
    for (int r = 0; r < 16; ++r) { acc0[r] = bv; acc1[r] = bv; }
  }
#pragma unroll
  for (int ks = 0; ks < 8; ++ks) {
    bf16x8 xh0 = *(const bf16x8*)&ahs[(0 * 32 + lr) * AS + ks * 16 + kh * 8];
    bf16x8 xl0 = *(const bf16x8*)&als[(0 * 32 + lr) * AS + ks * 16 + kh * 8];
    bf16x8 xh1 = *(const bf16x8*)&ahs[(1 * 32 + lr) * AS + ks * 16 + kh * 8];
    bf16x8 xl1 = *(const bf16x8*)&als[(1 * 32 + lr) * AS + ks * 16 + kh * 8];
    acc0 = __builtin_amdgcn_mfma_f32_32x32x16_bf16(xh0, wfh[ks], acc0, 0, 0, 0);
    acc0 = __builtin_amdgcn_mfma_f32_32x32x16_bf16(xl0, wfh[ks], acc0, 0, 0, 0);
    acc0 = __builtin_amdgcn_mfma_f32_32x32x16_bf16(xh0, wfl[ks], acc0, 0, 0, 0);
    acc1 = __builtin_amdgcn_mfma_f32_32x32x16_bf16(xh1, wfh[ks], acc1, 0, 0, 0);
    acc1 = __builtin_amdgcn_mfma_f32_32x32x16_bf16(xl1, wfh[ks], acc1, 0, 0, 0);
    acc1 = __builtin_amdgcn_mfma_f32_32x32x16_bf16(xh1, wfl[ks], acc1, 0, 0, 0);
  }
  // relu -> f1 hi/lo LDS (C layout: row=(r&3)+8*(r>>2)+4*kh, col=n)
#pragma unroll
  for (int r = 0; r < 16; ++r) {
    int crow = (r & 3) + 8 * (r >> 2) + 4 * kh;
    float f0 = fmaxf(acc0[r], 0.f);
    unsigned short h0 = f2bf(f0);
    f1h[crow * AS + n] = (short)h0;
    f1l[crow * AS + n] = (short)f2bf(f0 - __uint_as_float((unsigned)h0 << 16));
    float f1v = fmaxf(acc1[r], 0.f);
    unsigned short h1 = f2bf(f1v);
    f1h[(32 + crow) * AS + n] = (short)h1;
    f1l[(32 + crow) * AS + n] = (short)f2bf(f1v - __uint_as_float((unsigned)h1 << 16));
  }
  __syncthreads();                                    // f1 complete; A region dead
  // ---- W2 fragments ----
#pragma unroll
  for (int ks = 0; ks < 8; ++ks) {
#pragma unroll
    for (int i = 0; i < 8; ++i) {
      float w = W2[(size_t)(ks * 16 + kh * 8 + i) * H + n];
      unsigned short hi = f2bf(w);
      wfh[ks][i] = (short)hi;
      wfl[ks][i] = (short)f2bf(w - __uint_as_float((unsigned)hi << 16));
    }
  }
  // ---- GEMM2: pre = feed1 @ W2 + b2 + upd ----
  {
    float bv = b2[n];
#pragma unroll
    for (int r = 0; r < 16; ++r) { acc0[r] = bv; acc1[r] = bv; }
  }
#pragma unroll
  for (int ks = 0; ks < 8; ++ks) {
    bf16x8 xh0 = *(const bf16x8*)&f1h[(0 * 32 + lr) * AS + ks * 16 + kh * 8];
    bf16x8 xl0 = *(const bf16x8*)&f1l[(0 * 32 + lr) * AS + ks * 16 + kh * 8];
    bf16x8 xh1 = *(const bf16x8*)&f1h[(1 * 32 + lr) * AS + ks * 16 + kh * 8];
    bf16x8 xl1 = *(const bf16x8*)&f1l[(1 * 32 + lr) * AS + ks * 16 + kh * 8];
    acc0 = __builtin_amdgcn_mfma_f32_32x32x16_bf16(xh0, wfh[ks], acc0, 0, 0, 0);
    acc0 = __builtin_amdgcn_mfma_f32_32x32x16_bf16(xl0, wfh[ks], acc0, 0, 0, 0);
    acc0 = __builtin_amdgcn_mfma_f32_32x32x16_bf16(xh0, wfl[ks], acc0, 0, 0, 0);
    acc1 = __builtin_amdgcn_mfma_f32_32x32x16_bf16(xh1, wfh[ks], acc1, 0, 0, 0);
    acc1 = __builtin_amdgcn_mfma_f32_32x32x16_bf16(xl1, wfh[ks], acc1, 0, 0, 0);
    acc1 = __builtin_amdgcn_mfma_f32_32x32x16_bf16(xh1, wfl[ks], acc1, 0, 0, 0);
  }
  // residual + write ps (pre) — ps aliases A region (dead since barrier)
#pragma unroll
  for (int r = 0; r < 16; ++r) {
    int crow = (r & 3) + 8 * (r >> 2) + 4 * kh;
    float p0 = acc0[r] + upd[(size_t)(row0 + crow) * H + n];
    float p1 = acc1[r] + upd[(size_t)(row0 + 32 + crow) * H + n];
    acc0[r] = p0; acc1[r] = p1;
    ps[crow][n] = p0;
    ps[32 + crow][n] = p1;
  }
  __syncthreads();
  // ---- LN stats: 4 threads per row ----
  {
    int r = tid >> 2, sub = tid & 3;
    float s = 0.f, sq = 0.f;
#pragma unroll
    for (int j = 0; j < 8; ++j) {
      float4 x = *(const float4*)&ps[r][sub * 32 + j * 4];
      s += x.x + x.y + x.z + x.w;
      sq += x.x * x.x + x.y * x.y + x.z * x.z + x.w * x.w;
    }
    s += __shfl_down(s, 2, 4);  s += __shfl_down(s, 1, 4);
    sq += __shfl_down(sq, 2, 4); sq += __shfl_down(sq, 1, 4);
    if (sub == 0) {
      float mu = s * (1.f / 128.f);
      float var = sq * (1.f / 128.f) - mu * mu;
      mus[r] = mu;
      rsd[r] = rsqrtf(var + 1e-5f);
    }
  }
  __syncthreads();
  // ---- normalize, scale by cmask, write ----
  {
    float gn = g[n], bn = beta[n];
#pragma unroll
    for (int r = 0; r < 16; ++r) {
      int crow = (r & 3) + 8 * (r >> 2) + 4 * kh;
      float o0 = ((acc0[r] - mus[crow]) * rsd[crow] * gn + bn) * cmask[row0 + crow];
      float o1 = ((acc1[r] - mus[32 + crow]) * rsd[32 + crow] * gn + bn) * cmask[row0 + 32 + crow];
      upd[(size_t)(row0 + crow) * H + n] = o0;
      upd[(size_t)(row0 + 32 + crow) * H + n] = o1;
    }
  }
}

// ---------------------------------------------- ecacc += sum_l (weighted feed2)
__global__ __launch_bounds__(512) void k_ecadd(const float* __restrict__ wf,
                                               float* __restrict__ ecacc) {
  int b = blockIdx.x, tid = threadIdx.x;
  __shared__ float part[4][128];
  int h = tid & 127, seg = tid >> 7;
  float s = 0.f;
  for (int l = seg; l < L; l += 4) s += wf[(size_t)(b * L + l) * H + h];
  part[seg][h] = s;
  __syncthreads();
  if (tid < 128)
    ecacc[b * H + h] += part[0][h] + part[1][h] + part[2][h] + part[3][h];
}

// -------------------------------------------------------- gate -> sess, extras
__global__ __launch_bounds__(128) void k_gate(const float* __restrict__ ecacc,
                                              const float* __restrict__ e_s,
                                              const float* __restrict__ gw,
                                              float* __restrict__ sess,
                                              float* __restrict__ out) {
  __shared__ float cat[256];
  int b = blockIdx.x, h = threadIdx.x;
  float ec = ecacc[b * H + h] * (1.f / 3.f);
  float es = e_s[b * H + h];
  cat[h] = ec; cat[128 + h] = es;
  __syncthreads();
  float a = 0.f;
  for (int j = 0; j < 256; ++j) a = fmaf(cat[j], gw[(size_t)j * H + h], a);
  a = 1.f / (1.f + __expf(-a));
  sess[b * H + h] = a * ec + (1.f - a) * es;
  if (b == 0 && h == 0) out[(size_t)B * V] = 0.f;   // con_loss
}

// ------------------------------------------------- scores = sess @ emb^T (NT)
__global__ __launch_bounds__(256) void k_scores(const float* __restrict__ sess,
                                                const float* __restrict__ emb,
                                                float* __restrict__ out) {
  __shared__ float As[64][65], Bs[64][65];
  int n0 = blockIdx.x * 64, m0 = blockIdx.y * 64;
  int tid = threadIdx.x, tx = tid & 15, ty = tid >> 4;
  int tx4 = tx * 4, ty4 = ty * 4;
  float acc[4][4] = {};
  for (int kc = 0; kc < H; kc += 64) {
#pragma unroll
    for (int it = 0; it < 4; ++it) {
      int r = it * 16 + ty, c4 = tx4;
      float4 av = *(const float4*)&sess[(size_t)(m0 + r) * H + kc + c4];
      As[r][c4 + 0] = av.x; As[r][c4 + 1] = av.y; As[r][c4 + 2] = av.z; As[r][c4 + 3] = av.w;
      float4 bv = make_float4(0.f, 0.f, 0.f, 0.f);
      if (n0 + r < V) bv = *(const float4*)&emb[(size_t)(n0 + r) * H + kc + c4];
      Bs[r][c4 + 0] = bv.x; Bs[r][c4 + 1] = bv.y; Bs[r][c4 + 2] = bv.z; Bs[r][c4 + 3] = bv.w;
    }
    __syncthreads();
#pragma unroll 8
    for (int kk = 0; kk < 64; ++kk) {
      float a[4], bb[4];
#pragma unroll
      for (int i = 0; i < 4; ++i) a[i] = As[ty4 + i][kk];
#pragma unroll
      for (int j = 0; j < 4; ++j) bb[j] = Bs[tx4 + j][kk];
#pragma unroll
      for (int i = 0; i < 4; ++i)
#pragma unroll
        for (int j = 0; j < 4; ++j) acc[i][j] = fmaf(a[i], bb[j], acc[i][j]);
    }
    __syncthreads();
  }
#pragma unroll
  for (int i = 0; i < 4; ++i) {
    int m = m0 + ty4 + i;
#pragma unroll
    for (int j = 0; j < 4; ++j) {
      int n = n0 + tx4 + j;
      if (n < V) out[(size_t)m * V + n] = acc[i][j];
    }
  }
}

extern "C" void kernel_launch(void* const* d_in, const int* in_sizes, int n_in,
                              void* d_out, int out_size, void* d_ws, size_t ws_size,
                              hipStream_t stream) {
  const int*   seq  = (const int*)d_in[0];
  const int*   lens = (const int*)d_in[1];
  const int*   rev  = (const int*)d_in[2];
  const float* emb  = (const float*)d_in[3];
  const float* wnz  = (const float*)d_in[4];
  const float* clw  = (const float*)d_in[5];
  const float* w1   = (const float*)d_in[6];
  const float* fb1  = (const float*)d_in[7];
  const float* w2   = (const float*)d_in[8];
  const float* fb2  = (const float*)d_in[9];
  const float* lng  = (const float*)d_in[10];
  const float* lnb  = (const float*)d_in[11];
  const float* gw   = (const float*)d_in[12];
  const float* coff = (const float*)d_in[13];
  float* out = (float*)d_out;

  char* ws = (char*)d_ws;
  size_t off = 0;
  auto alloc = [&](size_t bytes) {
    void* p = ws + off;
    off += (bytes + 255) & ~(size_t)255;
    return p;
  };
  float* hidden = (float*)alloc((size_t)B * L * H * 4);
  float* nrm    = (float*)alloc((size_t)B * L * 4);
  float* S0     = (float*)alloc((size_t)B * L * L * 4);
  float* WS     = (float*)alloc((size_t)B * L * L * 4);
  float* P      = (float*)alloc((size_t)B * L * L * 4);
  float* upd    = (float*)alloc((size_t)B * L * H * 4);
  float* cmask  = (float*)alloc((size_t)B * L * 4);
  int*   cnt    = (int*)alloc((size_t)B * L * 4);
  float* e_s    = (float*)alloc((size_t)B * H * 4);
  float* ecacc  = (float*)alloc((size_t)B * H * 4);
  float* sess   = (float*)alloc((size_t)B * H * 4);
  unsigned char* ET = (unsigned char*)alloc((size_t)B * L * L);
  s16x8* hbh = (s16x8*)alloc((size_t)B * 7 * 8 * 64 * 16);   // frag-linear
  s16x8* wnh = (s16x8*)alloc((size_t)B * 7 * 8 * 64 * 16);
  // lo-residual staging aliases P/upd (first written only inside the layer loop,
  // strictly after k_simws has consumed the staging buffers)
  s16x8* hbl = (s16x8*)P;
  s16x8* wnl = (s16x8*)upd;

  k_embed<<<B * 7, 256, 0, stream>>>(seq, rev, emb, wnz, hidden, nrm,
                                     hbh, hbl, wnh, wnl);
  k_init<<<B, 512, 0, stream>>>(lens, hidden, ecacc, e_s);
  k_simws<<<B * 7, 256, 0, stream>>>(hbh, hbl, wnh, wnl, nrm, rev, clw, S0, WS);

  for (int i = 0; i < 2; ++i) {
    hipMemsetAsync(ET, 0, (size_t)B * L * L, stream);
    k_rowpass<<<B * 13, 256, 0, stream>>>(S0, WS, coff + (size_t)i * B * L * L,
                                          lens, P, ET);
    k_compact<<<B * L / 4, 256, 0, stream>>>(P, ET, cmask, cnt);
    k_cnorm<<<B, 64, 0, stream>>>(cmask);
    k_update<<<B * L / 2, 256, 0, stream>>>(P, ET, cnt, hidden, upd);
    k_ffn<<<B * L / 64, 256, 0, stream>>>(upd, w1, fb1, w2, fb2, lng, lnb, cmask);
    k_ecadd<<<B, 512, 0, stream>>>(upd, ecacc);
  }

  k_gate<<<B, 128, 0, stream>>>(ecacc, e_s, gw, sess, out);
  k_scores<<<dim3((V + 63) / 64, 4), 256, 0, stream>>>(sess, emb, out);
}

// Round 8
// 475.255 us; speedup vs baseline: 1.8847x; 1.0401x over previous
//
#include <hip/hip_runtime.h>
#include <cstdint>
#include <cstddef>

namespace {
constexpr int B = 256, L = 200, H = 128, V = 50000, TK = 20;
constexpr int NT = 1563;                   // ceil(V/32)
constexpr float NEGV = -1e10f;
}

using bf16x8 = __attribute__((ext_vector_type(8))) short;
using s16x8  = __attribute__((ext_vector_type(8))) short;
using f32x16 = __attribute__((ext_vector_type(16))) float;

__device__ inline unsigned short f2bf(float f) {
  unsigned int u = __float_as_uint(f);
  unsigned int r = (u + 0x7fffu + ((u >> 16) & 1u)) >> 16;   // RNE
  return (unsigned short)r;
}

// ---- 16-lane-group DPP reductions ------------------------------------------
#define DPP_QUAD_XOR1 0xB1
#define DPP_QUAD_XOR2 0x4E
#define DPP_ROW_HMIRR 0x141
#define DPP_ROW_MIRR  0x140

template <int CTRL>
__device__ inline unsigned dpp16_max_step(unsigned v) {
  unsigned t = (unsigned)__builtin_amdgcn_update_dpp(0, (int)v, CTRL, 0xF, 0xF, true);
  return v > t ? v : t;
}
__device__ inline unsigned grp16_max(unsigned v) {
  v = dpp16_max_step<DPP_QUAD_XOR1>(v);
  v = dpp16_max_step<DPP_QUAD_XOR2>(v);
  v = dpp16_max_step<DPP_ROW_HMIRR>(v);
  v = dpp16_max_step<DPP_ROW_MIRR>(v);
  return v;                                   // uniform within each 16-group
}
template <int CTRL>
__device__ inline float dpp16_add_step(float v) {
  int t = __builtin_amdgcn_update_dpp(0, __float_as_int(v), CTRL, 0xF, 0xF, true);
  return v + __int_as_float(t);
}
__device__ inline float grp16_sum(float v) {
  v = dpp16_add_step<DPP_QUAD_XOR1>(v);
  v = dpp16_add_step<DPP_QUAD_XOR2>(v);
  v = dpp16_add_step<DPP_ROW_HMIRR>(v);
  v = dpp16_add_step<DPP_ROW_MIRR>(v);
  return v;
}

__device__ inline unsigned f2key(float f) {        // order-preserving, bijective
  unsigned b = __float_as_uint(f);
  unsigned m = (unsigned)((int)b >> 31);
  return b ^ (m | 0x80000000u);
}
__device__ inline float key2f(unsigned u) {
  unsigned b = (u & 0x80000000u) ? (u & 0x7fffffffu) : ~u;
  return __uint_as_float(b);
}

// ---- embed + norm + frag-linear bf16 hi/lo staging --------------------------
__global__ __launch_bounds__(256) void k_embed(const int* __restrict__ seq,
                                               const int* __restrict__ rev,
                                               const float* __restrict__ emb,
                                               const float* __restrict__ wnoise,
                                               float* __restrict__ hidden,
                                               float* __restrict__ nrm,
                                               s16x8* __restrict__ hbh,
                                               s16x8* __restrict__ hbl,
                                               s16x8* __restrict__ wnh,
                                               s16x8* __restrict__ wnl) {
  int b = blockIdx.x / 7, lt = blockIdx.x % 7;
  int t = threadIdx.x;
  int r = t >> 3, c2 = t & 7;                 // row-in-tile, 16-elem h-chunk
  int l = lt * 32 + r;
  bool valid = l < L;
  float vv[16], wv[16];
  if (valid) {
    int row = b * L + l;
    int tok = seq[row];
    const float4* ep = (const float4*)&emb[(size_t)tok * H + c2 * 16];
    const float4* wp = (const float4*)&wnoise[(size_t)rev[row] * H + c2 * 16];
#pragma unroll
    for (int i = 0; i < 4; ++i) {
      float4 x = ep[i];
      vv[i * 4 + 0] = x.x; vv[i * 4 + 1] = x.y; vv[i * 4 + 2] = x.z; vv[i * 4 + 3] = x.w;
      float4 y = wp[i];
      wv[i * 4 + 0] = y.x; wv[i * 4 + 1] = y.y; wv[i * 4 + 2] = y.z; wv[i * 4 + 3] = y.w;
    }
  } else {
#pragma unroll
    for (int i = 0; i < 16; ++i) { vv[i] = 0.f; wv[i] = 0.f; }
  }
  if (valid) {
    int row = b * L + l;
#pragma unroll
    for (int i = 0; i < 4; ++i)
      *(float4*)&hidden[(size_t)row * H + c2 * 16 + i * 4] =
          make_float4(vv[i * 4], vv[i * 4 + 1], vv[i * 4 + 2], vv[i * 4 + 3]);
    float s = 0.f;
#pragma unroll
    for (int i = 0; i < 16; ++i) s += vv[i] * vv[i];
    s += __shfl_down(s, 4, 8);
    s += __shfl_down(s, 2, 8);
    s += __shfl_down(s, 1, 8);
    if (c2 == 0) nrm[row] = sqrtf(s);
  }
  s16x8 h0, h1, l0, l1, w0, w1, x0, x1;
#pragma unroll
  for (int i = 0; i < 8; ++i) {
    unsigned short hi = f2bf(vv[i]);
    h0[i] = (short)hi;
    l0[i] = (short)f2bf(vv[i] - __uint_as_float((unsigned)hi << 16));
    unsigned short wh = f2bf(wv[i]);
    w0[i] = (short)wh;
    x0[i] = (short)f2bf(wv[i] - __uint_as_float((unsigned)wh << 16));
  }
#pragma unroll
  for (int i = 0; i < 8; ++i) {
    unsigned short hi = f2bf(vv[8 + i]);
    h1[i] = (short)hi;
    l1[i] = (short)f2bf(vv[8 + i] - __uint_as_float((unsigned)hi << 16));
    unsigned short wh = f2bf(wv[8 + i]);
    w1[i] = (short)wh;
    x1[i] = (short)f2bf(wv[8 + i] - __uint_as_float((unsigned)wh << 16));
  }
  size_t fi0 = ((size_t)(b * 7 + lt) * 8 + c2) * 64 + r;   // kh=0
  size_t fi1 = fi0 + 32;                                   // kh=1
  hbh[fi0] = h0; hbh[fi1] = h1;
  hbl[fi0] = l0; hbl[fi1] = l1;
  wnh[fi0] = w0; wnh[fi1] = w1;
  wnl[fi0] = x0; wnl[fi1] = x1;
}

// ------------------------------------------ slen, zero_layer (into ecacc), e_s
__global__ __launch_bounds__(512) void k_init(const int* __restrict__ lengths,
                                              const float* __restrict__ hidden,
                                              float* __restrict__ ecacc,
                                              float* __restrict__ e_s) {
  int b = blockIdx.x, tid = threadIdx.x;
  __shared__ float part[4][128];
  __shared__ int wcnt[8];
  __shared__ int s_slen;
  int c = (tid < L && lengths[b * L + tid] > 0) ? 1 : 0;
  for (int o = 32; o > 0; o >>= 1) c += __shfl_down(c, o, 64);
  if ((tid & 63) == 0) wcnt[tid >> 6] = c;
  __syncthreads();
  if (tid == 0) {
    int s = 0;
#pragma unroll
    for (int i = 0; i < 8; ++i) s += wcnt[i];
    s_slen = s;
  }
  int h = tid & 127, seg = tid >> 7;
  float s = 0.f;
  for (int l = seg; l < L; l += 4) s += hidden[(size_t)(b * L + l) * H + h];
  part[seg][h] = s;
  __syncthreads();
  if (tid < 128) {
    float tot = part[0][h] + part[1][h] + part[2][h] + part[3][h];
    int slen = s_slen;
    ecacc[b * H + h] = tot / (float)slen;
    e_s[b * H + h] = hidden[(size_t)(b * L + slen - 1) * H + h];
  }
}

// ---- S0 = cosine sim (+diag), WS = softplus(hidden·wn), bf16x3 split MFMA ---
__global__ __launch_bounds__(256) void k_simws(const s16x8* __restrict__ hbh,
                                               const s16x8* __restrict__ hbl,
                                               const s16x8* __restrict__ wnh,
                                               const s16x8* __restrict__ wnl,
                                               const float* __restrict__ nrm,
                                               const int* __restrict__ rev,
                                               const float* __restrict__ cluster,
                                               float* __restrict__ S0,
                                               float* __restrict__ WS) {
  int orig = blockIdx.x;                     // 0..1791 (= 8 XCD * 32 b * 7 lt)
  int xcd = orig & 7, slot = orig >> 3;
  int b = xcd * 32 + slot / 7, lt = slot % 7;
  int wid = threadIdx.x >> 6, lane = threadIdx.x & 63;
  int lr = lane & 31, kh = lane >> 5;
  size_t abase = ((size_t)(b * 7 + lt) * 8) * 64 + lane;
  bf16x8 ah[8], al[8];
#pragma unroll
  for (int ks = 0; ks < 8; ++ks) {
    ah[ks] = (bf16x8)hbh[abase + ks * 64];
    al[ks] = (bf16x8)hbl[abase + ks * 64];
  }
  for (int mt = wid; mt < 7; mt += 4) {
    size_t bbase = ((size_t)(b * 7 + mt) * 8) * 64 + lane;
    f32x16 accs = {}, accw = {};
#pragma unroll
    for (int ks = 0; ks < 8; ++ks) {
      bf16x8 bhh = (bf16x8)hbh[bbase + ks * 64];
      bf16x8 bhl = (bf16x8)hbl[bbase + ks * 64];
      bf16x8 bwh = (bf16x8)wnh[bbase + ks * 64];
      bf16x8 bwl = (bf16x8)wnl[bbase + ks * 64];
      accs = __builtin_amdgcn_mfma_f32_32x32x16_bf16(ah[ks], bhh, accs, 0, 0, 0);
      accs = __builtin_amdgcn_mfma_f32_32x32x16_bf16(ah[ks], bhl, accs, 0, 0, 0);
      accs = __builtin_amdgcn_mfma_f32_32x32x16_bf16(al[ks], bhh, accs, 0, 0, 0);
      accw = __builtin_amdgcn_mfma_f32_32x32x16_bf16(ah[ks], bwh, accw, 0, 0, 0);
      accw = __builtin_amdgcn_mfma_f32_32x32x16_bf16(ah[ks], bwl, accw, 0, 0, 0);
      accw = __builtin_amdgcn_mfma_f32_32x32x16_bf16(al[ks], bwh, accw, 0, 0, 0);
    }
    int m = mt * 32 + lr;
    if (m < L) {
      float nm = nrm[b * L + m];
#pragma unroll
      for (int r = 0; r < 16; ++r) {
        int row = lt * 32 + (r & 3) + 8 * (r >> 2) + 4 * kh;
        if (row < L) {
          float nl = nrm[b * L + row];
          float s0 = accs[r] * __builtin_amdgcn_rcpf(nl * nm + 1e-6f);
          if (row == m) s0 += cluster[rev[b * L + row]];
          size_t o = (size_t)(b * L + row) * L + m;
          S0[o] = s0;
          float x = accw[r];
          WS[o] = (x > 1.f) ? x : __logf(1.f + __expf(x));
        }
      }
    }
  }
}

// ------- per row: msim in regs (13/lane over 16 lanes), DPP16 top-K, softmax
__global__ __launch_bounds__(256) void k_rowpass(const float* __restrict__ S0,
                                                 const float* __restrict__ WS,
                                                 const float* __restrict__ coff_i,
                                                 const int* __restrict__ lengths,
                                                 float* __restrict__ P,
                                                 unsigned char* __restrict__ ET) {
  int wid = threadIdx.x >> 6, lane = threadIdx.x & 63;
  int g = lane >> 4, q = lane & 15;
  int bb = blockIdx.x / 13, blk = blockIdx.x % 13;
  int l = blk * 16 + wid * 4 + g;
  bool lvalid = l < L;
  int lrow = bb * L + (lvalid ? l : 0);
  bool mask_l = lvalid && (lengths[lrow] > 0);
  size_t base = (size_t)lrow * L;
  float val[13]; unsigned key[13]; unsigned vmask = 0;
#pragma unroll
  for (int j = 0; j < 13; ++j) {
    int m = q + 16 * j;
    float v = 0.f; bool ok = false;
    if (mask_l && m < L) {
      ok = lengths[bb * L + m] > 0;
      if (ok) v = S0[base + m] + coff_i[base + m] * WS[base + m];
    }
    val[j] = v;
    key[j] = ok ? f2key(v) : 0u;
    vmask |= ok ? (1u << j) : 0u;
  }
  unsigned Mu = 0u;
  for (int t = 0; t < TK; ++t) {
    unsigned lv = key[0]; int lj = 0;
#pragma unroll
    for (int j = 1; j < 13; ++j) {
      bool gt = key[j] > lv;
      lv = gt ? key[j] : lv;
      lj = gt ? j : lj;
    }
    unsigned gm = grp16_max(lv);
    if (t == 0) Mu = gm;
    if (__all(gm == 0u)) break;              // all 4 groups exhausted
    unsigned long long bal = __ballot(lv == gm && gm != 0u);
    unsigned long long mine = bal & (0xFFFFull << (g * 16));
    int owner = mine ? (int)__builtin_ctzll(mine) : -1;
    bool is_owner = (lane == owner);         // lowest lane of group (tie ok)
    if (is_owner) {
      int m = q + 16 * lj;
      ET[((size_t)bb * L + m) * L + l] = 1;
    }
#pragma unroll
    for (int j = 0; j < 13; ++j) key[j] = (is_owner && lj == j) ? 0u : key[j];
  }
  // softmax over the row (invalid entries contribute exactly 0)
  float M = key2f(Mu);
  float e[13]; float s = 0.f;
#pragma unroll
  for (int j = 0; j < 13; ++j) {
    float ev = ((vmask >> j) & 1u) ? __expf(val[j] - M) : 0.f;
    e[j] = ev; s += ev;
  }
  s = grp16_sum(s);
  float inv = (s > 0.f) ? __builtin_amdgcn_rcpf(s) : 0.f;
  if (lvalid) {
#pragma unroll
    for (int j = 0; j < 13; ++j) {
      int m = q + 16 * j;
      if (m < L) P[base + m] = e[j] * inv;
    }
  }
}

// ---- ssm row = P * ET, row-sum -> cmask, ordered in-place compaction to lists
__global__ __launch_bounds__(256) void k_compact(float* __restrict__ P,
                                                 unsigned char* __restrict__ ET,
                                                 float* __restrict__ cmask,
                                                 int* __restrict__ cnt) {
  int wid = threadIdx.x >> 6, lane = threadIdx.x & 63;
  int row = blockIdx.x * 4 + wid;
  size_t base = (size_t)row * L;
  float w[4];
  float s = 0.f;
#pragma unroll
  for (int j = 0; j < 4; ++j) {
    int m = lane + 64 * j;
    float ww = 0.f;
    if (m < L) ww = P[base + m] * (float)ET[base + m];
    w[j] = ww; s += ww;
  }
  float ssum = s;
  for (int off = 1; off < 64; off <<= 1) ssum += __shfl_xor(ssum, off, 64);
  if (lane == 0) cmask[row] = ssum;
  int pos_base = 0;
#pragma unroll
  for (int j = 0; j < 4; ++j) {
    bool nz = (w[j] != 0.f);
    unsigned long long mk = __ballot(nz);
    int rank = __popcll(mk & ((1ull << lane) - 1ull));
    if (nz) {
      int pos = pos_base + rank;
      ET[base + pos] = (unsigned char)(lane + 64 * j);
      P[base + pos] = w[j];
    }
    pos_base += (int)__popcll(mk);
  }
  if (lane == 0) cnt[row] = pos_base;
}

// -------------------------------------------- cmask /= max(||cmask||_2, 1e-12)
__global__ __launch_bounds__(64) void k_cnorm(float* __restrict__ cmask) {
  int b = blockIdx.x, lane = threadIdx.x;   // 64 threads
  float v[4]; float s = 0.f;
#pragma unroll
  for (int j = 0; j < 4; ++j) {
    int l = lane + 64 * j;
    float x = (l < L) ? cmask[b * L + l] : 0.f;
    v[j] = x; s += x * x;
  }
  for (int off = 1; off < 64; off <<= 1) s += __shfl_xor(s, off, 64);
  float inv = 1.f / fmaxf(sqrtf(s), 1e-12f);
#pragma unroll
  for (int j = 0; j < 4; ++j) {
    int l = lane + 64 * j;
    if (l < L) cmask[b * L + l] = v[j] * inv;
  }
}

// --- update[l,:] = sum over edge list; chunked batched gather (n can be >TK!)
__global__ __launch_bounds__(256) void k_update(const float* __restrict__ P,
                                                const unsigned char* __restrict__ ET,
                                                const int* __restrict__ cnt,
                                                const float* __restrict__ hidden,
                                                float* __restrict__ upd) {
  int row = blockIdx.x * 2 + (threadIdx.x >> 7);
  int h = threadIdx.x & 127;
  int b = row / L;
  size_t base = (size_t)row * L;
  int n = cnt[row];
  float acc = 0.f;
  for (int e0 = 0; e0 < n; e0 += TK) {       // e0 multiple of 20, e0+20 <= 200
    float w[TK]; int m[TK];
    float4 p4[5];
#pragma unroll
    for (int i = 0; i < 5; ++i) p4[i] = *(const float4*)&P[base + e0 + i * 4];
#pragma unroll
    for (int i = 0; i < 5; ++i) {
      w[i * 4 + 0] = p4[i].x; w[i * 4 + 1] = p4[i].y;
      w[i * 4 + 2] = p4[i].z; w[i * 4 + 3] = p4[i].w;
    }
#pragma unroll
    for (int e = 0; e < TK; ++e) m[e] = ET[base + e0 + e];
    float hv[TK];
#pragma unroll
    for (int e = 0; e < TK; ++e)
      hv[e] = hidden[(size_t)(b * L + m[e]) * H + h];
#pragma unroll
    for (int e = 0; e < TK; ++e)
      acc += ((e0 + e) < n ? w[e] : 0.f) * hv[e];
  }
  upd[(size_t)row * H + h] = acc;
}

// ----- FFN + residual + LN via bf16x3 MFMA, weighted by cmask, in-place ------
__global__ __launch_bounds__(256) void k_ffn(float* __restrict__ upd,
                                             const float* __restrict__ W1,
                                             const float* __restrict__ b1,
                                             const float* __restrict__ W2,
                                             const float* __restrict__ b2,
                                             const float* __restrict__ g,
                                             const float* __restrict__ beta,
                                             const float* __restrict__ cmask) {
  constexpr int AS = 136;                            // short stride (16B-aligned rows)
  __shared__ __align__(16) char smem[4 * 64 * AS * 2];  // 69632 B
  short* ahs = (short*)smem;                         // A hi  [64][AS]
  short* als = ahs + 64 * AS;                        // A lo
  short* f1h = (short*)(smem + 2 * 64 * AS * 2);     // feed1 hi
  short* f1l = f1h + 64 * AS;
  float (*ps)[132] = (float (*)[132])smem;           // aliases A (dead after GEMM1)
  __shared__ float mus[64], rsd[64];
  int row0 = blockIdx.x * 64;
  int tid = threadIdx.x;
  int wid = tid >> 6, lane = tid & 63;
  int lr = lane & 31, kh = lane >> 5;
  int n0 = wid * 32;
  int n = n0 + lr;
  // ---- stage upd -> bf16 hi/lo LDS ----
#pragma unroll
  for (int it = 0; it < 8; ++it) {
    int f = it * 256 + tid;
    int r = f >> 5, c4 = (f & 31) * 4;
    float4 v = *(const float4*)&upd[(size_t)(row0 + r) * H + c4];
    float vv[4] = {v.x, v.y, v.z, v.w};
    unsigned short hh[4]; short ll[4];
#pragma unroll
    for (int q2 = 0; q2 < 4; ++q2) {
      hh[q2] = f2bf(vv[q2]);
      ll[q2] = (short)f2bf(vv[q2] - __uint_as_float((unsigned)hh[q2] << 16));
    }
    uint2 ph = make_uint2((unsigned)hh[0] | ((unsigned)hh[1] << 16),
                          (unsigned)hh[2] | ((unsigned)hh[3] << 16));
    uint2 pl = make_uint2((unsigned short)ll[0] | ((unsigned)(unsigned short)ll[1] << 16),
                          (unsigned short)ll[2] | ((unsigned)(unsigned short)ll[3] << 16));
    *(uint2*)&ahs[r * AS + c4] = ph;
    *(uint2*)&als[r * AS + c4] = pl;
  }
  __syncthreads();
  // ---- W1 fragments ----
  bf16x8 wfh[8], wfl[8];
#pragma unroll
  for (int ks = 0; ks < 8; ++ks) {
#pragma unroll
    for (int i = 0; i < 8; ++i) {
      float w = W1[(size_t)(ks * 16 + kh * 8 + i) * H + n];
      unsigned short hi = f2bf(w);
      wfh[ks][i] = (short)hi;
      wfl[ks][i] = (short)f2bf(w - __uint_as_float((unsigned)hi << 16));
    }
  }
  // ---- GEMM1: feed1 = relu(upd @ W1 + b1) ----
  f32x16 acc0, acc1;
  {
    float bv = b1[n];
#pragma unroll
    for (int r = 0; r < 16; ++r) { acc0[r] = bv; acc1[r] = bv; }
  }
#pragma unroll
  for (int ks = 0; ks < 8; ++ks) {
    bf16x8 xh0 = *(const bf16x8*)&ahs[(0 * 32 + lr) * AS + ks * 16 + kh * 8];
    bf16x8 xl0 = *(const bf16x8*)&als[(0 * 32 + lr) * AS + ks * 16 + kh * 8];
    bf16x8 xh1 = *(const bf16x8*)&ahs[(1 * 32 + lr) * AS + ks * 16 + kh * 8];
    bf16x8 xl1 = *(const bf16x8*)&als[(1 * 32 + lr) * AS + ks * 16 + kh * 8];
    acc0 = __builtin_amdgcn_mfma_f32_32x32x16_bf16(xh0, wfh[ks], acc0, 0, 0, 0);
    acc0 = __builtin_amdgcn_mfma_f32_32x32x16_bf16(xl0, wfh[ks], acc0, 0, 0, 0);
    acc0 = __builtin_amdgcn_mfma_f32_32x32x16_bf16(xh0, wfl[ks], acc0, 0, 0, 0);
    acc1 = __builtin_amdgcn_mfma_f32_32x32x16_bf16(xh1, wfh[ks], acc1, 0, 0, 0);
    acc1 = __builtin_amdgcn_mfma_f32_32x32x16_bf16(xl1, wfh[ks], acc1, 0, 0, 0);
    acc1 = __builtin_amdgcn_mfma_f32_32x32x16_bf16(xh1, wfl[ks], acc1, 0, 0, 0);
  }
  // relu -> f1 hi/lo LDS (C layout: row=(r&3)+8*(r>>2)+4*kh, col=n)
#pragma unroll
  for (int r = 0; r < 16; ++r) {
    int crow = (r & 3) + 8 * (r >> 2) + 4 * kh;
    float f0 = fmaxf(acc0[r], 0.f);
    unsigned short h0 = f2bf(f0);
    f1h[crow * AS + n] = (short)h0;
    f1l[crow * AS + n] = (short)f2bf(f0 - __uint_as_float((unsigned)h0 << 16));
    float f1v = fmaxf(acc1[r], 0.f);
    unsigned short h1 = f2bf(f1v);
    f1h[(32 + crow) * AS + n] = (short)h1;
    f1l[(32 + crow) * AS + n] = (short)f2bf(f1v - __uint_as_float((unsigned)h1 << 16));
  }
  __syncthreads();                                    // f1 complete; A region dead
  // ---- W2 fragments ----
#pragma unroll
  for (int ks = 0; ks < 8; ++ks) {
#pragma unroll
    for (int i = 0; i < 8; ++i) {
      float w = W2[(size_t)(ks * 16 + kh * 8 + i) * H + n];
      unsigned short hi = f2bf(w);
      wfh[ks][i] = (short)hi;
      wfl[ks][i] = (short)f2bf(w - __uint_as_float((unsigned)hi << 16));
    }
  }
  // ---- GEMM2: pre = feed1 @ W2 + b2 + upd ----
  {
    float bv = b2[n];
#pragma unroll
    for (int r = 0; r < 16; ++r) { acc0[r] = bv; acc1[r] = bv; }
  }
#pragma unroll
  for (int ks = 0; ks < 8; ++ks) {
    bf16x8 xh0 = *(const bf16x8*)&f1h[(0 * 32 + lr) * AS + ks * 16 + kh * 8];
    bf16x8 xl0 = *(const bf16x8*)&f1l[(0 * 32 + lr) * AS + ks * 16 + kh * 8];
    bf16x8 xh1 = *(const bf16x8*)&f1h[(1 * 32 + lr) * AS + ks * 16 + kh * 8];
    bf16x8 xl1 = *(const bf16x8*)&f1l[(1 * 32 + lr) * AS + ks * 16 + kh * 8];
    acc0 = __builtin_amdgcn_mfma_f32_32x32x16_bf16(xh0, wfh[ks], acc0, 0, 0, 0);
    acc0 = __builtin_amdgcn_mfma_f32_32x32x16_bf16(xl0, wfh[ks], acc0, 0, 0, 0);
    acc0 = __builtin_amdgcn_mfma_f32_32x32x16_bf16(xh0, wfl[ks], acc0, 0, 0, 0);
    acc1 = __builtin_amdgcn_mfma_f32_32x32x16_bf16(xh1, wfh[ks], acc1, 0, 0, 0);
    acc1 = __builtin_amdgcn_mfma_f32_32x32x16_bf16(xl1, wfh[ks], acc1, 0, 0, 0);
    acc1 = __builtin_amdgcn_mfma_f32_32x32x16_bf16(xh1, wfl[ks], acc1, 0, 0, 0);
  }
  // residual + write ps (pre) — ps aliases A region (dead since barrier)
#pragma unroll
  for (int r = 0; r < 16; ++r) {
    int crow = (r & 3) + 8 * (r >> 2) + 4 * kh;
    float p0 = acc0[r] + upd[(size_t)(row0 + crow) * H + n];
    float p1 = acc1[r] + upd[(size_t)(row0 + 32 + crow) * H + n];
    acc0[r] = p0; acc1[r] = p1;
    ps[crow][n] = p0;
    ps[32 + crow][n] = p1;
  }
  __syncthreads();
  // ---- LN stats: 4 threads per row ----
  {
    int r = tid >> 2, sub = tid & 3;
    float s = 0.f, sq = 0.f;
#pragma unroll
    for (int j = 0; j < 8; ++j) {
      float4 x = *(const float4*)&ps[r][sub * 32 + j * 4];
      s += x.x + x.y + x.z + x.w;
      sq += x.x * x.x + x.y * x.y + x.z * x.z + x.w * x.w;
    }
    s += __shfl_down(s, 2, 4);  s += __shfl_down(s, 1, 4);
    sq += __shfl_down(sq, 2, 4); sq += __shfl_down(sq, 1, 4);
    if (sub == 0) {
      float mu = s * (1.f / 128.f);
      float var = sq * (1.f / 128.f) - mu * mu;
      mus[r] = mu;
      rsd[r] = rsqrtf(var + 1e-5f);
    }
  }
  __syncthreads();
  // ---- normalize, scale by cmask, write ----
  {
    float gn = g[n], bn = beta[n];
#pragma unroll
    for (int r = 0; r < 16; ++r) {
      int crow = (r & 3) + 8 * (r >> 2) + 4 * kh;
      float o0 = ((acc0[r] - mus[crow]) * rsd[crow] * gn + bn) * cmask[row0 + crow];
      float o1 = ((acc1[r] - mus[32 + crow]) * rsd[32 + crow] * gn + bn) * cmask[row0 + 32 + crow];
      upd[(size_t)(row0 + crow) * H + n] = o0;
      upd[(size_t)(row0 + 32 + crow) * H + n] = o1;
    }
  }
}

// ---------------------------------------------- ecacc += sum_l (weighted feed2)
__global__ __launch_bounds__(512) void k_ecadd(const float* __restrict__ wf,
                                               float* __restrict__ ecacc) {
  int b = blockIdx.x, tid = threadIdx.x;
  __shared__ float part[4][128];
  int h = tid & 127, seg = tid >> 7;
  float s = 0.f;
  for (int l = seg; l < L; l += 4) s += wf[(size_t)(b * L + l) * H + h];
  part[seg][h] = s;
  __syncthreads();
  if (tid < 128)
    ecacc[b * H + h] += part[0][h] + part[1][h] + part[2][h] + part[3][h];
}

// ------------ emb fp32 -> frag-linear bf16 hi/lo (padded to NT 32-row tiles)
__global__ __launch_bounds__(256) void k_embconv(const float* __restrict__ emb,
                                                 s16x8* __restrict__ ebh,
                                                 s16x8* __restrict__ ebl) {
  int nt = blockIdx.x;
  int t = threadIdx.x;
  int r = t >> 3, c2 = t & 7;
  int n = nt * 32 + r;
  float vv[16];
  if (n < V) {
    const float4* ep = (const float4*)&emb[(size_t)n * H + c2 * 16];
#pragma unroll
    for (int i = 0; i < 4; ++i) {
      float4 x = ep[i];
      vv[i * 4 + 0] = x.x; vv[i * 4 + 1] = x.y; vv[i * 4 + 2] = x.z; vv[i * 4 + 3] = x.w;
    }
  } else {
#pragma unroll
    for (int i = 0; i < 16; ++i) vv[i] = 0.f;
  }
  s16x8 h0, h1, l0, l1;
#pragma unroll
  for (int i = 0; i < 8; ++i) {
    unsigned short hi = f2bf(vv[i]);
    h0[i] = (short)hi;
    l0[i] = (short)f2bf(vv[i] - __uint_as_float((unsigned)hi << 16));
    unsigned short hj = f2bf(vv[8 + i]);
    h1[i] = (short)hj;
    l1[i] = (short)f2bf(vv[8 + i] - __uint_as_float((unsigned)hj << 16));
  }
  size_t fi0 = ((size_t)nt * 8 + c2) * 64 + r;
  size_t fi1 = fi0 + 32;
  ebh[fi0] = h0; ebh[fi1] = h1;
  ebl[fi0] = l0; ebl[fi1] = l1;
}

// -------------------------------------------------------- gate -> sess, extras
__global__ __launch_bounds__(128) void k_gate(const float* __restrict__ ecacc,
                                              const float* __restrict__ e_s,
                                              const float* __restrict__ gw,
                                              float* __restrict__ sess,
                                              float* __restrict__ out) {
  __shared__ float cat[256];
  int b = blockIdx.x, h = threadIdx.x;
  float ec = ecacc[b * H + h] * (1.f / 3.f);
  float es = e_s[b * H + h];
  cat[h] = ec; cat[128 + h] = es;
  __syncthreads();
  float a = 0.f;
  for (int j = 0; j < 256; ++j) a = fmaf(cat[j], gw[(size_t)j * H + h], a);
  a = 1.f / (1.f + __expf(-a));
  sess[b * H + h] = a * ec + (1.f - a) * es;
  if (b == 0 && h == 0) out[(size_t)B * V] = 0.f;   // con_loss
}

// ---------- scores = sess @ emb^T via bf16x3 MFMA (frag-linear emb) ----------
// grid (ceil(NT/16), 8 mtiles); wave w handles nt = bx*16 + w + 4j
__global__ __launch_bounds__(256) void k_scores(const float* __restrict__ sess,
                                                const s16x8* __restrict__ ebh,
                                                const s16x8* __restrict__ ebl,
                                                float* __restrict__ out) {
  int wid = threadIdx.x >> 6, lane = threadIdx.x & 63;
  int lr = lane & 31, kh = lane >> 5;
  int mt = blockIdx.y;
  int m = mt * 32 + lr;
  // A fragments from sess (fp32 -> bf16 hi/lo in registers; sess is L2-hot)
  bf16x8 ah[8], al[8];
#pragma unroll
  for (int ks = 0; ks < 8; ++ks) {
    const float* sp = &sess[(size_t)m * H + ks * 16 + kh * 8];
    float4 a = *(const float4*)sp;
    float4 c = *(const float4*)(sp + 4);
    float av[8] = {a.x, a.y, a.z, a.w, c.x, c.y, c.z, c.w};
#pragma unroll
    for (int i = 0; i < 8; ++i) {
      unsigned short hi = f2bf(av[i]);
      ah[ks][i] = (short)hi;
      al[ks][i] = (short)f2bf(av[i] - __uint_as_float((unsigned)hi << 16));
    }
  }
  int ntEnd = min(blockIdx.x * 16 + 16, NT);
  for (int nt = blockIdx.x * 16 + wid; nt < ntEnd; nt += 4) {
    size_t bbase = ((size_t)nt * 8) * 64 + lane;
    f32x16 acc = {};
#pragma unroll
    for (int ks = 0; ks < 8; ++ks) {
      bf16x8 bh = (bf16x8)ebh[bbase + ks * 64];
      bf16x8 bl = (bf16x8)ebl[bbase + ks * 64];
      acc = __builtin_amdgcn_mfma_f32_32x32x16_bf16(ah[ks], bh, acc, 0, 0, 0);
      acc = __builtin_amdgcn_mfma_f32_32x32x16_bf16(al[ks], bh, acc, 0, 0, 0);
      acc = __builtin_amdgcn_mfma_f32_32x32x16_bf16(ah[ks], bl, acc, 0, 0, 0);
    }
    int n = nt * 32 + lr;
    if (n < V) {
#pragma unroll
      for (int r = 0; r < 16; ++r) {
        int row = mt * 32 + (r & 3) + 8 * (r >> 2) + 4 * kh;
        out[(size_t)row * V + n] = acc[r];
      }
    }
  }
}

extern "C" void kernel_launch(void* const* d_in, const int* in_sizes, int n_in,
                              void* d_out, int out_size, void* d_ws, size_t ws_size,
                              hipStream_t stream) {
  const int*   seq  = (const int*)d_in[0];
  const int*   lens = (const int*)d_in[1];
  const int*   rev  = (const int*)d_in[2];
  const float* emb  = (const float*)d_in[3];
  const float* wnz  = (const float*)d_in[4];
  const float* clw  = (const float*)d_in[5];
  const float* w1   = (const float*)d_in[6];
  const float* fb1  = (const float*)d_in[7];
  const float* w2   = (const float*)d_in[8];
  const float* fb2  = (const float*)d_in[9];
  const float* lng  = (const float*)d_in[10];
  const float* lnb  = (const float*)d_in[11];
  const float* gw   = (const float*)d_in[12];
  const float* coff = (const float*)d_in[13];
  float* out = (float*)d_out;

  char* ws = (char*)d_ws;
  size_t off = 0;
  auto alloc = [&](size_t bytes) {
    void* p = ws + off;
    off += (bytes + 255) & ~(size_t)255;
    return p;
  };
  float* hidden = (float*)alloc((size_t)B * L * H * 4);
  float* nrm    = (float*)alloc((size_t)B * L * 4);
  float* S0     = (float*)alloc((size_t)B * L * L * 4);
  float* WS     = (float*)alloc((size_t)B * L * L * 4);
  float* P      = (float*)alloc((size_t)B * L * L * 4);
  float* upd    = (float*)alloc((size_t)B * L * H * 4);
  float* cmask  = (float*)alloc((size_t)B * L * 4);
  int*   cnt    = (int*)alloc((size_t)B * L * 4);
  float* e_s    = (float*)alloc((size_t)B * H * 4);
  float* ecacc  = (float*)alloc((size_t)B * H * 4);
  float* sess   = (float*)alloc((size_t)B * H * 4);
  unsigned char* ET = (unsigned char*)alloc((size_t)B * L * L);
  s16x8* hbh = (s16x8*)alloc((size_t)B * 7 * 8 * 64 * 16);   // frag-linear
  s16x8* wnh = (s16x8*)alloc((size_t)B * 7 * 8 * 64 * 16);
  // lo-residual staging aliases P/upd (first written only inside the layer loop,
  // strictly after k_simws has consumed the staging buffers)
  s16x8* hbl = (s16x8*)P;
  s16x8* wnl = (s16x8*)upd;
  // emb bf16 hi/lo staging aliases S0/WS (dead after the last k_rowpass);
  // NT*8*64*16 B = 12.8 MB each <= 41 MB each
  s16x8* ebh = (s16x8*)S0;
  s16x8* ebl = (s16x8*)WS;

  k_embed<<<B * 7, 256, 0, stream>>>(seq, rev, emb, wnz, hidden, nrm,
                                     hbh, hbl, wnh, wnl);
  k_init<<<B, 512, 0, stream>>>(lens, hidden, ecacc, e_s);
  k_simws<<<B * 7, 256, 0, stream>>>(hbh, hbl, wnh, wnl, nrm, rev, clw, S0, WS);

  for (int i = 0; i < 2; ++i) {
    hipMemsetAsync(ET, 0, (size_t)B * L * L, stream);
    k_rowpass<<<B * 13, 256, 0, stream>>>(S0, WS, coff + (size_t)i * B * L * L,
                                          lens, P, ET);
    k_compact<<<B * L / 4, 256, 0, stream>>>(P, ET, cmask, cnt);
    k_cnorm<<<B, 64, 0, stream>>>(cmask);
    k_update<<<B * L / 2, 256, 0, stream>>>(P, ET, cnt, hidden, upd);
    k_ffn<<<B * L / 64, 256, 0, stream>>>(upd, w1, fb1, w2, fb2, lng, lnb, cmask);
    k_ecadd<<<B, 512, 0, stream>>>(upd, ecacc);
  }

  k_embconv<<<NT, 256, 0, stream>>>(emb, ebh, ebl);
  k_gate<<<B, 128, 0, stream>>>(ecacc, e_s, gw, sess, out);
  k_scores<<<dim3((NT + 15) / 16, 8), 256, 0, stream>>>(sess, ebh, ebl, out);
}

// Round 9
// 459.956 us; speedup vs baseline: 1.9474x; 1.0333x over previous
//
#include <hip/hip_runtime.h>
#include <cstdint>
#include <cstddef>

namespace {
constexpr int B = 256, L = 200, H = 128, V = 50000, TK = 20;
constexpr int NT = 1563;                   // ceil(V/32)
constexpr float NEGV = -1e10f;
}

using bf16x8 = __attribute__((ext_vector_type(8))) short;
using s16x8  = __attribute__((ext_vector_type(8))) short;
using f32x16 = __attribute__((ext_vector_type(16))) float;

__device__ inline unsigned short f2bf(float f) {
  unsigned int u = __float_as_uint(f);
  unsigned int r = (u + 0x7fffu + ((u >> 16) & 1u)) >> 16;   // RNE
  return (unsigned short)r;
}

// ---- 16-lane-group DPP reductions ------------------------------------------
#define DPP_QUAD_XOR1 0xB1
#define DPP_QUAD_XOR2 0x4E
#define DPP_ROW_HMIRR 0x141
#define DPP_ROW_MIRR  0x140

template <int CTRL>
__device__ inline unsigned dpp16_max_step(unsigned v) {
  unsigned t = (unsigned)__builtin_amdgcn_update_dpp(0, (int)v, CTRL, 0xF, 0xF, true);
  return v > t ? v : t;
}
__device__ inline unsigned grp16_max(unsigned v) {
  v = dpp16_max_step<DPP_QUAD_XOR1>(v);
  v = dpp16_max_step<DPP_QUAD_XOR2>(v);
  v = dpp16_max_step<DPP_ROW_HMIRR>(v);
  v = dpp16_max_step<DPP_ROW_MIRR>(v);
  return v;                                   // uniform within each 16-group
}
template <int CTRL>
__device__ inline float dpp16_add_step(float v) {
  int t = __builtin_amdgcn_update_dpp(0, __float_as_int(v), CTRL, 0xF, 0xF, true);
  return v + __int_as_float(t);
}
__device__ inline float grp16_sum(float v) {
  v = dpp16_add_step<DPP_QUAD_XOR1>(v);
  v = dpp16_add_step<DPP_QUAD_XOR2>(v);
  v = dpp16_add_step<DPP_ROW_HMIRR>(v);
  v = dpp16_add_step<DPP_ROW_MIRR>(v);
  return v;
}

__device__ inline unsigned f2key(float f) {        // order-preserving, bijective
  unsigned b = __float_as_uint(f);
  unsigned m = (unsigned)((int)b >> 31);
  return b ^ (m | 0x80000000u);
}
__device__ inline float key2f(unsigned u) {
  unsigned b = (u & 0x80000000u) ? (u & 0x7fffffffu) : ~u;
  return __uint_as_float(b);
}

// ---- embed + norm + frag-linear bf16 hi/lo staging --------------------------
__global__ __launch_bounds__(256) void k_embed(const int* __restrict__ seq,
                                               const int* __restrict__ rev,
                                               const float* __restrict__ emb,
                                               const float* __restrict__ wnoise,
                                               float* __restrict__ hidden,
                                               float* __restrict__ nrm,
                                               s16x8* __restrict__ hbh,
                                               s16x8* __restrict__ hbl,
                                               s16x8* __restrict__ wnh,
                                               s16x8* __restrict__ wnl) {
  int b = blockIdx.x / 7, lt = blockIdx.x % 7;
  int t = threadIdx.x;
  int r = t >> 3, c2 = t & 7;                 // row-in-tile, 16-elem h-chunk
  int l = lt * 32 + r;
  bool valid = l < L;
  float vv[16], wv[16];
  if (valid) {
    int row = b * L + l;
    int tok = seq[row];
    const float4* ep = (const float4*)&emb[(size_t)tok * H + c2 * 16];
    const float4* wp = (const float4*)&wnoise[(size_t)rev[row] * H + c2 * 16];
#pragma unroll
    for (int i = 0; i < 4; ++i) {
      float4 x = ep[i];
      vv[i * 4 + 0] = x.x; vv[i * 4 + 1] = x.y; vv[i * 4 + 2] = x.z; vv[i * 4 + 3] = x.w;
      float4 y = wp[i];
      wv[i * 4 + 0] = y.x; wv[i * 4 + 1] = y.y; wv[i * 4 + 2] = y.z; wv[i * 4 + 3] = y.w;
    }
  } else {
#pragma unroll
    for (int i = 0; i < 16; ++i) { vv[i] = 0.f; wv[i] = 0.f; }
  }
  if (valid) {
    int row = b * L + l;
#pragma unroll
    for (int i = 0; i < 4; ++i)
      *(float4*)&hidden[(size_t)row * H + c2 * 16 + i * 4] =
          make_float4(vv[i * 4], vv[i * 4 + 1], vv[i * 4 + 2], vv[i * 4 + 3]);
    float s = 0.f;
#pragma unroll
    for (int i = 0; i < 16; ++i) s += vv[i] * vv[i];
    s += __shfl_down(s, 4, 8);
    s += __shfl_down(s, 2, 8);
    s += __shfl_down(s, 1, 8);
    if (c2 == 0) nrm[row] = sqrtf(s);
  }
  s16x8 h0, h1, l0, l1, w0, w1, x0, x1;
#pragma unroll
  for (int i = 0; i < 8; ++i) {
    unsigned short hi = f2bf(vv[i]);
    h0[i] = (short)hi;
    l0[i] = (short)f2bf(vv[i] - __uint_as_float((unsigned)hi << 16));
    unsigned short wh = f2bf(wv[i]);
    w0[i] = (short)wh;
    x0[i] = (short)f2bf(wv[i] - __uint_as_float((unsigned)wh << 16));
  }
#pragma unroll
  for (int i = 0; i < 8; ++i) {
    unsigned short hi = f2bf(vv[8 + i]);
    h1[i] = (short)hi;
    l1[i] = (short)f2bf(vv[8 + i] - __uint_as_float((unsigned)hi << 16));
    unsigned short wh = f2bf(wv[8 + i]);
    w1[i] = (short)wh;
    x1[i] = (short)f2bf(wv[8 + i] - __uint_as_float((unsigned)wh << 16));
  }
  size_t fi0 = ((size_t)(b * 7 + lt) * 8 + c2) * 64 + r;   // kh=0
  size_t fi1 = fi0 + 32;                                   // kh=1
  hbh[fi0] = h0; hbh[fi1] = h1;
  hbl[fi0] = l0; hbl[fi1] = l1;
  wnh[fi0] = w0; wnh[fi1] = w1;
  wnl[fi0] = x0; wnl[fi1] = x1;
}

// ------------------------------------------ slen, zero_layer (into ecacc), e_s
__global__ __launch_bounds__(512) void k_init(const int* __restrict__ lengths,
                                              const float* __restrict__ hidden,
                                              float* __restrict__ ecacc,
                                              float* __restrict__ e_s) {
  int b = blockIdx.x, tid = threadIdx.x;
  __shared__ float part[4][128];
  __shared__ int wcnt[8];
  __shared__ int s_slen;
  int c = (tid < L && lengths[b * L + tid] > 0) ? 1 : 0;
  for (int o = 32; o > 0; o >>= 1) c += __shfl_down(c, o, 64);
  if ((tid & 63) == 0) wcnt[tid >> 6] = c;
  __syncthreads();
  if (tid == 0) {
    int s = 0;
#pragma unroll
    for (int i = 0; i < 8; ++i) s += wcnt[i];
    s_slen = s;
  }
  int h = tid & 127, seg = tid >> 7;
  float s = 0.f;
  for (int l = seg; l < L; l += 4) s += hidden[(size_t)(b * L + l) * H + h];
  part[seg][h] = s;
  __syncthreads();
  if (tid < 128) {
    float tot = part[0][h] + part[1][h] + part[2][h] + part[3][h];
    int slen = s_slen;
    ecacc[b * H + h] = tot / (float)slen;
    e_s[b * H + h] = hidden[(size_t)(b * L + slen - 1) * H + h];
  }
}

// ---- S0 = cosine sim (+diag), WS = softplus(hidden·wn), bf16x3 split MFMA ---
// one 32x32 mtile per wave; grid = 8 XCD * 32 b * 7 lt * 2 half
__global__ __launch_bounds__(256) void k_simws(const s16x8* __restrict__ hbh,
                                               const s16x8* __restrict__ hbl,
                                               const s16x8* __restrict__ wnh,
                                               const s16x8* __restrict__ wnl,
                                               const float* __restrict__ nrm,
                                               const int* __restrict__ rev,
                                               const float* __restrict__ cluster,
                                               float* __restrict__ S0,
                                               float* __restrict__ WS) {
  int orig = blockIdx.x;                     // 0..3583
  int xcd = orig & 7, slot = orig >> 3;      // slot 0..447
  int b = xcd * 32 + slot / 14;
  int rem = slot % 14;
  int lt = rem >> 1, half = rem & 1;
  int wid = threadIdx.x >> 6, lane = threadIdx.x & 63;
  int mt = half * 4 + wid;                   // 0..7
  if (mt > 6) return;                        // one idle wave in odd halves
  int lr = lane & 31, kh = lane >> 5;
  size_t abase = ((size_t)(b * 7 + lt) * 8) * 64 + lane;
  bf16x8 ah[8], al[8];
#pragma unroll
  for (int ks = 0; ks < 8; ++ks) {
    ah[ks] = (bf16x8)hbh[abase + ks * 64];
    al[ks] = (bf16x8)hbl[abase + ks * 64];
  }
  size_t bbase = ((size_t)(b * 7 + mt) * 8) * 64 + lane;
  f32x16 accs = {}, accw = {};
#pragma unroll
  for (int ks = 0; ks < 8; ++ks) {
    bf16x8 bhh = (bf16x8)hbh[bbase + ks * 64];
    bf16x8 bhl = (bf16x8)hbl[bbase + ks * 64];
    bf16x8 bwh = (bf16x8)wnh[bbase + ks * 64];
    bf16x8 bwl = (bf16x8)wnl[bbase + ks * 64];
    accs = __builtin_amdgcn_mfma_f32_32x32x16_bf16(ah[ks], bhh, accs, 0, 0, 0);
    accs = __builtin_amdgcn_mfma_f32_32x32x16_bf16(ah[ks], bhl, accs, 0, 0, 0);
    accs = __builtin_amdgcn_mfma_f32_32x32x16_bf16(al[ks], bhh, accs, 0, 0, 0);
    accw = __builtin_amdgcn_mfma_f32_32x32x16_bf16(ah[ks], bwh, accw, 0, 0, 0);
    accw = __builtin_amdgcn_mfma_f32_32x32x16_bf16(ah[ks], bwl, accw, 0, 0, 0);
    accw = __builtin_amdgcn_mfma_f32_32x32x16_bf16(al[ks], bwh, accw, 0, 0, 0);
  }
  int m = mt * 32 + lr;
  if (m < L) {
    float nm = nrm[b * L + m];
#pragma unroll
    for (int r = 0; r < 16; ++r) {
      int row = lt * 32 + (r & 3) + 8 * (r >> 2) + 4 * kh;
      if (row < L) {
        float nl = nrm[b * L + row];
        float s0 = accs[r] * __builtin_amdgcn_rcpf(nl * nm + 1e-6f);
        if (row == m) s0 += cluster[rev[b * L + row]];
        size_t o = (size_t)(b * L + row) * L + m;
        S0[o] = s0;
        float x = accw[r];
        WS[o] = (x > 1.f) ? x : __logf(1.f + __expf(x));
      }
    }
  }
}

// ------- per row: msim in regs (13/lane over 16 lanes), DPP16 top-K, softmax
__global__ __launch_bounds__(256) void k_rowpass(const float* __restrict__ S0,
                                                 const float* __restrict__ WS,
                                                 const float* __restrict__ coff_i,
                                                 const int* __restrict__ lengths,
                                                 float* __restrict__ P,
                                                 unsigned char* __restrict__ ET) {
  int wid = threadIdx.x >> 6, lane = threadIdx.x & 63;
  int g = lane >> 4, q = lane & 15;
  int bb = blockIdx.x / 13, blk = blockIdx.x % 13;
  int l = blk * 16 + wid * 4 + g;
  bool lvalid = l < L;
  int lrow = bb * L + (lvalid ? l : 0);
  bool mask_l = lvalid && (lengths[lrow] > 0);
  size_t base = (size_t)lrow * L;
  float val[13]; unsigned key[13]; unsigned vmask = 0;
#pragma unroll
  for (int j = 0; j < 13; ++j) {
    int m = q + 16 * j;
    float v = 0.f; bool ok = false;
    if (mask_l && m < L) {
      ok = lengths[bb * L + m] > 0;
      if (ok) v = S0[base + m] + coff_i[base + m] * WS[base + m];
    }
    val[j] = v;
    key[j] = ok ? f2key(v) : 0u;
    vmask |= ok ? (1u << j) : 0u;
  }
  unsigned Mu = 0u;
  for (int t = 0; t < TK; ++t) {
    unsigned lv = key[0]; int lj = 0;
#pragma unroll
    for (int j = 1; j < 13; ++j) {
      bool gt = key[j] > lv;
      lv = gt ? key[j] : lv;
      lj = gt ? j : lj;
    }
    unsigned gm = grp16_max(lv);
    if (t == 0) Mu = gm;
    if (__all(gm == 0u)) break;              // all 4 groups exhausted
    unsigned long long bal = __ballot(lv == gm && gm != 0u);
    unsigned long long mine = bal & (0xFFFFull << (g * 16));
    int owner = mine ? (int)__builtin_ctzll(mine) : -1;
    bool is_owner = (lane == owner);         // lowest lane of group (tie ok)
    if (is_owner) {
      int m = q + 16 * lj;
      ET[((size_t)bb * L + m) * L + l] = 1;
    }
#pragma unroll
    for (int j = 0; j < 13; ++j) key[j] = (is_owner && lj == j) ? 0u : key[j];
  }
  // softmax over the row (invalid entries contribute exactly 0)
  float M = key2f(Mu);
  float e[13]; float s = 0.f;
#pragma unroll
  for (int j = 0; j < 13; ++j) {
    float ev = ((vmask >> j) & 1u) ? __expf(val[j] - M) : 0.f;
    e[j] = ev; s += ev;
  }
  s = grp16_sum(s);
  float inv = (s > 0.f) ? __builtin_amdgcn_rcpf(s) : 0.f;
  if (lvalid) {
#pragma unroll
    for (int j = 0; j < 13; ++j) {
      int m = q + 16 * j;
      if (m < L) P[base + m] = e[j] * inv;
    }
  }
}

// ---- ssm row = P * ET, row-sum -> cmask, ordered in-place compaction to lists
__global__ __launch_bounds__(256) void k_compact(float* __restrict__ P,
                                                 unsigned char* __restrict__ ET,
                                                 float* __restrict__ cmask,
                                                 int* __restrict__ cnt) {
  int wid = threadIdx.x >> 6, lane = threadIdx.x & 63;
  int row = blockIdx.x * 4 + wid;
  size_t base = (size_t)row * L;
  float w[4];
  float s = 0.f;
#pragma unroll
  for (int j = 0; j < 4; ++j) {
    int m = lane + 64 * j;
    float ww = 0.f;
    if (m < L) ww = P[base + m] * (float)ET[base + m];
    w[j] = ww; s += ww;
  }
  float ssum = s;
  for (int off = 1; off < 64; off <<= 1) ssum += __shfl_xor(ssum, off, 64);
  if (lane == 0) cmask[row] = ssum;
  int pos_base = 0;
#pragma unroll
  for (int j = 0; j < 4; ++j) {
    bool nz = (w[j] != 0.f);
    unsigned long long mk = __ballot(nz);
    int rank = __popcll(mk & ((1ull << lane) - 1ull));
    if (nz) {
      int pos = pos_base + rank;
      ET[base + pos] = (unsigned char)(lane + 64 * j);
      P[base + pos] = w[j];
    }
    pos_base += (int)__popcll(mk);
  }
  if (lane == 0) cnt[row] = pos_base;
}

// -------------------------------------------- cmask /= max(||cmask||_2, 1e-12)
__global__ __launch_bounds__(64) void k_cnorm(float* __restrict__ cmask) {
  int b = blockIdx.x, lane = threadIdx.x;   // 64 threads
  float v[4]; float s = 0.f;
#pragma unroll
  for (int j = 0; j < 4; ++j) {
    int l = lane + 64 * j;
    float x = (l < L) ? cmask[b * L + l] : 0.f;
    v[j] = x; s += x * x;
  }
  for (int off = 1; off < 64; off <<= 1) s += __shfl_xor(s, off, 64);
  float inv = 1.f / fmaxf(sqrtf(s), 1e-12f);
#pragma unroll
  for (int j = 0; j < 4; ++j) {
    int l = lane + 64 * j;
    if (l < L) cmask[b * L + l] = v[j] * inv;
  }
}

// --- update[l,:] = sum over edge list; chunked batched gather (n can be >TK!)
__global__ __launch_bounds__(256) void k_update(const float* __restrict__ P,
                                                const unsigned char* __restrict__ ET,
                                                const int* __restrict__ cnt,
                                                const float* __restrict__ hidden,
                                                float* __restrict__ upd) {
  int row = blockIdx.x * 2 + (threadIdx.x >> 7);
  int h = threadIdx.x & 127;
  int b = row / L;
  size_t base = (size_t)row * L;
  int n = cnt[row];
  float acc = 0.f;
  for (int e0 = 0; e0 < n; e0 += TK) {       // e0 multiple of 20, e0+20 <= 200
    float w[TK]; int m[TK];
    float4 p4[5];
#pragma unroll
    for (int i = 0; i < 5; ++i) p4[i] = *(const float4*)&P[base + e0 + i * 4];
#pragma unroll
    for (int i = 0; i < 5; ++i) {
      w[i * 4 + 0] = p4[i].x; w[i * 4 + 1] = p4[i].y;
      w[i * 4 + 2] = p4[i].z; w[i * 4 + 3] = p4[i].w;
    }
#pragma unroll
    for (int e = 0; e < TK; ++e) m[e] = ET[base + e0 + e];
    float hv[TK];
#pragma unroll
    for (int e = 0; e < TK; ++e)
      hv[e] = hidden[(size_t)(b * L + m[e]) * H + h];
#pragma unroll
    for (int e = 0; e < TK; ++e)
      acc += ((e0 + e) < n ? w[e] : 0.f) * hv[e];
  }
  upd[(size_t)row * H + h] = acc;
}

// ----- FFN + residual + LN via bf16x3 MFMA, weighted by cmask, in-place ------
__global__ __launch_bounds__(256) void k_ffn(float* __restrict__ upd,
                                             const float* __restrict__ W1,
                                             const float* __restrict__ b1,
                                             const float* __restrict__ W2,
                                             const float* __restrict__ b2,
                                             const float* __restrict__ g,
                                             const float* __restrict__ beta,
                                             const float* __restrict__ cmask) {
  constexpr int AS = 136;                            // short stride (16B-aligned rows)
  __shared__ __align__(16) char smem[4 * 64 * AS * 2];  // 69632 B
  short* ahs = (short*)smem;                         // A hi  [64][AS]
  short* als = ahs + 64 * AS;                        // A lo
  short* f1h = (short*)(smem + 2 * 64 * AS * 2);     // feed1 hi
  short* f1l = f1h + 64 * AS;
  float (*ps)[132] = (float (*)[132])smem;           // aliases A (dead after GEMM1)
  __shared__ float mus[64], rsd[64];
  int row0 = blockIdx.x * 64;
  int tid = threadIdx.x;
  int wid = tid >> 6, lane = tid & 63;
  int lr = lane & 31, kh = lane >> 5;
  int n0 = wid * 32;
  int n = n0 + lr;
  // ---- stage upd -> bf16 hi/lo LDS ----
#pragma unroll
  for (int it = 0; it < 8; ++it) {
    int f = it * 256 + tid;
    int r = f >> 5, c4 = (f & 31) * 4;
    float4 v = *(const float4*)&upd[(size_t)(row0 + r) * H + c4];
    float vv[4] = {v.x, v.y, v.z, v.w};
    unsigned short hh[4]; short ll[4];
#pragma unroll
    for (int q2 = 0; q2 < 4; ++q2) {
      hh[q2] = f2bf(vv[q2]);
      ll[q2] = (short)f2bf(vv[q2] - __uint_as_float((unsigned)hh[q2] << 16));
    }
    uint2 ph = make_uint2((unsigned)hh[0] | ((unsigned)hh[1] << 16),
                          (unsigned)hh[2] | ((unsigned)hh[3] << 16));
    uint2 pl = make_uint2((unsigned short)ll[0] | ((unsigned)(unsigned short)ll[1] << 16),
                          (unsigned short)ll[2] | ((unsigned)(unsigned short)ll[3] << 16));
    *(uint2*)&ahs[r * AS + c4] = ph;
    *(uint2*)&als[r * AS + c4] = pl;
  }
  __syncthreads();
  // ---- W1 fragments ----
  bf16x8 wfh[8], wfl[8];
#pragma unroll
  for (int ks = 0; ks < 8; ++ks) {
#pragma unroll
    for (int i = 0; i < 8; ++i) {
      float w = W1[(size_t)(ks * 16 + kh * 8 + i) * H + n];
      unsigned short hi = f2bf(w);
      wfh[ks][i] = (short)hi;
      wfl[ks][i] = (short)f2bf(w - __uint_as_float((unsigned)hi << 16));
    }
  }
  // ---- GEMM1: feed1 = relu(upd @ W1 + b1) ----
  f32x16 acc0, acc1;
  {
    float bv = b1[n];
#pragma unroll
    for (int r = 0; r < 16; ++r) { acc0[r] = bv; acc1[r] = bv; }
  }
#pragma unroll
  for (int ks = 0; ks < 8; ++ks) {
    bf16x8 xh0 = *(const bf16x8*)&ahs[(0 * 32 + lr) * AS + ks * 16 + kh * 8];
    bf16x8 xl0 = *(const bf16x8*)&als[(0 * 32 + lr) * AS + ks * 16 + kh * 8];
    bf16x8 xh1 = *(const bf16x8*)&ahs[(1 * 32 + lr) * AS + ks * 16 + kh * 8];
    bf16x8 xl1 = *(const bf16x8*)&als[(1 * 32 + lr) * AS + ks * 16 + kh * 8];
    acc0 = __builtin_amdgcn_mfma_f32_32x32x16_bf16(xh0, wfh[ks], acc0, 0, 0, 0);
    acc0 = __builtin_amdgcn_mfma_f32_32x32x16_bf16(xl0, wfh[ks], acc0, 0, 0, 0);
    acc0 = __builtin_amdgcn_mfma_f32_32x32x16_bf16(xh0, wfl[ks], acc0, 0, 0, 0);
    acc1 = __builtin_amdgcn_mfma_f32_32x32x16_bf16(xh1, wfh[ks], acc1, 0, 0, 0);
    acc1 = __builtin_amdgcn_mfma_f32_32x32x16_bf16(xl1, wfh[ks], acc1, 0, 0, 0);
    acc1 = __builtin_amdgcn_mfma_f32_32x32x16_bf16(xh1, wfl[ks], acc1, 0, 0, 0);
  }
  // relu -> f1 hi/lo LDS (C layout: row=(r&3)+8*(r>>2)+4*kh, col=n)
#pragma unroll
  for (int r = 0; r < 16; ++r) {
    int crow = (r & 3) + 8 * (r >> 2) + 4 * kh;
    float f0 = fmaxf(acc0[r], 0.f);
    unsigned short h0 = f2bf(f0);
    f1h[crow * AS + n] = (short)h0;
    f1l[crow * AS + n] = (short)f2bf(f0 - __uint_as_float((unsigned)h0 << 16));
    float f1v = fmaxf(acc1[r], 0.f);
    unsigned short h1 = f2bf(f1v);
    f1h[(32 + crow) * AS + n] = (short)h1;
    f1l[(32 + crow) * AS + n] = (short)f2bf(f1v - __uint_as_float((unsigned)h1 << 16));
  }
  __syncthreads();                                    // f1 complete; A region dead
  // ---- W2 fragments ----
#pragma unroll
  for (int ks = 0; ks < 8; ++ks) {
#pragma unroll
    for (int i = 0; i < 8; ++i) {
      float w = W2[(size_t)(ks * 16 + kh * 8 + i) * H + n];
      unsigned short hi = f2bf(w);
      wfh[ks][i] = (short)hi;
      wfl[ks][i] = (short)f2bf(w - __uint_as_float((unsigned)hi << 16));
    }
  }
  // ---- GEMM2: pre = feed1 @ W2 + b2 + upd ----
  {
    float bv = b2[n];
#pragma unroll
    for (int r = 0; r < 16; ++r) { acc0[r] = bv; acc1[r] = bv; }
  }
#pragma unroll
  for (int ks = 0; ks < 8; ++ks) {
    bf16x8 xh0 = *(const bf16x8*)&f1h[(0 * 32 + lr) * AS + ks * 16 + kh * 8];
    bf16x8 xl0 = *(const bf16x8*)&f1l[(0 * 32 + lr) * AS + ks * 16 + kh * 8];
    bf16x8 xh1 = *(const bf16x8*)&f1h[(1 * 32 + lr) * AS + ks * 16 + kh * 8];
    bf16x8 xl1 = *(const bf16x8*)&f1l[(1 * 32 + lr) * AS + ks * 16 + kh * 8];
    acc0 = __builtin_amdgcn_mfma_f32_32x32x16_bf16(xh0, wfh[ks], acc0, 0, 0, 0);
    acc0 = __builtin_amdgcn_mfma_f32_32x32x16_bf16(xl0, wfh[ks], acc0, 0, 0, 0);
    acc0 = __builtin_amdgcn_mfma_f32_32x32x16_bf16(xh0, wfl[ks], acc0, 0, 0, 0);
    acc1 = __builtin_amdgcn_mfma_f32_32x32x16_bf16(xh1, wfh[ks], acc1, 0, 0, 0);
    acc1 = __builtin_amdgcn_mfma_f32_32x32x16_bf16(xl1, wfh[ks], acc1, 0, 0, 0);
    acc1 = __builtin_amdgcn_mfma_f32_32x32x16_bf16(xh1, wfl[ks], acc1, 0, 0, 0);
  }
  // residual + write ps (pre) — ps aliases A region (dead since barrier)
#pragma unroll
  for (int r = 0; r < 16; ++r) {
    int crow = (r & 3) + 8 * (r >> 2) + 4 * kh;
    float p0 = acc0[r] + upd[(size_t)(row0 + crow) * H + n];
    float p1 = acc1[r] + upd[(size_t)(row0 + 32 + crow) * H + n];
    acc0[r] = p0; acc1[r] = p1;
    ps[crow][n] = p0;
    ps[32 + crow][n] = p1;
  }
  __syncthreads();
  // ---- LN stats: 4 threads per row ----
  {
    int r = tid >> 2, sub = tid & 3;
    float s = 0.f, sq = 0.f;
#pragma unroll
    for (int j = 0; j < 8; ++j) {
      float4 x = *(const float4*)&ps[r][sub * 32 + j * 4];
      s += x.x + x.y + x.z + x.w;
      sq += x.x * x.x + x.y * x.y + x.z * x.z + x.w * x.w;
    }
    s += __shfl_down(s, 2, 4);  s += __shfl_down(s, 1, 4);
    sq += __shfl_down(sq, 2, 4); sq += __shfl_down(sq, 1, 4);
    if (sub == 0) {
      float mu = s * (1.f / 128.f);
      float var = sq * (1.f / 128.f) - mu * mu;
      mus[r] = mu;
      rsd[r] = rsqrtf(var + 1e-5f);
    }
  }
  __syncthreads();
  // ---- normalize, scale by cmask, write ----
  {
    float gn = g[n], bn = beta[n];
#pragma unroll
    for (int r = 0; r < 16; ++r) {
      int crow = (r & 3) + 8 * (r >> 2) + 4 * kh;
      float o0 = ((acc0[r] - mus[crow]) * rsd[crow] * gn + bn) * cmask[row0 + crow];
      float o1 = ((acc1[r] - mus[32 + crow]) * rsd[32 + crow] * gn + bn) * cmask[row0 + 32 + crow];
      upd[(size_t)(row0 + crow) * H + n] = o0;
      upd[(size_t)(row0 + 32 + crow) * H + n] = o1;
    }
  }
}

// ---------------------------------------------- ecacc += sum_l (weighted feed2)
__global__ __launch_bounds__(512) void k_ecadd(const float* __restrict__ wf,
                                               float* __restrict__ ecacc) {
  int b = blockIdx.x, tid = threadIdx.x;
  __shared__ float part[4][128];
  int h = tid & 127, seg = tid >> 7;
  float s = 0.f;
  for (int l = seg; l < L; l += 4) s += wf[(size_t)(b * L + l) * H + h];
  part[seg][h] = s;
  __syncthreads();
  if (tid < 128)
    ecacc[b * H + h] += part[0][h] + part[1][h] + part[2][h] + part[3][h];
}

// ------------ emb fp32 -> frag-linear bf16 hi/lo (padded to NT 32-row tiles)
__global__ __launch_bounds__(256) void k_embconv(const float* __restrict__ emb,
                                                 s16x8* __restrict__ ebh,
                                                 s16x8* __restrict__ ebl) {
  int nt = blockIdx.x;
  int t = threadIdx.x;
  int r = t >> 3, c2 = t & 7;
  int n = nt * 32 + r;
  float vv[16];
  if (n < V) {
    const float4* ep = (const float4*)&emb[(size_t)n * H + c2 * 16];
#pragma unroll
    for (int i = 0; i < 4; ++i) {
      float4 x = ep[i];
      vv[i * 4 + 0] = x.x; vv[i * 4 + 1] = x.y; vv[i * 4 + 2] = x.z; vv[i * 4 + 3] = x.w;
    }
  } else {
#pragma unroll
    for (int i = 0; i < 16; ++i) vv[i] = 0.f;
  }
  s16x8 h0, h1, l0, l1;
#pragma unroll
  for (int i = 0; i < 8; ++i) {
    unsigned short hi = f2bf(vv[i]);
    h0[i] = (short)hi;
    l0[i] = (short)f2bf(vv[i] - __uint_as_float((unsigned)hi << 16));
    unsigned short hj = f2bf(vv[8 + i]);
    h1[i] = (short)hj;
    l1[i] = (short)f2bf(vv[8 + i] - __uint_as_float((unsigned)hj << 16));
  }
  size_t fi0 = ((size_t)nt * 8 + c2) * 64 + r;
  size_t fi1 = fi0 + 32;
  ebh[fi0] = h0; ebh[fi1] = h1;
  ebl[fi0] = l0; ebl[fi1] = l1;
}

// -------------------------------------------------------- gate -> sess, extras
__global__ __launch_bounds__(128) void k_gate(const float* __restrict__ ecacc,
                                              const float* __restrict__ e_s,
                                              const float* __restrict__ gw,
                                              float* __restrict__ sess,
                                              float* __restrict__ out) {
  __shared__ float cat[256];
  int b = blockIdx.x, h = threadIdx.x;
  float ec = ecacc[b * H + h] * (1.f / 3.f);
  float es = e_s[b * H + h];
  cat[h] = ec; cat[128 + h] = es;
  __syncthreads();
  float a = 0.f;
  for (int j = 0; j < 256; ++j) a = fmaf(cat[j], gw[(size_t)j * H + h], a);
  a = 1.f / (1.f + __expf(-a));
  sess[b * H + h] = a * ec + (1.f - a) * es;
  if (b == 0 && h == 0) out[(size_t)B * V] = 0.f;   // con_loss
}

// ---------- scores = sess @ emb^T via bf16x3 MFMA (frag-linear emb) ----------
// grid (ceil(NT/16), 8 mtiles); wave w handles nt = bx*16 + w + 4j
__global__ __launch_bounds__(256) void k_scores(const float* __restrict__ sess,
                                                const s16x8* __restrict__ ebh,
                                                const s16x8* __restrict__ ebl,
                                                float* __restrict__ out) {
  int wid = threadIdx.x >> 6, lane = threadIdx.x & 63;
  int lr = lane & 31, kh = lane >> 5;
  int mt = blockIdx.y;
  int m = mt * 32 + lr;
  // A fragments from sess (fp32 -> bf16 hi/lo in registers; sess is L2-hot)
  bf16x8 ah[8], al[8];
#pragma unroll
  for (int ks = 0; ks < 8; ++ks) {
    const float* sp = &sess[(size_t)m * H + ks * 16 + kh * 8];
    float4 a = *(const float4*)sp;
    float4 c = *(const float4*)(sp + 4);
    float av[8] = {a.x, a.y, a.z, a.w, c.x, c.y, c.z, c.w};
#pragma unroll
    for (int i = 0; i < 8; ++i) {
      unsigned short hi = f2bf(av[i]);
      ah[ks][i] = (short)hi;
      al[ks][i] = (short)f2bf(av[i] - __uint_as_float((unsigned)hi << 16));
    }
  }
  int ntEnd = min(blockIdx.x * 16 + 16, NT);
  for (int nt = blockIdx.x * 16 + wid; nt < ntEnd; nt += 4) {
    size_t bbase = ((size_t)nt * 8) * 64 + lane;
    f32x16 acc = {};
#pragma unroll
    for (int ks = 0; ks < 8; ++ks) {
      bf16x8 bh = (bf16x8)ebh[bbase + ks * 64];
      bf16x8 bl = (bf16x8)ebl[bbase + ks * 64];
      acc = __builtin_amdgcn_mfma_f32_32x32x16_bf16(ah[ks], bh, acc, 0, 0, 0);
      acc = __builtin_amdgcn_mfma_f32_32x32x16_bf16(al[ks], bh, acc, 0, 0, 0);
      acc = __builtin_amdgcn_mfma_f32_32x32x16_bf16(ah[ks], bl, acc, 0, 0, 0);
    }
    int n = nt * 32 + lr;
    if (n < V) {
#pragma unroll
      for (int r = 0; r < 16; ++r) {
        int row = mt * 32 + (r & 3) + 8 * (r >> 2) + 4 * kh;
        out[(size_t)row * V + n] = acc[r];
      }
    }
  }
}

extern "C" void kernel_launch(void* const* d_in, const int* in_sizes, int n_in,
                              void* d_out, int out_size, void* d_ws, size_t ws_size,
                              hipStream_t stream) {
  const int*   seq  = (const int*)d_in[0];
  const int*   lens = (const int*)d_in[1];
  const int*   rev  = (const int*)d_in[2];
  const float* emb  = (const float*)d_in[3];
  const float* wnz  = (const float*)d_in[4];
  const float* clw  = (const float*)d_in[5];
  const float* w1   = (const float*)d_in[6];
  const float* fb1  = (const float*)d_in[7];
  const float* w2   = (const float*)d_in[8];
  const float* fb2  = (const float*)d_in[9];
  const float* lng  = (const float*)d_in[10];
  const float* lnb  = (const float*)d_in[11];
  const float* gw   = (const float*)d_in[12];
  const float* coff = (const float*)d_in[13];
  float* out = (float*)d_out;

  char* ws = (char*)d_ws;
  size_t off = 0;
  auto alloc = [&](size_t bytes) {
    void* p = ws + off;
    off += (bytes + 255) & ~(size_t)255;
    return p;
  };
  float* hidden = (float*)alloc((size_t)B * L * H * 4);
  float* nrm    = (float*)alloc((size_t)B * L * 4);
  float* S0     = (float*)alloc((size_t)B * L * L * 4);
  float* WS     = (float*)alloc((size_t)B * L * L * 4);
  float* P      = (float*)alloc((size_t)B * L * L * 4);
  float* upd    = (float*)alloc((size_t)B * L * H * 4);
  float* cmask  = (float*)alloc((size_t)B * L * 4);
  int*   cnt    = (int*)alloc((size_t)B * L * 4);
  float* e_s    = (float*)alloc((size_t)B * H * 4);
  float* ecacc  = (float*)alloc((size_t)B * H * 4);
  float* sess   = (float*)alloc((size_t)B * H * 4);
  unsigned char* ET = (unsigned char*)alloc((size_t)B * L * L);
  s16x8* hbh = (s16x8*)alloc((size_t)B * 7 * 8 * 64 * 16);   // frag-linear
  s16x8* wnh = (s16x8*)alloc((size_t)B * 7 * 8 * 64 * 16);
  // lo-residual staging aliases P/upd (first written only inside the layer loop,
  // strictly after k_simws has consumed the staging buffers)
  s16x8* hbl = (s16x8*)P;
  s16x8* wnl = (s16x8*)upd;
  // emb bf16 hi/lo staging aliases S0/WS (dead after the last k_rowpass);
  // NT*8*64*16 B = 12.8 MB each <= 41 MB each
  s16x8* ebh = (s16x8*)S0;
  s16x8* ebl = (s16x8*)WS;

  k_embed<<<B * 7, 256, 0, stream>>>(seq, rev, emb, wnz, hidden, nrm,
                                     hbh, hbl, wnh, wnl);
  k_init<<<B, 512, 0, stream>>>(lens, hidden, ecacc, e_s);
  k_simws<<<B * 14, 256, 0, stream>>>(hbh, hbl, wnh, wnl, nrm, rev, clw, S0, WS);

  for (int i = 0; i < 2; ++i) {
    hipMemsetAsync(ET, 0, (size_t)B * L * L, stream);
    k_rowpass<<<B * 13, 256, 0, stream>>>(S0, WS, coff + (size_t)i * B * L * L,
                                          lens, P, ET);
    k_compact<<<B * L / 4, 256, 0, stream>>>(P, ET, cmask, cnt);
    k_cnorm<<<B, 64, 0, stream>>>(cmask);
    k_update<<<B * L / 2, 256, 0, stream>>>(P, ET, cnt, hidden, upd);
    k_ffn<<<B * L / 64, 256, 0, stream>>>(upd, w1, fb1, w2, fb2, lng, lnb, cmask);
    k_ecadd<<<B, 512, 0, stream>>>(upd, ecacc);
  }

  k_embconv<<<NT, 256, 0, stream>>>(emb, ebh, ebl);
  k_gate<<<B, 128, 0, stream>>>(ecacc, e_s, gw, sess, out);
  k_scores<<<dim3((NT + 15) / 16, 8), 256, 0, stream>>>(sess, ebh, ebl, out);
}